// Round 6
// baseline (1345.921 us; speedup 1.0000x reference)
//
#include <hip/hip_runtime.h>
#include <hip/hip_bf16.h>
#include <math.h>

// ---------------------------------------------------------------------------
// Problem constants (from reference)
// ---------------------------------------------------------------------------
#define N_NODES  200000
#define N_EDGES  800000
#define N_GRAPHS 2048
#define N_SUB    32768
#define E_SUB    131072
#define F_IN     38
#define H0       256
#define H1       128
#define H2       64
#define BN_EPS   1e-5f

typedef __hip_bfloat16 bf16;
typedef __attribute__((ext_vector_type(8))) short short8;
typedef __attribute__((ext_vector_type(4))) short short4v;
typedef __attribute__((ext_vector_type(4))) float float4v;

static __host__ __device__ inline int cdiv(int a, int b) { return (a + b - 1) / b; }

__device__ inline float ldf(const float* p, size_t i) { return p[i]; }
__device__ inline float ldf(const bf16* p, size_t i)  { return __bfloat162float(p[i]); }
__device__ inline void  stf(float* p, size_t i, float v) { p[i] = v; }
__device__ inline void  stf(bf16* p, size_t i, float v)  { p[i] = __float2bfloat16(v); }

__device__ inline float2 ldf2(const float* p, size_t i) { return ((const float2*)p)[i]; }
__device__ inline float2 ldf2(const bf16* p, size_t i) {
    __hip_bfloat162 v = ((const __hip_bfloat162*)p)[i];
    return make_float2(__bfloat162float(v.x), __bfloat162float(v.y));
}
__device__ inline void stf2(float* p, size_t i, float2 v) { ((float2*)p)[i] = v; }
__device__ inline void stf2(bf16* p, size_t i, float2 v) {
    __hip_bfloat162 t;
    t.x = __float2bfloat16(v.x);
    t.y = __float2bfloat16(v.y);
    ((__hip_bfloat162*)p)[i] = t;
}

__device__ inline short bf16bits(float v) {
    bf16 t = __float2bfloat16(v);
    return *reinterpret_cast<short*>(&t);
}
__device__ inline float bits2f(short s) {
    return __bfloat162float(*reinterpret_cast<const bf16*>(&s));
}

// ---------------------------------------------------------------------------
// Zero fill (graph-capture-safe replacement for hipMemsetAsync)
// ---------------------------------------------------------------------------
__global__ void k_zero(float* __restrict__ p, int n) {
    int i = blockIdx.x * 256 + threadIdx.x;
    if (i < n) p[i] = 0.f;
}

// ---------------------------------------------------------------------------
// Graph preprocessing: degree, CSR build
// ---------------------------------------------------------------------------
__global__ void k_count(const int* __restrict__ dst, int* __restrict__ cnt, int e) {
    int i = blockIdx.x * 256 + threadIdx.x;
    if (i < e) atomicAdd(&cnt[dst[i]], 1);
}

__global__ void k_dinv(const int* __restrict__ cnt, float* __restrict__ dinv, int n) {
    int i = blockIdx.x * 256 + threadIdx.x;
    if (i < n) dinv[i] = rsqrtf(1.0f + (float)cnt[i]);
}

__global__ void k_scan_sum(const int* __restrict__ cnt, int* __restrict__ bsum, int n) {
    __shared__ int tmp[256];
    int t = threadIdx.x;
    int i = blockIdx.x * 256 + t;
    tmp[t] = (i < n) ? cnt[i] : 0;
    __syncthreads();
    for (int off = 128; off > 0; off >>= 1) {
        if (t < off) tmp[t] += tmp[t + off];
        __syncthreads();
    }
    if (t == 0) bsum[blockIdx.x] = tmp[0];
}

__global__ void k_scan_top(int* __restrict__ bsum, int nb) {
    __shared__ int tmp[1024];
    int t = threadIdx.x;
    int v = (t < nb) ? bsum[t] : 0;
    tmp[t] = v;
    __syncthreads();
    for (int off = 1; off < 1024; off <<= 1) {
        int a = (t >= off) ? tmp[t - off] : 0;
        __syncthreads();
        tmp[t] += a;
        __syncthreads();
    }
    if (t < nb) bsum[t] = tmp[t] - v;  // exclusive
}

__global__ void k_scan_apply(const int* __restrict__ cnt, const int* __restrict__ bsum,
                             int* __restrict__ rowptr, int n) {
    __shared__ int tmp[256];
    int t = threadIdx.x;
    int i = blockIdx.x * 256 + t;
    int v = (i < n) ? cnt[i] : 0;
    tmp[t] = v;
    __syncthreads();
    for (int off = 1; off < 256; off <<= 1) {
        int a = (t >= off) ? tmp[t - off] : 0;
        __syncthreads();
        tmp[t] += a;
        __syncthreads();
    }
    int excl = tmp[t] - v + bsum[blockIdx.x];
    if (i < n) rowptr[i] = excl;
    if (i == n - 1) rowptr[n] = excl + v;
}

// cursor aliases the (consumed) cnt buffer — re-zeroed before this kernel.
__global__ void k_fill(const int* __restrict__ src, const int* __restrict__ dst,
                       const int* __restrict__ rowptr, int* __restrict__ cursor,
                       int* __restrict__ col, int e) {
    int i = blockIdx.x * 256 + threadIdx.x;
    if (i < e) {
        int d = dst[i];
        int p = rowptr[d] + atomicAdd(&cursor[d], 1);
        col[p] = src[i];
    }
}

// ---------------------------------------------------------------------------
// Segment boundaries from a SORTED segment array.
// ---------------------------------------------------------------------------
__global__ void k_gbound(const int* __restrict__ seg, int n, int nseg,
                         int* __restrict__ gstart) {
    int i = blockIdx.x * 256 + threadIdx.x;
    if (i >= n) return;
    int s = seg[i];
    if (i == 0) {
        for (int g = 0; g <= s; ++g) gstart[g] = 0;
    } else {
        int p = seg[i - 1];
        for (int g = p + 1; g <= s; ++g) gstart[g] = i;
    }
    if (i == n - 1) {
        for (int g = s + 1; g <= nseg; ++g) gstart[g] = n;
    }
}

// ---------------------------------------------------------------------------
// Merge pos/neg subgraph inputs into one batched problem.
// ---------------------------------------------------------------------------
__global__ void k_merge(const float* __restrict__ px, const float* __restrict__ nx,
                        const int* __restrict__ pei, const int* __restrict__ nei,
                        const int* __restrict__ pb, const int* __restrict__ nbt,
                        float* __restrict__ mx, int* __restrict__ msrc,
                        int* __restrict__ mdst, int* __restrict__ mb) {
    int stride = gridDim.x * 256;
    for (int i = blockIdx.x * 256 + threadIdx.x; i < N_SUB * F_IN; i += stride) {
        mx[i] = px[i];
        mx[(size_t)N_SUB * F_IN + i] = nx[i];
    }
    for (int i = blockIdx.x * 256 + threadIdx.x; i < E_SUB; i += stride) {
        msrc[i] = pei[i];
        mdst[i] = pei[E_SUB + i];
        msrc[E_SUB + i] = nei[i] + N_SUB;
        mdst[E_SUB + i] = nei[E_SUB + i] + N_SUB;
    }
    for (int i = blockIdx.x * 256 + threadIdx.x; i < N_SUB; i += stride) {
        mb[i] = pb[i];
        mb[N_SUB + i] = nbt[i] + N_GRAPHS;
    }
}

// ---------------------------------------------------------------------------
// Gather v5 (dual-chain rotated pipeline; float2/lane).  Kept for the two
// fp32-input layer-0 sites (M=38).
// ---------------------------------------------------------------------------
template <typename TI, typename TO, int PPN>
__global__ __launch_bounds__(256) void k_gather5(
    const TI* __restrict__ h, const float* __restrict__ dinv,
    const int* __restrict__ rowptr, const int* __restrict__ col,
    TO* __restrict__ o, int n, int M2, int S2,
    const float* __restrict__ bias, int relu)
{
    const int NPW = 64 / PPN;  // lane-groups per wave
    int g0 = threadIdx.x / PPN;
    int pr = threadIdx.x % PPN;
    int nA = (blockIdx.x * 4 + threadIdx.y) * (2 * NPW) + g0 * 2;
    if (nA >= n) return;
    int nB = nA + 1;
    bool okB = nB < n;
    bool pld = pr < M2, pst = pr < S2;

    int2 rp = *(const int2*)(rowptr + nA);
    float diA = dinv[nA];
    float diB = okB ? dinv[nB] : 0.f;
    float2 vsA = make_float2(0.f, 0.f), vsB = make_float2(0.f, 0.f);
    if (pld) {
        vsA = ldf2(h, (size_t)nA * M2 + pr);
        if (okB) vsB = ldf2(h, (size_t)nB * M2 + pr);
    }
    int peB = okB ? rowptr[nA + 2] : rp.y;

    int pA = rp.x, peA = rp.y;
    int pB = peA;  // rowptr[nB] == rowptr[nA+1]

    int sA1 = 0, sB1 = 0;
    float dA0 = 0.f, dB0 = 0.f;
    float2 vA0 = make_float2(0.f, 0.f), vB0 = make_float2(0.f, 0.f);

    if (pA < peA) {
        int s0 = col[pA];
        sA1 = (pA + 1 < peA) ? col[pA + 1] : 0;
        dA0 = dinv[s0];
        if (pld) vA0 = ldf2(h, (size_t)s0 * M2 + pr);
    }
    if (pB < peB) {
        int s0 = col[pB];
        sB1 = (pB + 1 < peB) ? col[pB + 1] : 0;
        dB0 = dinv[s0];
        if (pld) vB0 = ldf2(h, (size_t)s0 * M2 + pr);
    }

    float2 accA, accB;
    accA.x = diA * diA * vsA.x; accA.y = diA * diA * vsA.y;
    accB.x = diB * diB * vsB.x; accB.y = diB * diB * vsB.y;

    while (pA < peA && pB < peB) {
        int sA2 = (pA + 2 < peA) ? col[pA + 2] : 0;
        int sB2 = (pB + 2 < peB) ? col[pB + 2] : 0;
        float2 vA1 = (pA + 1 < peA && pld) ? ldf2(h, (size_t)sA1 * M2 + pr)
                                           : make_float2(0.f, 0.f);
        float2 vB1 = (pB + 1 < peB && pld) ? ldf2(h, (size_t)sB1 * M2 + pr)
                                           : make_float2(0.f, 0.f);
        float dA1 = (pA + 1 < peA) ? dinv[sA1] : 0.f;
        float dB1 = (pB + 1 < peB) ? dinv[sB1] : 0.f;
        float cfA = dA0 * diA, cfB = dB0 * diB;
        accA.x += cfA * vA0.x; accA.y += cfA * vA0.y;
        accB.x += cfB * vB0.x; accB.y += cfB * vB0.y;
        sA1 = sA2; vA0 = vA1; dA0 = dA1;
        sB1 = sB2; vB0 = vB1; dB0 = dB1;
        ++pA; ++pB;
    }
    while (pA < peA) {
        int sA2 = (pA + 2 < peA) ? col[pA + 2] : 0;
        float2 vA1 = (pA + 1 < peA && pld) ? ldf2(h, (size_t)sA1 * M2 + pr)
                                           : make_float2(0.f, 0.f);
        float dA1 = (pA + 1 < peA) ? dinv[sA1] : 0.f;
        float cfA = dA0 * diA;
        accA.x += cfA * vA0.x; accA.y += cfA * vA0.y;
        sA1 = sA2; vA0 = vA1; dA0 = dA1; ++pA;
    }
    while (pB < peB) {
        int sB2 = (pB + 2 < peB) ? col[pB + 2] : 0;
        float2 vB1 = (pB + 1 < peB && pld) ? ldf2(h, (size_t)sB1 * M2 + pr)
                                           : make_float2(0.f, 0.f);
        float dB1 = (pB + 1 < peB) ? dinv[sB1] : 0.f;
        float cfB = dB0 * diB;
        accB.x += cfB * vB0.x; accB.y += cfB * vB0.y;
        sB1 = sB2; vB0 = vB1; dB0 = dB1; ++pB;
    }

    if (pst) {
        float2 rA = accA;
        if (bias && pld) { rA.x += bias[2 * pr]; rA.y += bias[2 * pr + 1]; }
        if (relu) { rA.x = fmaxf(rA.x, 0.f); rA.y = fmaxf(rA.y, 0.f); }
        stf2(o, (size_t)nA * S2 + pr, rA);
        if (okB) {
            float2 rB = accB;
            if (bias && pld) { rB.x += bias[2 * pr]; rB.y += bias[2 * pr + 1]; }
            if (relu) { rB.x = fmaxf(rB.x, 0.f); rB.y = fmaxf(rB.y, 0.f); }
            stf2(o, (size_t)nB * S2 + pr, rB);
        }
    }
}

template <typename TI, typename TO>
static void launch_gather(const TI* h, const float* dinv, const int* rowptr,
                          const int* col, TO* o, int n, int M, int Sout,
                          const float* bias, int relu, hipStream_t stream) {
    dim3 b(64, 4);
    int M2 = M >> 1, S2 = Sout >> 1;
    if (S2 > 32)
        k_gather5<TI, TO, 64><<<cdiv(n, 8), b, 0, stream>>>(h, dinv, rowptr, col, o,
                                                            n, M2, S2, bias, relu);
    else
        k_gather5<TI, TO, 32><<<cdiv(n, 16), b, 0, stream>>>(h, dinv, rowptr, col, o,
                                                             n, M2, S2, bias, relu);
}

// ---------------------------------------------------------------------------
// Gather v6 (bf16 in, 16 B/lane): LPR lanes cover one row (LPR*8 = W cols),
// 64/LPR dual-chain lane-groups per wave; rotated pipeline.
// ---------------------------------------------------------------------------
template <typename TO, int LPR>
__global__ __launch_bounds__(256) void k_gather6(
    const bf16* __restrict__ h, const float* __restrict__ dinv,
    const int* __restrict__ rowptr, const int* __restrict__ col,
    TO* __restrict__ o, int n, const float* __restrict__ bias, int relu)
{
    const int W = LPR * 8;
    const int NG = 64 / LPR;
    const int g = threadIdx.x / LPR;
    const int c0 = (threadIdx.x % LPR) * 8;
    const int nA = (blockIdx.x * 4 + threadIdx.y) * (2 * NG) + g * 2;
    const int nB = nA + 1;
    if (nA >= n) return;           // group-uniform
    const bool okB = nB < n;

    int2 rp = *(const int2*)(rowptr + nA);
    int peB = okB ? rowptr[nB + 1] : rp.y;
    float diA = dinv[nA];
    float diB = okB ? dinv[nB] : 0.f;
    short8 zed = {0, 0, 0, 0, 0, 0, 0, 0};
    short8 slA = *(const short8*)(h + (size_t)nA * W + c0);
    short8 slB = okB ? *(const short8*)(h + (size_t)nB * W + c0) : zed;

    int pA = rp.x, peA = rp.y;
    int pB = rp.y;

    float accA[8], accB[8];
    float qA = diA * diA, qB = diB * diB;
#pragma unroll
    for (int j = 0; j < 8; ++j) {
        accA[j] = qA * bits2f(slA[j]);
        accB[j] = qB * bits2f(slB[j]);
    }

    // rotated pipeline state
    int sA1 = 0, sB1 = 0;
    float dA0 = 0.f, dB0 = 0.f;
    short8 vA0 = zed, vB0 = zed;
    if (pA < peA) {
        int s0 = col[pA];
        sA1 = (pA + 1 < peA) ? col[pA + 1] : 0;
        dA0 = dinv[s0];
        vA0 = *(const short8*)(h + (size_t)s0 * W + c0);
    }
    if (pB < peB) {
        int s0 = col[pB];
        sB1 = (pB + 1 < peB) ? col[pB + 1] : 0;
        dB0 = dinv[s0];
        vB0 = *(const short8*)(h + (size_t)s0 * W + c0);
    }

    while (__any(pA < peA || pB < peB)) {
        if (pA < peA) {
            int sA2 = (pA + 2 < peA) ? col[pA + 2] : 0;
            short8 vA1 = zed;
            float dA1 = 0.f;
            if (pA + 1 < peA) {
                vA1 = *(const short8*)(h + (size_t)sA1 * W + c0);
                dA1 = dinv[sA1];
            }
            float cf = dA0 * diA;
#pragma unroll
            for (int j = 0; j < 8; ++j) accA[j] += cf * bits2f(vA0[j]);
            vA0 = vA1; dA0 = dA1; sA1 = sA2; ++pA;
        }
        if (pB < peB) {
            int sB2 = (pB + 2 < peB) ? col[pB + 2] : 0;
            short8 vB1 = zed;
            float dB1 = 0.f;
            if (pB + 1 < peB) {
                vB1 = *(const short8*)(h + (size_t)sB1 * W + c0);
                dB1 = dinv[sB1];
            }
            float cf = dB0 * diB;
#pragma unroll
            for (int j = 0; j < 8; ++j) accB[j] += cf * bits2f(vB0[j]);
            vB0 = vB1; dB0 = dB1; sB1 = sB2; ++pB;
        }
    }

    float bv[8];
#pragma unroll
    for (int j = 0; j < 8; ++j) bv[j] = 0.f;
    if (bias) {
        float4 b0 = *(const float4*)(bias + c0);
        float4 b1 = *(const float4*)(bias + c0 + 4);
        bv[0] = b0.x; bv[1] = b0.y; bv[2] = b0.z; bv[3] = b0.w;
        bv[4] = b1.x; bv[5] = b1.y; bv[6] = b1.z; bv[7] = b1.w;
    }

    auto store_row = [&](int node, float* acc) {
        float r[8];
#pragma unroll
        for (int j = 0; j < 8; ++j) {
            r[j] = acc[j] + bv[j];
            if (relu) r[j] = fmaxf(r[j], 0.f);
        }
        size_t off = (size_t)node * W + c0;
        if constexpr (sizeof(TO) == 2) {
            short8 pk;
#pragma unroll
            for (int j = 0; j < 8; ++j) pk[j] = bf16bits(r[j]);
            *(short8*)((bf16*)o + off) = pk;
        } else {
            float4 f0 = {r[0], r[1], r[2], r[3]};
            float4 f1 = {r[4], r[5], r[6], r[7]};
            *(float4*)((float*)o + off) = f0;
            *(float4*)((float*)o + off + 4) = f1;
        }
    };
    store_row(nA, accA);
    if (okB) store_row(nB, accB);
}

template <typename TO>
static void launch_gather6(const bf16* h, const float* dinv, const int* rowptr,
                           const int* col, TO* o, int n, int W,
                           const float* bias, int relu, hipStream_t stream) {
    dim3 b(64, 4);
    if (W == 128)
        k_gather6<TO, 16><<<cdiv(n, 32), b, 0, stream>>>(h, dinv, rowptr, col, o, n,
                                                         bias, relu);
    else
        k_gather6<TO, 8><<<cdiv(n, 64), b, 0, stream>>>(h, dinv, rowptr, col, o, n,
                                                        bias, relu);
}

// ---------------------------------------------------------------------------
// W pre-pack into MFMA fragment layout (bf16), all 8 weights in ONE launch:
//   Wb[((s*Mp) + n)*32 + kk] = W[s*32+kk][n]   (zero-padded k>=K or n>=M)
// ---------------------------------------------------------------------------
template <int K, int M, int Mp>
__device__ inline void wpack1(const float* __restrict__ W, bf16* __restrict__ o, int j) {
    int kk = j & 31;
    int rem = j >> 5;
    int ncol = rem % Mp;
    int s = rem / Mp;
    int k = s * 32 + kk;
    float v = (k < K && ncol < M) ? W[(size_t)k * M + ncol] : 0.f;
    o[j] = __float2bfloat16(v);
}

__global__ void k_wpack_all(const float* __restrict__ eW0, const float* __restrict__ eW1,
                            const float* __restrict__ eW2, const float* __restrict__ dW0,
                            const float* __restrict__ dW1, const float* __restrict__ dW2,
                            const float* __restrict__ sW0, const float* __restrict__ sW1,
                            bf16* __restrict__ arena) {
    for (int i = blockIdx.x * 256 + threadIdx.x; i < 159744; i += gridDim.x * 256) {
        if (i < 16384)       wpack1<38, 256, 256>(eW0, arena, i);
        else if (i < 49152)  wpack1<256, 128, 128>(eW1, arena + 16384, i - 16384);
        else if (i < 57344)  wpack1<128, 64, 64>(eW2, arena + 49152, i - 49152);
        else if (i < 65536)  wpack1<64, 128, 128>(dW0, arena + 57344, i - 57344);
        else if (i < 98304)  wpack1<128, 256, 256>(dW1, arena + 65536, i - 65536);
        else if (i < 110592) wpack1<256, 38, 48>(dW2, arena + 98304, i - 98304);
        else if (i < 126976) wpack1<38, 256, 256>(sW0, arena + 110592, i - 110592);
        else                 wpack1<256, 128, 128>(sW1, arena + 126976, i - 126976);
    }
}

// ---------------------------------------------------------------------------
// Fold global BN into weights:  W'[k,j] = sc[k]*W[k,j] packed to MFMA layout;
// b'[j] = -sum_k mu[k]*sc[k]*W[k,j]  (all fp32 math).  bn(A)@W == A@W' + b'.
// ---------------------------------------------------------------------------
template <int K, int M, int Mp>
__global__ void k_wfold(const float* __restrict__ W, const float* __restrict__ mu,
                        const float* __restrict__ sc, bf16* __restrict__ Wb,
                        float* __restrict__ bout) {
    const int tot = (K / 32) * Mp * 32;
    for (int i = blockIdx.x * 256 + threadIdx.x; i < tot; i += gridDim.x * 256) {
        int kk = i & 31;
        int rem = i >> 5;
        int ncol = rem % Mp;
        int s = rem / Mp;
        int k = s * 32 + kk;
        float v = (k < K && ncol < M) ? sc[k] * W[(size_t)k * M + ncol] : 0.f;
        Wb[i] = __float2bfloat16(v);
    }
    if (blockIdx.x == 0 && threadIdx.x < M) {
        int j = threadIdx.x;
        float s = 0.f;
        for (int k = 0; k < K; ++k) s -= mu[k] * sc[k] * W[(size_t)k * M + j];
        bout[j] = s;
    }
}

// ---------------------------------------------------------------------------
// MFMA GEMM v4:  C = act( bn(A) @ W + bias )
// R5 diagnosis: VGPR_Count=72 with a 64-VGPR accumulator meant at most TWO
// weight loads in flight — every wf load ran serially (load->vmcnt(0)->mfma),
// ~200-500cy each => everything-idle counters.  Fix: batch ALL S A-fragments
// and all NT weight fragments of one K-step into register arrays BEFORE the
// MFMAs (compiler emits counted vmcnt), and allow ~170 VGPR via
// __launch_bounds__(256,3).  Swapped operands: lane holds 4 consecutive
// output cols of one row -> packed stores.
//   BNM: 0 = none (global BN pre-folded into W); 2 = per-segment tables.
// ---------------------------------------------------------------------------
template <typename TC, int NT, int S, int BNM>
__global__ __launch_bounds__(256, 3) void k_mfma_gemm(
    const bf16* __restrict__ A, const bf16* __restrict__ Wb,
    TC* __restrict__ C, int M, int MC,
    const float* __restrict__ bias, int act,
    const float* __restrict__ mu, const float* __restrict__ sc,
    const int* __restrict__ seg)
{
    const int SA = S * 32;
    const int Mp = NT * 16;
    const int lane = threadIdx.x;
    const int wave = threadIdx.y;
    const int row0 = blockIdx.x * 64 + wave * 16;
    const int qr = lane >> 4;
    const int lc = lane & 15;

    // batch-load all A fragments (S loads in flight)
    short8 af[S];
    {
        const bf16* arow = A + (size_t)(row0 + lc) * SA + qr * 8;
#pragma unroll
        for (int s = 0; s < S; ++s) af[s] = *(const short8*)(arow + s * 32);
    }
    if (BNM == 2) {
        size_t bnbase = (size_t)seg[row0 + lc] * SA;
#pragma unroll
        for (int s = 0; s < S; ++s) {
            int kb = s * 32 + qr * 8;
            const float* mp = mu + bnbase + kb;
            const float* sp = sc + bnbase + kb;
            float4 m0 = *(const float4*)mp, m1 = *(const float4*)(mp + 4);
            float4 s0 = *(const float4*)sp, s1 = *(const float4*)(sp + 4);
            float av[8];
#pragma unroll
            for (int j = 0; j < 8; ++j) av[j] = bits2f(af[s][j]);
            av[0] = (av[0] - m0.x) * s0.x; av[1] = (av[1] - m0.y) * s0.y;
            av[2] = (av[2] - m0.z) * s0.z; av[3] = (av[3] - m0.w) * s0.w;
            av[4] = (av[4] - m1.x) * s1.x; av[5] = (av[5] - m1.y) * s1.y;
            av[6] = (av[6] - m1.z) * s1.z; av[7] = (av[7] - m1.w) * s1.w;
#pragma unroll
            for (int j = 0; j < 8; ++j) af[s][j] = bf16bits(av[j]);
        }
    }

    float4v acc[NT];
#pragma unroll
    for (int t = 0; t < NT; ++t) acc[t] = (float4v){0.f, 0.f, 0.f, 0.f};

    const bf16* wrow = Wb + (size_t)lc * 32 + qr * 8;
#pragma unroll
    for (int s = 0; s < S; ++s) {
        short8 wfv[NT];
#pragma unroll
        for (int t = 0; t < NT; ++t)
            wfv[t] = *(const short8*)(wrow + ((size_t)s * Mp + t * 16) * 32);
#pragma unroll
        for (int t = 0; t < NT; ++t)
            acc[t] = __builtin_amdgcn_mfma_f32_16x16x32_bf16(wfv[t], af[s], acc[t], 0, 0, 0);
    }

    const int row = row0 + lc;
#pragma unroll
    for (int t = 0; t < NT; ++t) {
        int c0 = t * 16 + qr * 4;
        if (c0 >= M) continue;
        float v[4];
#pragma unroll
        for (int r = 0; r < 4; ++r) v[r] = acc[t][r];
        if (bias) {
            if (c0 + 3 < M) {
                float4 bv = *(const float4*)(bias + c0);
                v[0] += bv.x; v[1] += bv.y; v[2] += bv.z; v[3] += bv.w;
            } else {
#pragma unroll
                for (int r = 0; r < 4; ++r) if (c0 + r < M) v[r] += bias[c0 + r];
            }
        }
#pragma unroll
        for (int r = 0; r < 4; ++r) {
            if (act == 1) v[r] = fmaxf(v[r], 0.f);
            else if (act == 2) v[r] = 1.f / (1.f + expf(-v[r]));
        }
        if (c0 + 3 < M) {
            if constexpr (sizeof(TC) == 2) {
                short4v pk = {bf16bits(v[0]), bf16bits(v[1]), bf16bits(v[2]), bf16bits(v[3])};
                *(short4v*)((bf16*)C + (size_t)row * MC + c0) = pk;
            } else {
                stf2((float*)C, ((size_t)row * MC + c0) >> 1, make_float2(v[0], v[1]));
                stf2((float*)C, ((size_t)row * MC + c0 + 2) >> 1, make_float2(v[2], v[3]));
            }
        } else {
#pragma unroll
            for (int r = 0; r < 4; ++r)
                if (c0 + r < M) stf(C, (size_t)row * MC + c0 + r, v[r]);
        }
    }
}

template <typename TC, int BNM>
static void launch_mfma(const bf16* A, const bf16* Wb, TC* C, int n, int SA,
                        int Mp, int M, int MC, const float* bias, int act,
                        const float* mu, const float* sc, const int* seg,
                        hipStream_t stream) {
    dim3 b(64, 4);
    int g = n / 64;
    if (SA == 64 && Mp == 256)
        k_mfma_gemm<TC, 16, 2, BNM><<<g, b, 0, stream>>>(A, Wb, C, M, MC, bias, act, mu, sc, seg);
    else if (SA == 256 && Mp == 128)
        k_mfma_gemm<TC, 8, 8, BNM><<<g, b, 0, stream>>>(A, Wb, C, M, MC, bias, act, mu, sc, seg);
    else if (SA == 128 && Mp == 64)
        k_mfma_gemm<TC, 4, 4, BNM><<<g, b, 0, stream>>>(A, Wb, C, M, MC, bias, act, mu, sc, seg);
}

// ---------------------------------------------------------------------------
// L0 stats: a0 = relu(Y0@W0+b0) recomputed IN REGISTERS (unswapped MFMA so a
// lane owns a column).  Batched weight loads in half-windows of 8.
// ---------------------------------------------------------------------------
__global__ __launch_bounds__(256, 3) void k_l0stats(
    const bf16* __restrict__ Y0, const bf16* __restrict__ W0b,
    const float* __restrict__ b0, float* __restrict__ sum,
    float* __restrict__ sumsq, int ntiles)
{
    __shared__ float ls[4][512];
    const int lane = threadIdx.x;
    const int wave = threadIdx.y;
    const int lc = lane & 15, qr = lane >> 4;

    float sReg[16], qReg[16];
#pragma unroll
    for (int t = 0; t < 16; ++t) { sReg[t] = 0.f; qReg[t] = 0.f; }

    for (int tile = blockIdx.x; tile < ntiles; tile += gridDim.x) {
        const int row0 = tile * 64 + wave * 16;
        const bf16* arow = Y0 + (size_t)(row0 + lc) * 64 + qr * 8;
        short8 af0 = *(const short8*)(arow);
        short8 af1 = *(const short8*)(arow + 32);
        float4v acc[16];
#pragma unroll
        for (int t = 0; t < 16; ++t) acc[t] = (float4v){0.f, 0.f, 0.f, 0.f};
#pragma unroll
        for (int s = 0; s < 2; ++s) {
            short8 af = s ? af1 : af0;
#pragma unroll
            for (int h = 0; h < 2; ++h) {
                short8 wfv[8];
#pragma unroll
                for (int tt = 0; tt < 8; ++tt) {
                    int t = h * 8 + tt;
                    wfv[tt] = *(const short8*)(W0b + ((size_t)(s * 256 + t * 16 + lc)) * 32 + qr * 8);
                }
#pragma unroll
                for (int tt = 0; tt < 8; ++tt) {
                    int t = h * 8 + tt;
                    // UNSWAPPED: lane owns col t*16+lc, rows qr*4+r
                    acc[t] = __builtin_amdgcn_mfma_f32_16x16x32_bf16(af, wfv[tt], acc[t], 0, 0, 0);
                }
            }
        }
#pragma unroll
        for (int t = 0; t < 16; ++t) {
            float bvt = b0[t * 16 + lc];
            float s4 = 0.f, q4 = 0.f;
#pragma unroll
            for (int r = 0; r < 4; ++r) {
                float v = fmaxf(acc[t][r] + bvt, 0.f);
                v = bits2f(bf16bits(v));     // match bf16-stored a0 semantics
                s4 += v;
                q4 += v * v;
            }
            s4 += __shfl_xor(s4, 16, 64); s4 += __shfl_xor(s4, 32, 64);
            q4 += __shfl_xor(q4, 16, 64); q4 += __shfl_xor(q4, 32, 64);
            sReg[t] += s4;
            qReg[t] += q4;
        }
    }
    if (lane < 16) {
#pragma unroll
        for (int t = 0; t < 16; ++t) {
            ls[wave][t * 16 + lc] = sReg[t];
            ls[wave][256 + t * 16 + lc] = qReg[t];
        }
    }
    __syncthreads();
    int tid = wave * 64 + lane;
    if (tid < 256) {
        atomicAdd(&sum[tid], ls[0][tid] + ls[1][tid] + ls[2][tid] + ls[3][tid]);
        atomicAdd(&sumsq[tid],
                  ls[0][256 + tid] + ls[1][256 + tid] + ls[2][256 + tid] + ls[3][256 + tid]);
    }
}

// ---------------------------------------------------------------------------
// Fused L0+L1: G1 = relu(Y0@W0+b0) @ W1' + b1'  — a0 never touches memory.
// Per-wave private XOR-swizzled LDS [16][256], zero barriers.  v2: batched
// register weight/activation loads (see k_mfma_gemm v4 note).
// ---------------------------------------------------------------------------
__global__ __launch_bounds__(256, 3) void k_fused01(
    const bf16* __restrict__ Y0, const bf16* __restrict__ W0b,
    const float* __restrict__ b0, const bf16* __restrict__ W1b,
    const float* __restrict__ b1f, bf16* __restrict__ G1, int n)
{
    __shared__ __attribute__((aligned(16))) char lds[4][8192];
    const int lane = threadIdx.x;
    const int wave = threadIdx.y;
    const int lc = lane & 15, qr = lane >> 4;
    const int row0 = blockIdx.x * 64 + wave * 16;
    char* r2 = lds[wave];            // [16][256] bf16, 512B/row
    const int swz = (lc & 7) << 4;

    // ---- phase 1: a0 = relu(Y0@W0 + b0), K=64 (S=2), 256 cols (NT=16) ----
    {
        const bf16* arow = Y0 + (size_t)(row0 + lc) * 64 + qr * 8;
        short8 af0 = *(const short8*)(arow);
        short8 af1 = *(const short8*)(arow + 32);
        float4v acc[16];
#pragma unroll
        for (int t = 0; t < 16; ++t) acc[t] = (float4v){0.f, 0.f, 0.f, 0.f};
#pragma unroll
        for (int s = 0; s < 2; ++s) {
            short8 af = s ? af1 : af0;
            short8 wfv[16];
#pragma unroll
            for (int t = 0; t < 16; ++t)
                wfv[t] = *(const short8*)(W0b + ((size_t)(s * 256 + t * 16 + lc)) * 32 + qr * 8);
#pragma unroll
            for (int t = 0; t < 16; ++t)
                acc[t] = __builtin_amdgcn_mfma_f32_16x16x32_bf16(wfv[t], af, acc[t], 0, 0, 0);
        }
#pragma unroll
        for (int t = 0; t < 16; ++t) {
            int c0 = t * 16 + qr * 4;
            float4 bv = *(const float4*)(b0 + c0);
            short4v pk = {bf16bits(fmaxf(acc[t][0] + bv.x, 0.f)),
                          bf16bits(fmaxf(acc[t][1] + bv.y, 0.f)),
                          bf16bits(fmaxf(acc[t][2] + bv.z, 0.f)),
                          bf16bits(fmaxf(acc[t][3] + bv.w, 0.f))};
            int off = lc * 512 + t * 32 + qr * 8;
            *(short4v*)(r2 + (off ^ swz)) = pk;
        }
    }

    // ---- phase 2: G1 = a0 @ W1' + b1', K=256 (S=8), 128 cols (NT=8) ----
    short8 afv[8];
#pragma unroll
    for (int s = 0; s < 8; ++s) {
        int off = lc * 512 + s * 64 + qr * 16;
        afv[s] = *(const short8*)(r2 + (off ^ swz));
    }
    float4v a2[8];
#pragma unroll
    for (int t = 0; t < 8; ++t) a2[t] = (float4v){0.f, 0.f, 0.f, 0.f};
#pragma unroll
    for (int s = 0; s < 8; ++s) {
        short8 wfv[8];
#pragma unroll
        for (int t = 0; t < 8; ++t)
            wfv[t] = *(const short8*)(W1b + ((size_t)(s * 128 + t * 16 + lc)) * 32 + qr * 8);
#pragma unroll
        for (int t = 0; t < 8; ++t)
            a2[t] = __builtin_amdgcn_mfma_f32_16x16x32_bf16(wfv[t], afv[s], a2[t], 0, 0, 0);
    }
    const int row = row0 + lc;
#pragma unroll
    for (int t = 0; t < 8; ++t) {
        int c0 = t * 16 + qr * 4;
        float4 bv = *(const float4*)(b1f + c0);
        short4v pk = {bf16bits(a2[t][0] + bv.x), bf16bits(a2[t][1] + bv.y),
                      bf16bits(a2[t][2] + bv.z), bf16bits(a2[t][3] + bv.w)};
        *(short4v*)(G1 + (size_t)row * 128 + c0) = pk;
    }
}

// ---------------------------------------------------------------------------
// Fused decoder: xrec = sigmoid(relu(relu(zb@dW0)@dW1)@dW2), one kernel.
// Per-wave private XOR-swizzled LDS slab, zero barriers.  v2: batched loads.
// ---------------------------------------------------------------------------
__global__ __launch_bounds__(256, 3) void k_decoder(
    const bf16* __restrict__ zb, const bf16* __restrict__ dW0b,
    const bf16* __restrict__ dW1b, const bf16* __restrict__ dW2b,
    float* __restrict__ xrec, int n)
{
    __shared__ __attribute__((aligned(16))) char lds[4][12288];
    const int lane = threadIdx.x;
    const int wave = threadIdx.y;
    const int lc = lane & 15, qr = lane >> 4;
    const int row0 = blockIdx.x * 64 + wave * 16;
    char* r1 = lds[wave];            // [16][128] bf16, 256B/row
    char* r2 = lds[wave] + 4096;     // [16][256] bf16, 512B/row
    const int swz = (lc & 7) << 4;

    // ---- layer 1: relu(zb @ dW0), K=64 (S=2), 128 cols (NT=8) ----
    {
        const bf16* arow = zb + (size_t)(row0 + lc) * 64 + qr * 8;
        short8 af0 = *(const short8*)(arow);
        short8 af1 = *(const short8*)(arow + 32);
        float4v a1[8];
#pragma unroll
        for (int t = 0; t < 8; ++t) a1[t] = (float4v){0.f, 0.f, 0.f, 0.f};
#pragma unroll
        for (int s = 0; s < 2; ++s) {
            short8 af = s ? af1 : af0;
            short8 wfv[8];
#pragma unroll
            for (int t = 0; t < 8; ++t)
                wfv[t] = *(const short8*)(dW0b + ((size_t)(s * 128 + t * 16 + lc)) * 32 + qr * 8);
#pragma unroll
            for (int t = 0; t < 8; ++t)
                a1[t] = __builtin_amdgcn_mfma_f32_16x16x32_bf16(wfv[t], af, a1[t], 0, 0, 0);
        }
#pragma unroll
        for (int t = 0; t < 8; ++t) {
            short4v pk = {bf16bits(fmaxf(a1[t][0], 0.f)), bf16bits(fmaxf(a1[t][1], 0.f)),
                          bf16bits(fmaxf(a1[t][2], 0.f)), bf16bits(fmaxf(a1[t][3], 0.f))};
            int off = lc * 256 + t * 32 + qr * 8;
            *(short4v*)(r1 + (off ^ swz)) = pk;
        }
    }

    // ---- layer 2: relu(r1 @ dW1), K=128 (S=4), 256 cols (NT=16) ----
    {
        short8 afv[4];
#pragma unroll
        for (int s = 0; s < 4; ++s) {
            int off = lc * 256 + s * 64 + qr * 16;
            afv[s] = *(const short8*)(r1 + (off ^ swz));
        }
        float4v a2[16];
#pragma unroll
        for (int t = 0; t < 16; ++t) a2[t] = (float4v){0.f, 0.f, 0.f, 0.f};
#pragma unroll
        for (int s = 0; s < 4; ++s) {
            short8 wfv[16];
#pragma unroll
            for (int t = 0; t < 16; ++t)
                wfv[t] = *(const short8*)(dW1b + ((size_t)(s * 256 + t * 16 + lc)) * 32 + qr * 8);
#pragma unroll
            for (int t = 0; t < 16; ++t)
                a2[t] = __builtin_amdgcn_mfma_f32_16x16x32_bf16(wfv[t], afv[s], a2[t], 0, 0, 0);
        }
#pragma unroll
        for (int t = 0; t < 16; ++t) {
            short4v pk = {bf16bits(fmaxf(a2[t][0], 0.f)), bf16bits(fmaxf(a2[t][1], 0.f)),
                          bf16bits(fmaxf(a2[t][2], 0.f)), bf16bits(fmaxf(a2[t][3], 0.f))};
            int off = lc * 512 + t * 32 + qr * 8;
            *(short4v*)(r2 + (off ^ swz)) = pk;
        }
    }

    // ---- layer 3: sigmoid(r2 @ dW2), K=256 (S=8), 38 cols (NT=3, Mp=48) ----
    short8 afv[8];
#pragma unroll
    for (int s = 0; s < 8; ++s) {
        int off = lc * 512 + s * 64 + qr * 16;
        afv[s] = *(const short8*)(r2 + (off ^ swz));
    }
    float4v a3[3];
#pragma unroll
    for (int t = 0; t < 3; ++t) a3[t] = (float4v){0.f, 0.f, 0.f, 0.f};
#pragma unroll
    for (int s = 0; s < 8; ++s) {
        short8 wfv[3];
#pragma unroll
        for (int t = 0; t < 3; ++t)
            wfv[t] = *(const short8*)(dW2b + ((size_t)(s * 48 + t * 16 + lc)) * 32 + qr * 8);
#pragma unroll
        for (int t = 0; t < 3; ++t)
            a3[t] = __builtin_amdgcn_mfma_f32_16x16x32_bf16(wfv[t], afv[s], a3[t], 0, 0, 0);
    }
    float* orow = xrec + (size_t)(row0 + lc) * 38;
#pragma unroll
    for (int t = 0; t < 3; ++t) {
        int c0 = t * 16 + qr * 4;
        float v0 = 1.f / (1.f + expf(-a3[t][0]));
        float v1 = 1.f / (1.f + expf(-a3[t][1]));
        float v2 = 1.f / (1.f + expf(-a3[t][2]));
        float v3 = 1.f / (1.f + expf(-a3[t][3]));
        if (c0 + 1 < 38) *(float2*)(orow + c0) = make_float2(v0, v1);
        if (c0 + 3 < 38) *(float2*)(orow + c0 + 2) = make_float2(v2, v3);
    }
}

// ---------------------------------------------------------------------------
// LDS-tiled fp32 vector GEMM (t-MLP / classifier — tiny n, precision-tight)
// ---------------------------------------------------------------------------
template <typename TA, typename TC, int NJ>
__global__ __launch_bounds__(256) void k_gemm(
    const TA* __restrict__ A, const float* __restrict__ W,
    TC* __restrict__ C, int n, int K, int M,
    const float* __restrict__ bias, int act,
    const float* __restrict__ mu, const float* __restrict__ sc)
{
    __shared__ float alds[64 * 32];
    __shared__ float wlds[32 * 256];
    const int l = threadIdx.x;
    const int wy = threadIdx.y;
    const int tid = wy * 64 + l;
    const int row0 = blockIdx.x * 64;

    float acc[16][NJ];
#pragma unroll
    for (int r = 0; r < 16; ++r)
#pragma unroll
        for (int j = 0; j < NJ; ++j) acc[r][j] = 0.f;

    int cidx[NJ]; bool jval[NJ];
#pragma unroll
    for (int j = 0; j < NJ; ++j) {
        cidx[j] = l + 64 * j;
        jval[j] = cidx[j] < M;
    }

    for (int k0 = 0; k0 < K; k0 += 32) {
        int kt = min(32, K - k0);
        __syncthreads();
        for (int i = tid; i < 64 * 32; i += 256) {
            int r = i >> 5, kk = i & 31;
            int row = row0 + r, k = k0 + kk;
            float v = (row < n && k < K) ? ldf(A, (size_t)row * K + k) : 0.f;
            if (mu && k < K) v = (v - mu[k]) * sc[k];
            alds[i] = v;
        }
        for (int i = tid; i < kt * M; i += 256)
            wlds[i] = W[(size_t)k0 * M + i];
        if (kt < 32)
            for (int i = kt * M + tid; i < 32 * M; i += 256) wlds[i] = 0.f;
        __syncthreads();

#pragma unroll 2
        for (int kkg = 0; kkg < 8; ++kkg) {
            float wv[4][NJ];
#pragma unroll
            for (int q = 0; q < 4; ++q)
#pragma unroll
                for (int j = 0; j < NJ; ++j)
                    wv[q][j] = jval[j] ? wlds[(kkg * 4 + q) * M + cidx[j]] : 0.f;
#pragma unroll
            for (int rr = 0; rr < 16; ++rr) {
                const float4* arow = (const float4*)&alds[(wy * 16 + rr) * 32];
                float4 av = arow[kkg];
#pragma unroll
                for (int j = 0; j < NJ; ++j) {
                    acc[rr][j] += av.x * wv[0][j];
                    acc[rr][j] += av.y * wv[1][j];
                    acc[rr][j] += av.z * wv[2][j];
                    acc[rr][j] += av.w * wv[3][j];
                }
            }
        }
    }

#pragma unroll
    for (int rr = 0; rr < 16; ++rr) {
        int row = row0 + wy * 16 + rr;
        if (row >= n) continue;
#pragma unroll
        for (int j = 0; j < NJ; ++j) {
            if (!jval[j]) continue;
            float v = acc[rr][j];
            if (bias) v += bias[cidx[j]];
            if (act == 1) v = fmaxf(v, 0.f);
            else if (act == 2) v = 1.f / (1.f + expf(-v));
            stf(C, (size_t)row * M + cidx[j], v);
        }
    }
}

// ---------------------------------------------------------------------------
// BatchNorm stats: vectorized 8-col loads, LDS-staged atomics.
// ---------------------------------------------------------------------------
template <typename T>
__global__ __launch_bounds__(256) void k_bn_stats8(
    const T* __restrict__ x, int n, int M,
    float* __restrict__ sum, float* __restrict__ sumsq)
{
    __shared__ float ls[512];
    int t = threadIdx.x;
    for (int i = t; i < 2 * M; i += 256) ls[i] = 0.f;
    __syncthreads();

    int gpr = M >> 3;           // col-groups per row
    int c8 = (t % gpr) * 8;
    int g = t / gpr;
    int rpb = 256 / gpr;

    float s[8], q[8];
#pragma unroll
    for (int j = 0; j < 8; ++j) { s[j] = 0.f; q[j] = 0.f; }

    for (int r = blockIdx.x * rpb + g; r < n; r += gridDim.x * rpb) {
        float v[8];
        if constexpr (sizeof(T) == 2) {
            short8 v8 = *(const short8*)((const bf16*)x + (size_t)r * M + c8);
#pragma unroll
            for (int j = 0; j < 8; ++j) v[j] = bits2f(v8[j]);
        } else {
            float4 f0 = *(const float4*)((const float*)x + (size_t)r * M + c8);
            float4 f1 = *(const float4*)((const float*)x + (size_t)r * M + c8 + 4);
            v[0] = f0.x; v[1] = f0.y; v[2] = f0.z; v[3] = f0.w;
            v[4] = f1.x; v[5] = f1.y; v[6] = f1.z; v[7] = f1.w;
        }
#pragma unroll
        for (int j = 0; j < 8; ++j) { s[j] += v[j]; q[j] += v[j] * v[j]; }
    }
#pragma unroll
    for (int j = 0; j < 8; ++j) {
        atomicAdd(&ls[c8 + j], s[j]);
        atomicAdd(&ls[M + c8 + j], q[j]);
    }
    __syncthreads();
    for (int i = t; i < M; i += 256) {
        atomicAdd(&sum[i], ls[i]);
        atomicAdd(&sumsq[i], ls[M + i]);
    }
}

__global__ void k_bn_fin(float* __restrict__ sum, float* __restrict__ sumsq, int n, int M) {
    int c = threadIdx.x;
    if (c < M) {
        float m = sum[c] / (float)n;
        float v = fmaxf(sumsq[c] / (float)n - m * m, 0.f);
        sum[c] = m;
        sumsq[c] = rsqrtf(v + BN_EPS);
    }
}

// ---------------------------------------------------------------------------
// Wave-per-segment BN stats (sorted seg, boundaries precomputed): writes
// mu/sc DIRECTLY.  No atomics, no zero-fill, no fin pass.  M = 64*CPL.
// ---------------------------------------------------------------------------
template <int CPL>
__global__ __launch_bounds__(256) void k_segbn(
    const bf16* __restrict__ x, const int* __restrict__ gstart, int nseg,
    float* __restrict__ mu, float* __restrict__ sc)
{
    const int M = 64 * CPL;
    int s = blockIdx.x * 4 + threadIdx.y;
    if (s >= nseg) return;
    int l = threadIdx.x;
    int gs = gstart[s], ge = gstart[s + 1];
    float sum[CPL], sq[CPL];
#pragma unroll
    for (int j = 0; j < CPL; ++j) { sum[j] = 0.f; sq[j] = 0.f; }
    for (int r = gs; r < ge; ++r) {
        const bf16* px = x + (size_t)r * M + l * CPL;
        if constexpr (CPL == 4) {
            short4v v4 = *(const short4v*)px;
#pragma unroll
            for (int j = 0; j < 4; ++j) {
                float v = bits2f(v4[j]);
                sum[j] += v; sq[j] += v * v;
            }
        } else {
            __hip_bfloat162 v2 = *(const __hip_bfloat162*)px;
            float v0 = __bfloat162float(v2.x), v1 = __bfloat162float(v2.y);
            sum[0] += v0; sq[0] += v0 * v0;
            sum[1] += v1; sq[1] += v1 * v1;
        }
    }
    float c = fmaxf((float)(ge - gs), 1.f);
#pragma unroll
    for (int j = 0; j < CPL; ++j) {
        float m = sum[j] / c;
        float v = fmaxf(sq[j] / c - m * m, 0.f);
        mu[(size_t)s * M + l * CPL + j] = m;
        sc[(size_t)s * M + l * CPL + j] = rsqrtf(v + BN_EPS);
    }
}

// ---------------------------------------------------------------------------
// Wave-per-segment mean pool over 64-col fp32 rows (input pre-normalized).
// ---------------------------------------------------------------------------
__global__ __launch_bounds__(256) void k_pool(
    const float* __restrict__ z, const int* __restrict__ gstart, int nseg,
    float* __restrict__ o)
{
    int s = blockIdx.x * 4 + threadIdx.y;
    if (s >= nseg) return;
    int l = threadIdx.x;
    int gs = gstart[s], ge = gstart[s + 1];
    float acc = 0.f;
    for (int r = gs; r < ge; ++r) acc += z[(size_t)r * 64 + l];
    o[(size_t)s * 64 + l] = acc / fmaxf((float)(ge - gs), 1.f);
}

// ---------------------------------------------------------------------------
// Wave-per-segment fused l2norm + mean pool (sub path: zs is only pooled).
// ---------------------------------------------------------------------------
__global__ __launch_bounds__(256) void k_l2pool(
    const float* __restrict__ zs, const int* __restrict__ gstart, int nseg,
    float* __restrict__ o)
{
    int s = blockIdx.x * 4 + threadIdx.y;
    if (s >= nseg) return;
    int l = threadIdx.x;
    int gs = gstart[s], ge = gstart[s + 1];
    float acc = 0.f;
    for (int r = gs; r < ge; ++r) {
        float v = zs[(size_t)r * 64 + l];
        float ss = v * v;
        for (int off = 32; off > 0; off >>= 1) ss += __shfl_xor(ss, off, 64);
        acc += v / fmaxf(sqrtf(ss), 1e-12f);
    }
    o[(size_t)s * 64 + l] = acc / fmaxf((float)(ge - gs), 1.f);
}

// ---------------------------------------------------------------------------
// Row L2 normalize, M = 64; writes fp32 in place + optional bf16 copy
// ---------------------------------------------------------------------------
__global__ void k_l2norm2(float* __restrict__ x, bf16* __restrict__ xb, int n) {
    int row = blockIdx.x * 4 + threadIdx.y;
    if (row >= n) return;
    int l = threadIdx.x;
    float v = x[(size_t)row * 64 + l];
    float ss = v * v;
    for (int o = 32; o > 0; o >>= 1) ss += __shfl_xor(ss, o, 64);
    float r = v / fmaxf(sqrtf(ss), 1e-12f);
    x[(size_t)row * 64 + l] = r;
    if (xb) xb[(size_t)row * 64 + l] = __float2bfloat16(r);
}

// ---------------------------------------------------------------------------
// Host-side vector-GEMM launch helper
// ---------------------------------------------------------------------------
template <typename TA, typename TC>
static void launch_gemm(const TA* A, const float* W, TC* C, int n, int K, int M,
                        const float* bias, int act, const float* mu, const float* sc,
                        hipStream_t stream) {
    dim3 b(64, 4);
    int g = cdiv(n, 64);
    int nj = (M + 63) >> 6;
    if (nj >= 4)      k_gemm<TA, TC, 4><<<g, b, 0, stream>>>(A, W, C, n, K, M, bias, act, mu, sc);
    else if (nj == 2) k_gemm<TA, TC, 2><<<g, b, 0, stream>>>(A, W, C, n, K, M, bias, act, mu, sc);
    else              k_gemm<TA, TC, 1><<<g, b, 0, stream>>>(A, W, C, n, K, M, bias, act, mu, sc);
}

// ---------------------------------------------------------------------------
// Host launch
// ---------------------------------------------------------------------------
extern "C" void kernel_launch(void* const* d_in, const int* in_sizes, int n_in,
                              void* d_out, int out_size, void* d_ws, size_t ws_size,
                              hipStream_t stream) {
    const float* x        = (const float*)d_in[0];
    const int*   ei       = (const int*)  d_in[1];
    const int*   batch    = (const int*)  d_in[2];
    const float* target_x = (const float*)d_in[3];
    const float* pos_x    = (const float*)d_in[4];
    const int*   pos_ei   = (const int*)  d_in[5];
    const int*   pos_b    = (const int*)  d_in[6];
    const float* neg_x    = (const float*)d_in[7];
    const int*   neg_ei   = (const int*)  d_in[8];
    const int*   neg_b    = (const int*)  d_in[9];
    const float* enc_W0 = (const float*)d_in[10]; const float* enc_b0 = (const float*)d_in[11];
    const float* enc_W1 = (const float*)d_in[12]; const float* enc_b1 = (const float*)d_in[13];
    const float* enc_W2 = (const float*)d_in[14]; const float* enc_b2 = (const float*)d_in[15];
    const float* dec_W0 = (const float*)d_in[16];
    const float* dec_W1 = (const float*)d_in[17];
    const float* dec_W2 = (const float*)d_in[18];
    const float* node_W0 = (const float*)d_in[19]; const float* node_b0 = (const float*)d_in[20];
    const float* node_W1 = (const float*)d_in[21]; const float* node_b1 = (const float*)d_in[22];
    const float* node_W2 = (const float*)d_in[23]; const float* node_b2 = (const float*)d_in[24];
    const float* sub_W0 = (const float*)d_in[25]; const float* sub_b0 = (const float*)d_in[26];
    const float* sub_W1 = (const float*)d_in[27]; const float* sub_b1 = (const float*)d_in[28];
    const float* cls_W0 = (const float*)d_in[29]; const float* cls_b0 = (const float*)d_in[30];
    const float* cls_W1 = (const float*)d_in[31]; const float* cls_b1 = (const float*)d_in[32];
    const float* cls_W2 = (const float*)d_in[33]; const float* cls_b2 = (const float*)d_in[34];

    float* out = (float*)d_out;
    const size_t OFF_XREC  = 0;
    const size_t OFF_ZPOOL = (size_t)N_NODES * F_IN;
    const size_t OFF_TZ    = OFF_ZPOOL + (size_t)N_GRAPHS * H2;
    const size_t OFF_PPOOL = OFF_TZ    + (size_t)N_GRAPHS * H2;
    const size_t OFF_NPOOL = OFF_PPOOL + (size_t)N_GRAPHS * H2;
    const size_t OFF_PRED  = OFF_NPOOL + (size_t)N_GRAPHS * H2;

    // ----- workspace carve-up (by floats; total ~207 MB) -----
    char* wsp = (char*)d_ws;
    auto alloc = [&](size_t nfloats) -> float* {
        float* p = (float*)wsp;
        wsp += ((nfloats + 63) / 64) * 64 * sizeof(float);
        return p;
    };
    float* R1     = alloc((size_t)N_NODES * 128);   // fp32 N*128 / bf16 N*256
    float* R2     = alloc((size_t)N_NODES * 128);
    float* dinv   = alloc(N_NODES);
    int*   cnt    = (int*)alloc(N_NODES);           // degree, then reused as cursor
    int*   rowptr = (int*)alloc(N_NODES + 1);
    int*   bsum   = (int*)alloc(1024);
    int*   ccol   = (int*)alloc(N_EDGES);
    float* ssum   = alloc(256);
    float* ssumsq = alloc(256);   // contiguous with ssum
    bf16*  wpk    = (bf16*)alloc(101 * 1024);  // 206848-bf16 arena, 200704 used
    float* bfold  = alloc(256);   // folded biases: b1' [0..128), b2' [128..192)
    (void)ws_size; (void)in_sizes; (void)n_in; (void)out_size;

    // packed-weight arena offsets (bf16 elements): S*Mp*32 each
    bf16* eW0b = wpk;            // K38->S2,  Mp256: 16384
    bf16* eW1b = eW0b + 16384;   // K256->S8, Mp128: 32768 (unused; layout keep)
    bf16* eW2b = eW1b + 32768;   // K128->S4, Mp64 :  8192
    bf16* dW0b = eW2b + 8192;    // K64->S2,  Mp128:  8192
    bf16* dW1b = dW0b + 8192;    // K128->S4, Mp256: 32768
    bf16* dW2b = dW1b + 32768;   // K256->S8, Mp48 : 12288
    bf16* sW0b = dW2b + 12288;   // K38->S2,  Mp256: 16384
    bf16* sW1b = sW0b + 16384;   // K256->S8, Mp128: 32768
    bf16* fW1b = sW1b + 32768;   // folded enc_W1': K256, Mp128: 32768
    bf16* fW2b = fW1b + 32768;   // folded enc_W2': K128, Mp64 :  8192

    // ----- R2-tail carve (no new allocs).
    float* tailf    = R2 + (size_t)16 * 1024 * 1024;          // 64 MB offset
    float* segsumM  = tailf;                                  // mu  4096*256
    float* segsumqM = tailf + (size_t)1048576;                // sc  4096*256
    float* mx       = tailf + (size_t)2097152;                // 2*N_SUB*F_IN fp32
    int*   msrc     = (int*)(mx + (size_t)2 * N_SUB * F_IN);  // 2*E_SUB
    int*   mdst     = msrc + 2 * E_SUB;                       // 2*E_SUB
    int*   mb       = mdst + 2 * E_SUB;                       // 2*N_SUB
    int*   gstartM  = mb + 2 * N_SUB;                         // 4097 ints (sub)
    int*   gstart2k = gstartM + 4112;                         // 2049 ints (main)

    dim3 b64x4(64, 4);
    auto zero = [&](void* p, size_t nfloats) {
        k_zero<<<cdiv((int)nfloats, 256), 256, 0, stream>>>((float*)p, (int)nfloats);
    };

    // pack all 8 weights in one launch (seg-BN fused at GEMM A-load;
    // global BN folded into W via k_wfold after stats)
    k_wpack_all<<<624, 256, 0, stream>>>(enc_W0, enc_W1, enc_W2, dec_W0, dec_W1,
                                         dec_W2, sub_W0, sub_W1, wpk);

    auto build_graph = [&](const int* srcp, const int* dstp, int n, int e) {
        zero(cnt, n);
        k_count<<<cdiv(e, 256), 256, 0, stream>>>(dstp, cnt, e);
        k_dinv<<<cdiv(n, 256), 256, 0, stream>>>(cnt, dinv, n);
        int nb = cdiv(n, 256);
        k_scan_sum<<<nb, 256, 0, stream>>>(cnt, bsum, n);
        k_scan_top<<<1, 1024, 0, stream>>>(bsum, nb);
        k_scan_apply<<<nb, 256, 0, stream>>>(cnt, bsum, rowptr, n);
        zero(cnt, n);  // cnt now serves as the fill cursor
        k_fill<<<cdiv(e, 256), 256, 0, stream>>>(srcp, dstp, rowptr, cnt, ccol, e);
    };

    auto bn_stats = [&](auto* xx, int n, int M) {
        zero(ssum, 512);  // ssum+ssumsq contiguous
        int rpb = 256 / (M >> 3);
        int g = min(512, cdiv(n, rpb));
        k_bn_stats8<<<g, 256, 0, stream>>>(xx, n, M, ssum, ssumsq);
        k_bn_fin<<<1, 256, 0, stream>>>(ssum, ssumsq, n, M);
    };

    // ============ main graph encode (fused L0+L1, BN folded into W) ============
    build_graph(ei, ei + N_EDGES, N_NODES, N_EDGES);

    // Y0 = A_hat * x  (bf16 N x 64, K-pad 38->64)  — in R1 (fused01 writes R2)
    bf16* Y0 = (bf16*)R1;
    launch_gather<float, bf16>(x, dinv, rowptr, ccol, Y0, N_NODES, F_IN, 64,
                               nullptr, 0, stream);

    // a0 stats computed in-register from Y0 (a0 never materialized)
    zero(ssum, 512);
    k_l0stats<<<512, b64x4, 0, stream>>>(Y0, eW0b, enc_b0, ssum, ssumsq,
                                         N_NODES / 64);
    k_bn_fin<<<1, 256, 0, stream>>>(ssum, ssumsq, N_NODES, H0);
    k_wfold<256, 128, 128><<<128, 256, 0, stream>>>(enc_W1, ssum, ssumsq, fW1b, bfold);

    // Fused L0+L1: G1 = relu(Y0@W0+b0) @ W1' + b1'
    bf16* G1 = (bf16*)R2;
    k_fused01<<<N_NODES / 64, b64x4, 0, stream>>>(Y0, eW0b, enc_b0, fW1b, bfold,
                                                  G1, N_NODES);

    // a1 = relu(A_hat*G1 + b1)   (Y0 dead -> a1 in R1)
    bf16* a1 = (bf16*)R1;
    launch_gather6<bf16>(G1, dinv, rowptr, ccol, a1, N_NODES, 128, enc_b1, 1, stream);
    bn_stats(a1, N_NODES, H1);
    k_wfold<128, 64, 64><<<32, 256, 0, stream>>>(enc_W2, ssum, ssumsq, fW2b, bfold + 128);

    // Layer 2: G2 = a1@W2' + b2'; z = A_hat*G2 + b2, l2norm
    bf16* G2 = (bf16*)R2;
    launch_mfma<bf16, 0>(a1, fW2b, G2, N_NODES, 128, 64, H2, H2, bfold + 128, 0,
                         nullptr, nullptr, nullptr, stream);
    float* z  = R1;
    bf16*  zb = (bf16*)(R1 + (size_t)N_NODES * 64);
    launch_gather6<float>(G2, dinv, rowptr, ccol, z, N_NODES, 64, enc_b2, 0, stream);
    k_l2norm2<<<cdiv(N_NODES, 4), b64x4, 0, stream>>>(z, zb, N_NODES);

    // z_pool (boundaries from sorted batch; wave-per-segment mean)
    k_gbound<<<cdiv(N_NODES, 256), 256, 0, stream>>>(batch, N_NODES, N_GRAPHS, gstart2k);
    k_pool<<<cdiv(N_GRAPHS, 4), b64x4, 0, stream>>>(z, gstart2k, N_GRAPHS,
                                                    out + OFF_ZPOOL);

    // ===================== decode: single fused kernel =====================
    k_decoder<<<N_NODES / 64, b64x4, 0, stream>>>(zb, dW0b, dW1b, dW2b,
                                                  out + OFF_XREC, N_NODES);

    // ===================== target node MLP (fp32 vector) =====================
    float* t0 = R2;  // 2048 x 256
    launch_gemm<float, float>(target_x, node_W0, t0, N_GRAPHS, F_IN, H0, node_b0, 1,
                              nullptr, nullptr, stream);
    bn_stats(t0, N_GRAPHS, H0);
    float* t1 = R1;  // 2048 x 128
    launch_gemm<float, float>(t0, node_W1, t1, N_GRAPHS, H0, H1, node_b1, 1,
                              ssum, ssumsq, stream);
    bn_stats(t1, N_GRAPHS, H1);
    launch_gemm<float, float>(t1, node_W2, out + OFF_TZ, N_GRAPHS, H1, H2, node_b2, 0,
                              ssum, ssumsq, stream);
    k_l2norm2<<<cdiv(N_GRAPHS, 4), b64x4, 0, stream>>>(out + OFF_TZ, nullptr, N_GRAPHS);

    // ========== merged pos+neg subgraph pipeline (one batched pass) ==========
    k_merge<<<2048, 256, 0, stream>>>(pos_x, neg_x, pos_ei, neg_ei, pos_b, neg_b,
                                      mx, msrc, mdst, mb);
    const int NS2 = 2 * N_SUB, ES2 = 2 * E_SUB, NG2 = 2 * N_GRAPHS;
    build_graph(msrc, mdst, NS2, ES2);
    k_gbound<<<cdiv(NS2, 256), 256, 0, stream>>>(mb, NS2, NG2, gstartM);

    // Layer 0: Ys = A_hat*mx (bf16, pad 38->64); as0 = relu(Ys@sW0 + b)
    bf16* Ys = (bf16*)R2;
    launch_gather<float, bf16>(mx, dinv, rowptr, ccol, Ys, NS2, F_IN, 64,
                               nullptr, 0, stream);
    bf16* as0 = (bf16*)R1;  // 65536 x 256
    launch_mfma<bf16, 0>(Ys, sW0b, as0, NS2, 64, 256, H0, H0, sub_b0, 1,
                         nullptr, nullptr, nullptr, stream);
    k_segbn<4><<<cdiv(NG2, 4), b64x4, 0, stream>>>(as0, gstartM, NG2,
                                                   segsumM, segsumqM);

    // Layer 1: Gs1 = segbn(as0)@sW1; as1 = relu(A_hat*Gs1 + b1)
    bf16* Gs1 = (bf16*)R2;  // 65536 x 128
    launch_mfma<bf16, 2>(as0, sW1b, Gs1, NS2, 256, 128, H1, H1, nullptr, 0,
                         segsumM, segsumqM, mb, stream);
    bf16* as1 = (bf16*)R1;  // 65536 x 128
    launch_gather6<bf16>(Gs1, dinv, rowptr, ccol, as1, NS2, 128, sub_b1, 1, stream);
    k_segbn<2><<<cdiv(NG2, 4), b64x4, 0, stream>>>(as1, gstartM, NG2,
                                                   segsumM, segsumqM);

    // Layer 2: Gs2 = segbn(as1)@encW2; zs = A_hat*Gs2 + b2; fused l2norm+pool
    bf16* Gs2 = (bf16*)R2;  // 65536 x 64
    launch_mfma<bf16, 2>(as1, eW2b, Gs2, NS2, 128, 64, H2, H2, nullptr, 0,
                         segsumM, segsumqM, mb, stream);
    float* zs = R1;  // 65536 x 64 fp32
    launch_gather6<float>(Gs2, dinv, rowptr, ccol, zs, NS2, 64, enc_b2, 0, stream);
    k_l2pool<<<cdiv(NG2, 4), b64x4, 0, stream>>>(zs, gstartM, NG2, out + OFF_PPOOL);

    // ===================== classifier on neg_pool (fp32 vector) =====================
    float* c1 = R2;
    launch_gemm<float, float>(out + OFF_NPOOL, cls_W0, c1, N_GRAPHS, H2, H1, cls_b0, 1,
                              nullptr, nullptr, stream);
    float* c2 = R1;
    launch_gemm<float, float>(c1, cls_W1, c2, N_GRAPHS, H1, 16, cls_b1, 1,
                              nullptr, nullptr, stream);
    launch_gemm<float, float>(c2, cls_W2, out + OFF_PRED, N_GRAPHS, 16, 1, cls_b2, 2,
                              nullptr, nullptr, stream);
}

// Round 7
// 1177.943 us; speedup vs baseline: 1.1426x; 1.1426x over previous
//
#include <hip/hip_runtime.h>
#include <hip/hip_bf16.h>
#include <math.h>

// ---------------------------------------------------------------------------
// Problem constants (from reference)
// ---------------------------------------------------------------------------
#define N_NODES  200000
#define N_EDGES  800000
#define N_GRAPHS 2048
#define N_SUB    32768
#define E_SUB    131072
#define F_IN     38
#define H0       256
#define H1       128
#define H2       64
#define BN_EPS   1e-5f

typedef __hip_bfloat16 bf16;
typedef __attribute__((ext_vector_type(8))) short short8;
typedef __attribute__((ext_vector_type(4))) short short4v;
typedef __attribute__((ext_vector_type(4))) float float4v;

static __host__ __device__ inline int cdiv(int a, int b) { return (a + b - 1) / b; }

__device__ inline float ldf(const float* p, size_t i) { return p[i]; }
__device__ inline float ldf(const bf16* p, size_t i)  { return __bfloat162float(p[i]); }
__device__ inline void  stf(float* p, size_t i, float v) { p[i] = v; }
__device__ inline void  stf(bf16* p, size_t i, float v)  { p[i] = __float2bfloat16(v); }

__device__ inline float2 ldf2(const float* p, size_t i) { return ((const float2*)p)[i]; }
__device__ inline float2 ldf2(const bf16* p, size_t i) {
    __hip_bfloat162 v = ((const __hip_bfloat162*)p)[i];
    return make_float2(__bfloat162float(v.x), __bfloat162float(v.y));
}
__device__ inline void stf2(float* p, size_t i, float2 v) { ((float2*)p)[i] = v; }
__device__ inline void stf2(bf16* p, size_t i, float2 v) {
    __hip_bfloat162 t;
    t.x = __float2bfloat16(v.x);
    t.y = __float2bfloat16(v.y);
    ((__hip_bfloat162*)p)[i] = t;
}

__device__ inline short bf16bits(float v) {
    bf16 t = __float2bfloat16(v);
    return *reinterpret_cast<short*>(&t);
}
__device__ inline float bits2f(short s) {
    return __bfloat162float(*reinterpret_cast<const bf16*>(&s));
}

// ---------------------------------------------------------------------------
// Zero fill (graph-capture-safe replacement for hipMemsetAsync)
// ---------------------------------------------------------------------------
__global__ void k_zero(float* __restrict__ p, int n) {
    int i = blockIdx.x * 256 + threadIdx.x;
    if (i < n) p[i] = 0.f;
}

// ---------------------------------------------------------------------------
// Graph preprocessing: degree, CSR build
// ---------------------------------------------------------------------------
__global__ void k_count(const int* __restrict__ dst, int* __restrict__ cnt, int e) {
    int i = blockIdx.x * 256 + threadIdx.x;
    if (i < e) atomicAdd(&cnt[dst[i]], 1);
}

__global__ void k_dinv(const int* __restrict__ cnt, float* __restrict__ dinv, int n) {
    int i = blockIdx.x * 256 + threadIdx.x;
    if (i < n) dinv[i] = rsqrtf(1.0f + (float)cnt[i]);
}

__global__ void k_scan_sum(const int* __restrict__ cnt, int* __restrict__ bsum, int n) {
    __shared__ int tmp[256];
    int t = threadIdx.x;
    int i = blockIdx.x * 256 + t;
    tmp[t] = (i < n) ? cnt[i] : 0;
    __syncthreads();
    for (int off = 128; off > 0; off >>= 1) {
        if (t < off) tmp[t] += tmp[t + off];
        __syncthreads();
    }
    if (t == 0) bsum[blockIdx.x] = tmp[0];
}

__global__ void k_scan_top(int* __restrict__ bsum, int nb) {
    __shared__ int tmp[1024];
    int t = threadIdx.x;
    int v = (t < nb) ? bsum[t] : 0;
    tmp[t] = v;
    __syncthreads();
    for (int off = 1; off < 1024; off <<= 1) {
        int a = (t >= off) ? tmp[t - off] : 0;
        __syncthreads();
        tmp[t] += a;
        __syncthreads();
    }
    if (t < nb) bsum[t] = tmp[t] - v;  // exclusive
}

__global__ void k_scan_apply(const int* __restrict__ cnt, const int* __restrict__ bsum,
                             int* __restrict__ rowptr, int n) {
    __shared__ int tmp[256];
    int t = threadIdx.x;
    int i = blockIdx.x * 256 + t;
    int v = (i < n) ? cnt[i] : 0;
    tmp[t] = v;
    __syncthreads();
    for (int off = 1; off < 256; off <<= 1) {
        int a = (t >= off) ? tmp[t - off] : 0;
        __syncthreads();
        tmp[t] += a;
        __syncthreads();
    }
    int excl = tmp[t] - v + bsum[blockIdx.x];
    if (i < n) rowptr[i] = excl;
    if (i == n - 1) rowptr[n] = excl + v;
}

// cursor aliases the (consumed) cnt buffer — re-zeroed before this kernel.
__global__ void k_fill(const int* __restrict__ src, const int* __restrict__ dst,
                       const int* __restrict__ rowptr, int* __restrict__ cursor,
                       int* __restrict__ col, int e) {
    int i = blockIdx.x * 256 + threadIdx.x;
    if (i < e) {
        int d = dst[i];
        int p = rowptr[d] + atomicAdd(&cursor[d], 1);
        col[p] = src[i];
    }
}

// ---------------------------------------------------------------------------
// Segment boundaries from a SORTED segment array.
// ---------------------------------------------------------------------------
__global__ void k_gbound(const int* __restrict__ seg, int n, int nseg,
                         int* __restrict__ gstart) {
    int i = blockIdx.x * 256 + threadIdx.x;
    if (i >= n) return;
    int s = seg[i];
    if (i == 0) {
        for (int g = 0; g <= s; ++g) gstart[g] = 0;
    } else {
        int p = seg[i - 1];
        for (int g = p + 1; g <= s; ++g) gstart[g] = i;
    }
    if (i == n - 1) {
        for (int g = s + 1; g <= nseg; ++g) gstart[g] = n;
    }
}

// ---------------------------------------------------------------------------
// Merge pos/neg subgraph inputs into one batched problem.
// ---------------------------------------------------------------------------
__global__ void k_merge(const float* __restrict__ px, const float* __restrict__ nx,
                        const int* __restrict__ pei, const int* __restrict__ nei,
                        const int* __restrict__ pb, const int* __restrict__ nbt,
                        float* __restrict__ mx, int* __restrict__ msrc,
                        int* __restrict__ mdst, int* __restrict__ mb) {
    int stride = gridDim.x * 256;
    for (int i = blockIdx.x * 256 + threadIdx.x; i < N_SUB * F_IN; i += stride) {
        mx[i] = px[i];
        mx[(size_t)N_SUB * F_IN + i] = nx[i];
    }
    for (int i = blockIdx.x * 256 + threadIdx.x; i < E_SUB; i += stride) {
        msrc[i] = pei[i];
        mdst[i] = pei[E_SUB + i];
        msrc[E_SUB + i] = nei[i] + N_SUB;
        mdst[E_SUB + i] = nei[E_SUB + i] + N_SUB;
    }
    for (int i = blockIdx.x * 256 + threadIdx.x; i < N_SUB; i += stride) {
        mb[i] = pb[i];
        mb[N_SUB + i] = nbt[i] + N_GRAPHS;
    }
}

// ---------------------------------------------------------------------------
// Gather v5 (dual-chain rotated pipeline; float2/lane).  Kept for the two
// fp32-input layer-0 sites (M=38).
// ---------------------------------------------------------------------------
template <typename TI, typename TO, int PPN>
__global__ __launch_bounds__(256) void k_gather5(
    const TI* __restrict__ h, const float* __restrict__ dinv,
    const int* __restrict__ rowptr, const int* __restrict__ col,
    TO* __restrict__ o, int n, int M2, int S2,
    const float* __restrict__ bias, int relu)
{
    const int NPW = 64 / PPN;  // lane-groups per wave
    int g0 = threadIdx.x / PPN;
    int pr = threadIdx.x % PPN;
    int nA = (blockIdx.x * 4 + threadIdx.y) * (2 * NPW) + g0 * 2;
    if (nA >= n) return;
    int nB = nA + 1;
    bool okB = nB < n;
    bool pld = pr < M2, pst = pr < S2;

    int2 rp = *(const int2*)(rowptr + nA);
    float diA = dinv[nA];
    float diB = okB ? dinv[nB] : 0.f;
    float2 vsA = make_float2(0.f, 0.f), vsB = make_float2(0.f, 0.f);
    if (pld) {
        vsA = ldf2(h, (size_t)nA * M2 + pr);
        if (okB) vsB = ldf2(h, (size_t)nB * M2 + pr);
    }
    int peB = okB ? rowptr[nA + 2] : rp.y;

    int pA = rp.x, peA = rp.y;
    int pB = peA;  // rowptr[nB] == rowptr[nA+1]

    int sA1 = 0, sB1 = 0;
    float dA0 = 0.f, dB0 = 0.f;
    float2 vA0 = make_float2(0.f, 0.f), vB0 = make_float2(0.f, 0.f);

    if (pA < peA) {
        int s0 = col[pA];
        sA1 = (pA + 1 < peA) ? col[pA + 1] : 0;
        dA0 = dinv[s0];
        if (pld) vA0 = ldf2(h, (size_t)s0 * M2 + pr);
    }
    if (pB < peB) {
        int s0 = col[pB];
        sB1 = (pB + 1 < peB) ? col[pB + 1] : 0;
        dB0 = dinv[s0];
        if (pld) vB0 = ldf2(h, (size_t)s0 * M2 + pr);
    }

    float2 accA, accB;
    accA.x = diA * diA * vsA.x; accA.y = diA * diA * vsA.y;
    accB.x = diB * diB * vsB.x; accB.y = diB * diB * vsB.y;

    while (pA < peA && pB < peB) {
        int sA2 = (pA + 2 < peA) ? col[pA + 2] : 0;
        int sB2 = (pB + 2 < peB) ? col[pB + 2] : 0;
        float2 vA1 = (pA + 1 < peA && pld) ? ldf2(h, (size_t)sA1 * M2 + pr)
                                           : make_float2(0.f, 0.f);
        float2 vB1 = (pB + 1 < peB && pld) ? ldf2(h, (size_t)sB1 * M2 + pr)
                                           : make_float2(0.f, 0.f);
        float dA1 = (pA + 1 < peA) ? dinv[sA1] : 0.f;
        float dB1 = (pB + 1 < peB) ? dinv[sB1] : 0.f;
        float cfA = dA0 * diA, cfB = dB0 * diB;
        accA.x += cfA * vA0.x; accA.y += cfA * vA0.y;
        accB.x += cfB * vB0.x; accB.y += cfB * vB0.y;
        sA1 = sA2; vA0 = vA1; dA0 = dA1;
        sB1 = sB2; vB0 = vB1; dB0 = dB1;
        ++pA; ++pB;
    }
    while (pA < peA) {
        int sA2 = (pA + 2 < peA) ? col[pA + 2] : 0;
        float2 vA1 = (pA + 1 < peA && pld) ? ldf2(h, (size_t)sA1 * M2 + pr)
                                           : make_float2(0.f, 0.f);
        float dA1 = (pA + 1 < peA) ? dinv[sA1] : 0.f;
        float cfA = dA0 * diA;
        accA.x += cfA * vA0.x; accA.y += cfA * vA0.y;
        sA1 = sA2; vA0 = vA1; dA0 = dA1; ++pA;
    }
    while (pB < peB) {
        int sB2 = (pB + 2 < peB) ? col[pB + 2] : 0;
        float2 vB1 = (pB + 1 < peB && pld) ? ldf2(h, (size_t)sB1 * M2 + pr)
                                           : make_float2(0.f, 0.f);
        float dB1 = (pB + 1 < peB) ? dinv[sB1] : 0.f;
        float cfB = dB0 * diB;
        accB.x += cfB * vB0.x; accB.y += cfB * vB0.y;
        sB1 = sB2; vB0 = vB1; dB0 = dB1; ++pB;
    }

    if (pst) {
        float2 rA = accA;
        if (bias && pld) { rA.x += bias[2 * pr]; rA.y += bias[2 * pr + 1]; }
        if (relu) { rA.x = fmaxf(rA.x, 0.f); rA.y = fmaxf(rA.y, 0.f); }
        stf2(o, (size_t)nA * S2 + pr, rA);
        if (okB) {
            float2 rB = accB;
            if (bias && pld) { rB.x += bias[2 * pr]; rB.y += bias[2 * pr + 1]; }
            if (relu) { rB.x = fmaxf(rB.x, 0.f); rB.y = fmaxf(rB.y, 0.f); }
            stf2(o, (size_t)nB * S2 + pr, rB);
        }
    }
}

template <typename TI, typename TO>
static void launch_gather(const TI* h, const float* dinv, const int* rowptr,
                          const int* col, TO* o, int n, int M, int Sout,
                          const float* bias, int relu, hipStream_t stream) {
    dim3 b(64, 4);
    int M2 = M >> 1, S2 = Sout >> 1;
    if (S2 > 32)
        k_gather5<TI, TO, 64><<<cdiv(n, 8), b, 0, stream>>>(h, dinv, rowptr, col, o,
                                                            n, M2, S2, bias, relu);
    else
        k_gather5<TI, TO, 32><<<cdiv(n, 16), b, 0, stream>>>(h, dinv, rowptr, col, o,
                                                             n, M2, S2, bias, relu);
}

// ---------------------------------------------------------------------------
// Gather v6 (bf16 in, 16 B/lane): LPR lanes cover one row (LPR*8 = W cols),
// 64/LPR dual-chain lane-groups per wave; rotated pipeline.
// ---------------------------------------------------------------------------
template <typename TO, int LPR>
__global__ __launch_bounds__(256) void k_gather6(
    const bf16* __restrict__ h, const float* __restrict__ dinv,
    const int* __restrict__ rowptr, const int* __restrict__ col,
    TO* __restrict__ o, int n, const float* __restrict__ bias, int relu)
{
    const int W = LPR * 8;
    const int NG = 64 / LPR;
    const int g = threadIdx.x / LPR;
    const int c0 = (threadIdx.x % LPR) * 8;
    const int nA = (blockIdx.x * 4 + threadIdx.y) * (2 * NG) + g * 2;
    const int nB = nA + 1;
    if (nA >= n) return;           // group-uniform
    const bool okB = nB < n;

    int2 rp = *(const int2*)(rowptr + nA);
    int peB = okB ? rowptr[nB + 1] : rp.y;
    float diA = dinv[nA];
    float diB = okB ? dinv[nB] : 0.f;
    short8 zed = {0, 0, 0, 0, 0, 0, 0, 0};
    short8 slA = *(const short8*)(h + (size_t)nA * W + c0);
    short8 slB = okB ? *(const short8*)(h + (size_t)nB * W + c0) : zed;

    int pA = rp.x, peA = rp.y;
    int pB = rp.y;

    float accA[8], accB[8];
    float qA = diA * diA, qB = diB * diB;
#pragma unroll
    for (int j = 0; j < 8; ++j) {
        accA[j] = qA * bits2f(slA[j]);
        accB[j] = qB * bits2f(slB[j]);
    }

    // rotated pipeline state
    int sA1 = 0, sB1 = 0;
    float dA0 = 0.f, dB0 = 0.f;
    short8 vA0 = zed, vB0 = zed;
    if (pA < peA) {
        int s0 = col[pA];
        sA1 = (pA + 1 < peA) ? col[pA + 1] : 0;
        dA0 = dinv[s0];
        vA0 = *(const short8*)(h + (size_t)s0 * W + c0);
    }
    if (pB < peB) {
        int s0 = col[pB];
        sB1 = (pB + 1 < peB) ? col[pB + 1] : 0;
        dB0 = dinv[s0];
        vB0 = *(const short8*)(h + (size_t)s0 * W + c0);
    }

    while (__any(pA < peA || pB < peB)) {
        if (pA < peA) {
            int sA2 = (pA + 2 < peA) ? col[pA + 2] : 0;
            short8 vA1 = zed;
            float dA1 = 0.f;
            if (pA + 1 < peA) {
                vA1 = *(const short8*)(h + (size_t)sA1 * W + c0);
                dA1 = dinv[sA1];
            }
            float cf = dA0 * diA;
#pragma unroll
            for (int j = 0; j < 8; ++j) accA[j] += cf * bits2f(vA0[j]);
            vA0 = vA1; dA0 = dA1; sA1 = sA2; ++pA;
        }
        if (pB < peB) {
            int sB2 = (pB + 2 < peB) ? col[pB + 2] : 0;
            short8 vB1 = zed;
            float dB1 = 0.f;
            if (pB + 1 < peB) {
                vB1 = *(const short8*)(h + (size_t)sB1 * W + c0);
                dB1 = dinv[sB1];
            }
            float cf = dB0 * diB;
#pragma unroll
            for (int j = 0; j < 8; ++j) accB[j] += cf * bits2f(vB0[j]);
            vB0 = vB1; dB0 = dB1; sB1 = sB2; ++pB;
        }
    }

    float bv[8];
#pragma unroll
    for (int j = 0; j < 8; ++j) bv[j] = 0.f;
    if (bias) {
        float4 b0 = *(const float4*)(bias + c0);
        float4 b1 = *(const float4*)(bias + c0 + 4);
        bv[0] = b0.x; bv[1] = b0.y; bv[2] = b0.z; bv[3] = b0.w;
        bv[4] = b1.x; bv[5] = b1.y; bv[6] = b1.z; bv[7] = b1.w;
    }

    auto store_row = [&](int node, float* acc) {
        float r[8];
#pragma unroll
        for (int j = 0; j < 8; ++j) {
            r[j] = acc[j] + bv[j];
            if (relu) r[j] = fmaxf(r[j], 0.f);
        }
        size_t off = (size_t)node * W + c0;
        if constexpr (sizeof(TO) == 2) {
            short8 pk;
#pragma unroll
            for (int j = 0; j < 8; ++j) pk[j] = bf16bits(r[j]);
            *(short8*)((bf16*)o + off) = pk;
        } else {
            float4 f0 = {r[0], r[1], r[2], r[3]};
            float4 f1 = {r[4], r[5], r[6], r[7]};
            *(float4*)((float*)o + off) = f0;
            *(float4*)((float*)o + off + 4) = f1;
        }
    };
    store_row(nA, accA);
    if (okB) store_row(nB, accB);
}

template <typename TO>
static void launch_gather6(const bf16* h, const float* dinv, const int* rowptr,
                           const int* col, TO* o, int n, int W,
                           const float* bias, int relu, hipStream_t stream) {
    dim3 b(64, 4);
    if (W == 128)
        k_gather6<TO, 16><<<cdiv(n, 32), b, 0, stream>>>(h, dinv, rowptr, col, o, n,
                                                         bias, relu);
    else
        k_gather6<TO, 8><<<cdiv(n, 64), b, 0, stream>>>(h, dinv, rowptr, col, o, n,
                                                        bias, relu);
}

// ---------------------------------------------------------------------------
// W pre-pack into MFMA fragment layout (bf16), all 8 weights in ONE launch:
//   Wb[((s*Mp) + n)*32 + kk] = W[s*32+kk][n]   (zero-padded k>=K or n>=M)
// ---------------------------------------------------------------------------
template <int K, int M, int Mp>
__device__ inline void wpack1(const float* __restrict__ W, bf16* __restrict__ o, int j) {
    int kk = j & 31;
    int rem = j >> 5;
    int ncol = rem % Mp;
    int s = rem / Mp;
    int k = s * 32 + kk;
    float v = (k < K && ncol < M) ? W[(size_t)k * M + ncol] : 0.f;
    o[j] = __float2bfloat16(v);
}

__global__ void k_wpack_all(const float* __restrict__ eW0, const float* __restrict__ eW1,
                            const float* __restrict__ eW2, const float* __restrict__ dW0,
                            const float* __restrict__ dW1, const float* __restrict__ dW2,
                            const float* __restrict__ sW0, const float* __restrict__ sW1,
                            bf16* __restrict__ arena) {
    for (int i = blockIdx.x * 256 + threadIdx.x; i < 159744; i += gridDim.x * 256) {
        if (i < 16384)       wpack1<38, 256, 256>(eW0, arena, i);
        else if (i < 49152)  wpack1<256, 128, 128>(eW1, arena + 16384, i - 16384);
        else if (i < 57344)  wpack1<128, 64, 64>(eW2, arena + 49152, i - 49152);
        else if (i < 65536)  wpack1<64, 128, 128>(dW0, arena + 57344, i - 57344);
        else if (i < 98304)  wpack1<128, 256, 256>(dW1, arena + 65536, i - 65536);
        else if (i < 110592) wpack1<256, 38, 48>(dW2, arena + 98304, i - 98304);
        else if (i < 126976) wpack1<38, 256, 256>(sW0, arena + 110592, i - 110592);
        else                 wpack1<256, 128, 128>(sW1, arena + 126976, i - 126976);
    }
}

// ---------------------------------------------------------------------------
// Fold global BN into weights:  W'[k,j] = sc[k]*W[k,j] packed to MFMA layout;
// b'[j] = -sum_k mu[k]*sc[k]*W[k,j]  (all fp32 math).  bn(A)@W == A@W' + b'.
// ---------------------------------------------------------------------------
template <int K, int M, int Mp>
__global__ void k_wfold(const float* __restrict__ W, const float* __restrict__ mu,
                        const float* __restrict__ sc, bf16* __restrict__ Wb,
                        float* __restrict__ bout) {
    const int tot = (K / 32) * Mp * 32;
    for (int i = blockIdx.x * 256 + threadIdx.x; i < tot; i += gridDim.x * 256) {
        int kk = i & 31;
        int rem = i >> 5;
        int ncol = rem % Mp;
        int s = rem / Mp;
        int k = s * 32 + kk;
        float v = (k < K && ncol < M) ? sc[k] * W[(size_t)k * M + ncol] : 0.f;
        Wb[i] = __float2bfloat16(v);
    }
    if (blockIdx.x == 0 && threadIdx.x < M) {
        int j = threadIdx.x;
        float s = 0.f;
        for (int k = 0; k < K; ++k) s -= mu[k] * sc[k] * W[(size_t)k * M + j];
        bout[j] = s;
    }
}

// ---------------------------------------------------------------------------
// MFMA GEMM v4 (kept from R6):  C = act( bn(A) @ W + bias )
// Batched A/W fragment loads + __launch_bounds__(256,3) headroom.
// ---------------------------------------------------------------------------
template <typename TC, int NT, int S, int BNM>
__global__ __launch_bounds__(256, 3) void k_mfma_gemm(
    const bf16* __restrict__ A, const bf16* __restrict__ Wb,
    TC* __restrict__ C, int M, int MC,
    const float* __restrict__ bias, int act,
    const float* __restrict__ mu, const float* __restrict__ sc,
    const int* __restrict__ seg)
{
    const int SA = S * 32;
    const int Mp = NT * 16;
    const int lane = threadIdx.x;
    const int wave = threadIdx.y;
    const int row0 = blockIdx.x * 64 + wave * 16;
    const int qr = lane >> 4;
    const int lc = lane & 15;

    // batch-load all A fragments (S loads in flight)
    short8 af[S];
    {
        const bf16* arow = A + (size_t)(row0 + lc) * SA + qr * 8;
#pragma unroll
        for (int s = 0; s < S; ++s) af[s] = *(const short8*)(arow + s * 32);
    }
    if (BNM == 2) {
        size_t bnbase = (size_t)seg[row0 + lc] * SA;
#pragma unroll
        for (int s = 0; s < S; ++s) {
            int kb = s * 32 + qr * 8;
            const float* mp = mu + bnbase + kb;
            const float* sp = sc + bnbase + kb;
            float4 m0 = *(const float4*)mp, m1 = *(const float4*)(mp + 4);
            float4 s0 = *(const float4*)sp, s1 = *(const float4*)(sp + 4);
            float av[8];
#pragma unroll
            for (int j = 0; j < 8; ++j) av[j] = bits2f(af[s][j]);
            av[0] = (av[0] - m0.x) * s0.x; av[1] = (av[1] - m0.y) * s0.y;
            av[2] = (av[2] - m0.z) * s0.z; av[3] = (av[3] - m0.w) * s0.w;
            av[4] = (av[4] - m1.x) * s1.x; av[5] = (av[5] - m1.y) * s1.y;
            av[6] = (av[6] - m1.z) * s1.z; av[7] = (av[7] - m1.w) * s1.w;
#pragma unroll
            for (int j = 0; j < 8; ++j) af[s][j] = bf16bits(av[j]);
        }
    }

    float4v acc[NT];
#pragma unroll
    for (int t = 0; t < NT; ++t) acc[t] = (float4v){0.f, 0.f, 0.f, 0.f};

    const bf16* wrow = Wb + (size_t)lc * 32 + qr * 8;
#pragma unroll
    for (int s = 0; s < S; ++s) {
        short8 wfv[NT];
#pragma unroll
        for (int t = 0; t < NT; ++t)
            wfv[t] = *(const short8*)(wrow + ((size_t)s * Mp + t * 16) * 32);
#pragma unroll
        for (int t = 0; t < NT; ++t)
            acc[t] = __builtin_amdgcn_mfma_f32_16x16x32_bf16(wfv[t], af[s], acc[t], 0, 0, 0);
    }

    const int row = row0 + lc;
#pragma unroll
    for (int t = 0; t < NT; ++t) {
        int c0 = t * 16 + qr * 4;
        if (c0 >= M) continue;
        float v[4];
#pragma unroll
        for (int r = 0; r < 4; ++r) v[r] = acc[t][r];
        if (bias) {
            if (c0 + 3 < M) {
                float4 bv = *(const float4*)(bias + c0);
                v[0] += bv.x; v[1] += bv.y; v[2] += bv.z; v[3] += bv.w;
            } else {
#pragma unroll
                for (int r = 0; r < 4; ++r) if (c0 + r < M) v[r] += bias[c0 + r];
            }
        }
#pragma unroll
        for (int r = 0; r < 4; ++r) {
            if (act == 1) v[r] = fmaxf(v[r], 0.f);
            else if (act == 2) v[r] = 1.f / (1.f + expf(-v[r]));
        }
        if (c0 + 3 < M) {
            if constexpr (sizeof(TC) == 2) {
                short4v pk = {bf16bits(v[0]), bf16bits(v[1]), bf16bits(v[2]), bf16bits(v[3])};
                *(short4v*)((bf16*)C + (size_t)row * MC + c0) = pk;
            } else {
                stf2((float*)C, ((size_t)row * MC + c0) >> 1, make_float2(v[0], v[1]));
                stf2((float*)C, ((size_t)row * MC + c0 + 2) >> 1, make_float2(v[2], v[3]));
            }
        } else {
#pragma unroll
            for (int r = 0; r < 4; ++r)
                if (c0 + r < M) stf(C, (size_t)row * MC + c0 + r, v[r]);
        }
    }
}

template <typename TC, int BNM>
static void launch_mfma(const bf16* A, const bf16* Wb, TC* C, int n, int SA,
                        int Mp, int M, int MC, const float* bias, int act,
                        const float* mu, const float* sc, const int* seg,
                        hipStream_t stream) {
    dim3 b(64, 4);
    int g = n / 64;
    if (SA == 64 && Mp == 256)
        k_mfma_gemm<TC, 16, 2, BNM><<<g, b, 0, stream>>>(A, Wb, C, M, MC, bias, act, mu, sc, seg);
    else if (SA == 256 && Mp == 128)
        k_mfma_gemm<TC, 8, 8, BNM><<<g, b, 0, stream>>>(A, Wb, C, M, MC, bias, act, mu, sc, seg);
    else if (SA == 128 && Mp == 64)
        k_mfma_gemm<TC, 4, 4, BNM><<<g, b, 0, stream>>>(A, Wb, C, M, MC, bias, act, mu, sc, seg);
}

// ---------------------------------------------------------------------------
// L0 stats (R5-proven version — R6's batched variant SPILLED: VGPR_Count 84
// vs ~140 live, 171MB scratch reads, 170µs.  Reverted verbatim.)
// ---------------------------------------------------------------------------
__global__ __launch_bounds__(256) void k_l0stats(
    const bf16* __restrict__ Y0, const bf16* __restrict__ W0b,
    const float* __restrict__ b0, float* __restrict__ sum,
    float* __restrict__ sumsq, int ntiles)
{
    __shared__ float ls[4][512];
    const int lane = threadIdx.x;
    const int wave = threadIdx.y;
    const int lc = lane & 15, qr = lane >> 4;

    float bv[16];
#pragma unroll
    for (int t = 0; t < 16; ++t) bv[t] = b0[t * 16 + lc];

    float sReg[16], qReg[16];
#pragma unroll
    for (int t = 0; t < 16; ++t) { sReg[t] = 0.f; qReg[t] = 0.f; }

    for (int tile = blockIdx.x; tile < ntiles; tile += gridDim.x) {
        const int row0 = tile * 64 + wave * 16;
        const bf16* arow = Y0 + (size_t)(row0 + lc) * 64 + qr * 8;
        float4v acc[16];
#pragma unroll
        for (int t = 0; t < 16; ++t) acc[t] = (float4v){0.f, 0.f, 0.f, 0.f};
#pragma unroll
        for (int s = 0; s < 2; ++s) {
            short8 af = *(const short8*)(arow + s * 32);
#pragma unroll
            for (int t = 0; t < 16; ++t) {
                short8 wf = *(const short8*)(W0b + ((size_t)(s * 256 + t * 16 + lc)) * 32 + qr * 8);
                // UNSWAPPED: lane owns col t*16+lc, rows qr*4+r
                acc[t] = __builtin_amdgcn_mfma_f32_16x16x32_bf16(af, wf, acc[t], 0, 0, 0);
            }
        }
#pragma unroll
        for (int t = 0; t < 16; ++t) {
            float s4 = 0.f, q4 = 0.f;
#pragma unroll
            for (int r = 0; r < 4; ++r) {
                float v = fmaxf(acc[t][r] + bv[t], 0.f);
                v = bits2f(bf16bits(v));     // match bf16-stored a0 semantics
                s4 += v;
                q4 += v * v;
            }
            s4 += __shfl_xor(s4, 16, 64); s4 += __shfl_xor(s4, 32, 64);
            q4 += __shfl_xor(q4, 16, 64); q4 += __shfl_xor(q4, 32, 64);
            sReg[t] += s4;
            qReg[t] += q4;
        }
    }
    if (lane < 16) {
#pragma unroll
        for (int t = 0; t < 16; ++t) {
            ls[wave][t * 16 + lc] = sReg[t];
            ls[wave][256 + t * 16 + lc] = qReg[t];
        }
    }
    __syncthreads();
    int tid = wave * 64 + lane;
    if (tid < 256) {
        atomicAdd(&sum[tid], ls[0][tid] + ls[1][tid] + ls[2][tid] + ls[3][tid]);
        atomicAdd(&sumsq[tid],
                  ls[0][256 + tid] + ls[1][256 + tid] + ls[2][256 + tid] + ls[3][256 + tid]);
    }
}

// ---------------------------------------------------------------------------
// Fused L0+L1 (R6 batched form, kept): G1 = relu(Y0@W0+b0) @ W1' + b1'.
// ---------------------------------------------------------------------------
__global__ __launch_bounds__(256, 3) void k_fused01(
    const bf16* __restrict__ Y0, const bf16* __restrict__ W0b,
    const float* __restrict__ b0, const bf16* __restrict__ W1b,
    const float* __restrict__ b1f, bf16* __restrict__ G1, int n)
{
    __shared__ __attribute__((aligned(16))) char lds[4][8192];
    const int lane = threadIdx.x;
    const int wave = threadIdx.y;
    const int lc = lane & 15, qr = lane >> 4;
    const int row0 = blockIdx.x * 64 + wave * 16;
    char* r2 = lds[wave];            // [16][256] bf16, 512B/row
    const int swz = (lc & 7) << 4;

    // ---- phase 1: a0 = relu(Y0@W0 + b0), K=64 (S=2), 256 cols (NT=16) ----
    {
        const bf16* arow = Y0 + (size_t)(row0 + lc) * 64 + qr * 8;
        short8 af0 = *(const short8*)(arow);
        short8 af1 = *(const short8*)(arow + 32);
        float4v acc[16];
#pragma unroll
        for (int t = 0; t < 16; ++t) acc[t] = (float4v){0.f, 0.f, 0.f, 0.f};
#pragma unroll
        for (int s = 0; s < 2; ++s) {
            short8 af = s ? af1 : af0;
            short8 wfv[16];
#pragma unroll
            for (int t = 0; t < 16; ++t)
                wfv[t] = *(const short8*)(W0b + ((size_t)(s * 256 + t * 16 + lc)) * 32 + qr * 8);
#pragma unroll
            for (int t = 0; t < 16; ++t)
                acc[t] = __builtin_amdgcn_mfma_f32_16x16x32_bf16(wfv[t], af, acc[t], 0, 0, 0);
        }
#pragma unroll
        for (int t = 0; t < 16; ++t) {
            int c0 = t * 16 + qr * 4;
            float4 bv = *(const float4*)(b0 + c0);
            short4v pk = {bf16bits(fmaxf(acc[t][0] + bv.x, 0.f)),
                          bf16bits(fmaxf(acc[t][1] + bv.y, 0.f)),
                          bf16bits(fmaxf(acc[t][2] + bv.z, 0.f)),
                          bf16bits(fmaxf(acc[t][3] + bv.w, 0.f))};
            int off = lc * 512 + t * 32 + qr * 8;
            *(short4v*)(r2 + (off ^ swz)) = pk;
        }
    }

    // ---- phase 2: G1 = a0 @ W1' + b1', K=256 (S=8), 128 cols (NT=8) ----
    short8 afv[8];
#pragma unroll
    for (int s = 0; s < 8; ++s) {
        int off = lc * 512 + s * 64 + qr * 16;
        afv[s] = *(const short8*)(r2 + (off ^ swz));
    }
    float4v a2[8];
#pragma unroll
    for (int t = 0; t < 8; ++t) a2[t] = (float4v){0.f, 0.f, 0.f, 0.f};
#pragma unroll
    for (int s = 0; s < 8; ++s) {
        short8 wfv[8];
#pragma unroll
        for (int t = 0; t < 8; ++t)
            wfv[t] = *(const short8*)(W1b + ((size_t)(s * 128 + t * 16 + lc)) * 32 + qr * 8);
#pragma unroll
        for (int t = 0; t < 8; ++t)
            a2[t] = __builtin_amdgcn_mfma_f32_16x16x32_bf16(wfv[t], afv[s], a2[t], 0, 0, 0);
    }
    const int row = row0 + lc;
#pragma unroll
    for (int t = 0; t < 8; ++t) {
        int c0 = t * 16 + qr * 4;
        float4 bv = *(const float4*)(b1f + c0);
        short4v pk = {bf16bits(a2[t][0] + bv.x), bf16bits(a2[t][1] + bv.y),
                      bf16bits(a2[t][2] + bv.z), bf16bits(a2[t][3] + bv.w)};
        *(short4v*)(G1 + (size_t)row * 128 + c0) = pk;
    }
}

// ---------------------------------------------------------------------------
// Fused decoder v3: sched_group_barrier-forced load clustering.
// R6 evidence: decoder VGPR_Count=68 — the compiler SANK the batched weight
// loads back to just-before-use, keeping them serialized (~250cy each, 98µs,
// all pipes idle).  sched_group_barrier(VMEM_READ=0x20, N) then (MFMA=0x8, N)
// is a compile-time scheduling directive it must honor: 8-load windows give
// 8x MLP while keeping live wfv at 32 VGPR (no spill; cap ~168 at 3 w/EU).
// ---------------------------------------------------------------------------
__global__ __launch_bounds__(256, 3) void k_decoder(
    const bf16* __restrict__ zb, const bf16* __restrict__ dW0b,
    const bf16* __restrict__ dW1b, const bf16* __restrict__ dW2b,
    float* __restrict__ xrec, int n)
{
    __shared__ __attribute__((aligned(16))) char lds[4][12288];
    const int lane = threadIdx.x;
    const int wave = threadIdx.y;
    const int lc = lane & 15, qr = lane >> 4;
    const int row0 = blockIdx.x * 64 + wave * 16;
    char* r1 = lds[wave];            // [16][128] bf16, 256B/row
    char* r2 = lds[wave] + 4096;     // [16][256] bf16, 512B/row
    const int swz = (lc & 7) << 4;

    // ---- layer 1: relu(zb @ dW0), K=64 (S=2), 128 cols (NT=8) ----
    {
        const bf16* arow = zb + (size_t)(row0 + lc) * 64 + qr * 8;
        short8 af0 = *(const short8*)(arow);
        short8 af1 = *(const short8*)(arow + 32);
        float4v a1[8];
#pragma unroll
        for (int t = 0; t < 8; ++t) a1[t] = (float4v){0.f, 0.f, 0.f, 0.f};
#pragma unroll
        for (int s = 0; s < 2; ++s) {
            short8 af = s ? af1 : af0;
            short8 wfv[8];
#pragma unroll
            for (int t = 0; t < 8; ++t)
                wfv[t] = *(const short8*)(dW0b + ((size_t)(s * 128 + t * 16 + lc)) * 32 + qr * 8);
#pragma unroll
            for (int t = 0; t < 8; ++t)
                a1[t] = __builtin_amdgcn_mfma_f32_16x16x32_bf16(wfv[t], af, a1[t], 0, 0, 0);
            __builtin_amdgcn_sched_group_barrier(0x020, 8, 0);  // 8 VMEM reads
            __builtin_amdgcn_sched_group_barrier(0x008, 8, 0);  // 8 MFMAs
        }
#pragma unroll
        for (int t = 0; t < 8; ++t) {
            short4v pk = {bf16bits(fmaxf(a1[t][0], 0.f)), bf16bits(fmaxf(a1[t][1], 0.f)),
                          bf16bits(fmaxf(a1[t][2], 0.f)), bf16bits(fmaxf(a1[t][3], 0.f))};
            int off = lc * 256 + t * 32 + qr * 8;
            *(short4v*)(r1 + (off ^ swz)) = pk;
        }
    }

    // ---- layer 2: relu(r1 @ dW1), K=128 (S=4), 256 cols (NT=16) ----
    {
        short8 afv[4];
#pragma unroll
        for (int s = 0; s < 4; ++s) {
            int off = lc * 256 + s * 64 + qr * 16;
            afv[s] = *(const short8*)(r1 + (off ^ swz));
        }
        float4v a2[16];
#pragma unroll
        for (int t = 0; t < 16; ++t) a2[t] = (float4v){0.f, 0.f, 0.f, 0.f};
#pragma unroll
        for (int s = 0; s < 4; ++s) {
#pragma unroll
            for (int h = 0; h < 2; ++h) {
                short8 wfv[8];
#pragma unroll
                for (int tt = 0; tt < 8; ++tt) {
                    int t = h * 8 + tt;
                    wfv[tt] = *(const short8*)(dW1b + ((size_t)(s * 256 + t * 16 + lc)) * 32 + qr * 8);
                }
#pragma unroll
                for (int tt = 0; tt < 8; ++tt) {
                    int t = h * 8 + tt;
                    a2[t] = __builtin_amdgcn_mfma_f32_16x16x32_bf16(wfv[tt], afv[s], a2[t], 0, 0, 0);
                }
                __builtin_amdgcn_sched_group_barrier(0x020, 8, 0);
                __builtin_amdgcn_sched_group_barrier(0x008, 8, 0);
            }
        }
#pragma unroll
        for (int t = 0; t < 16; ++t) {
            short4v pk = {bf16bits(fmaxf(a2[t][0], 0.f)), bf16bits(fmaxf(a2[t][1], 0.f)),
                          bf16bits(fmaxf(a2[t][2], 0.f)), bf16bits(fmaxf(a2[t][3], 0.f))};
            int off = lc * 512 + t * 32 + qr * 8;
            *(short4v*)(r2 + (off ^ swz)) = pk;
        }
    }

    // ---- layer 3: sigmoid(r2 @ dW2), K=256 (S=8), 38 cols (NT=3, Mp=48) ----
    short8 afv[8];
#pragma unroll
    for (int s = 0; s < 8; ++s) {
        int off = lc * 512 + s * 64 + qr * 16;
        afv[s] = *(const short8*)(r2 + (off ^ swz));
    }
    float4v a3[3];
#pragma unroll
    for (int t = 0; t < 3; ++t) a3[t] = (float4v){0.f, 0.f, 0.f, 0.f};
#pragma unroll
    for (int s = 0; s < 8; ++s) {
        short8 wfv[3];
#pragma unroll
        for (int t = 0; t < 3; ++t)
            wfv[t] = *(const short8*)(dW2b + ((size_t)(s * 48 + t * 16 + lc)) * 32 + qr * 8);
#pragma unroll
        for (int t = 0; t < 3; ++t)
            a3[t] = __builtin_amdgcn_mfma_f32_16x16x32_bf16(wfv[t], afv[s], a3[t], 0, 0, 0);
        __builtin_amdgcn_sched_group_barrier(0x020, 3, 0);
        __builtin_amdgcn_sched_group_barrier(0x008, 3, 0);
    }
    float* orow = xrec + (size_t)(row0 + lc) * 38;
#pragma unroll
    for (int t = 0; t < 3; ++t) {
        int c0 = t * 16 + qr * 4;
        float v0 = 1.f / (1.f + expf(-a3[t][0]));
        float v1 = 1.f / (1.f + expf(-a3[t][1]));
        float v2 = 1.f / (1.f + expf(-a3[t][2]));
        float v3 = 1.f / (1.f + expf(-a3[t][3]));
        if (c0 + 1 < 38) *(float2*)(orow + c0) = make_float2(v0, v1);
        if (c0 + 3 < 38) *(float2*)(orow + c0 + 2) = make_float2(v2, v3);
    }
}

// ---------------------------------------------------------------------------
// LDS-tiled fp32 vector GEMM (t-MLP / classifier — tiny n, precision-tight)
// ---------------------------------------------------------------------------
template <typename TA, typename TC, int NJ>
__global__ __launch_bounds__(256) void k_gemm(
    const TA* __restrict__ A, const float* __restrict__ W,
    TC* __restrict__ C, int n, int K, int M,
    const float* __restrict__ bias, int act,
    const float* __restrict__ mu, const float* __restrict__ sc)
{
    __shared__ float alds[64 * 32];
    __shared__ float wlds[32 * 256];
    const int l = threadIdx.x;
    const int wy = threadIdx.y;
    const int tid = wy * 64 + l;
    const int row0 = blockIdx.x * 64;

    float acc[16][NJ];
#pragma unroll
    for (int r = 0; r < 16; ++r)
#pragma unroll
        for (int j = 0; j < NJ; ++j) acc[r][j] = 0.f;

    int cidx[NJ]; bool jval[NJ];
#pragma unroll
    for (int j = 0; j < NJ; ++j) {
        cidx[j] = l + 64 * j;
        jval[j] = cidx[j] < M;
    }

    for (int k0 = 0; k0 < K; k0 += 32) {
        int kt = min(32, K - k0);
        __syncthreads();
        for (int i = tid; i < 64 * 32; i += 256) {
            int r = i >> 5, kk = i & 31;
            int row = row0 + r, k = k0 + kk;
            float v = (row < n && k < K) ? ldf(A, (size_t)row * K + k) : 0.f;
            if (mu && k < K) v = (v - mu[k]) * sc[k];
            alds[i] = v;
        }
        for (int i = tid; i < kt * M; i += 256)
            wlds[i] = W[(size_t)k0 * M + i];
        if (kt < 32)
            for (int i = kt * M + tid; i < 32 * M; i += 256) wlds[i] = 0.f;
        __syncthreads();

#pragma unroll 2
        for (int kkg = 0; kkg < 8; ++kkg) {
            float wv[4][NJ];
#pragma unroll
            for (int q = 0; q < 4; ++q)
#pragma unroll
                for (int j = 0; j < NJ; ++j)
                    wv[q][j] = jval[j] ? wlds[(kkg * 4 + q) * M + cidx[j]] : 0.f;
#pragma unroll
            for (int rr = 0; rr < 16; ++rr) {
                const float4* arow = (const float4*)&alds[(wy * 16 + rr) * 32];
                float4 av = arow[kkg];
#pragma unroll
                for (int j = 0; j < NJ; ++j) {
                    acc[rr][j] += av.x * wv[0][j];
                    acc[rr][j] += av.y * wv[1][j];
                    acc[rr][j] += av.z * wv[2][j];
                    acc[rr][j] += av.w * wv[3][j];
                }
            }
        }
    }

#pragma unroll
    for (int rr = 0; rr < 16; ++rr) {
        int row = row0 + wy * 16 + rr;
        if (row >= n) continue;
#pragma unroll
        for (int j = 0; j < NJ; ++j) {
            if (!jval[j]) continue;
            float v = acc[rr][j];
            if (bias) v += bias[cidx[j]];
            if (act == 1) v = fmaxf(v, 0.f);
            else if (act == 2) v = 1.f / (1.f + expf(-v));
            stf(C, (size_t)row * M + cidx[j], v);
        }
    }
}

// ---------------------------------------------------------------------------
// BatchNorm stats: vectorized 8-col loads, LDS-staged atomics.
// ---------------------------------------------------------------------------
template <typename T>
__global__ __launch_bounds__(256) void k_bn_stats8(
    const T* __restrict__ x, int n, int M,
    float* __restrict__ sum, float* __restrict__ sumsq)
{
    __shared__ float ls[512];
    int t = threadIdx.x;
    for (int i = t; i < 2 * M; i += 256) ls[i] = 0.f;
    __syncthreads();

    int gpr = M >> 3;           // col-groups per row
    int c8 = (t % gpr) * 8;
    int g = t / gpr;
    int rpb = 256 / gpr;

    float s[8], q[8];
#pragma unroll
    for (int j = 0; j < 8; ++j) { s[j] = 0.f; q[j] = 0.f; }

    for (int r = blockIdx.x * rpb + g; r < n; r += gridDim.x * rpb) {
        float v[8];
        if constexpr (sizeof(T) == 2) {
            short8 v8 = *(const short8*)((const bf16*)x + (size_t)r * M + c8);
#pragma unroll
            for (int j = 0; j < 8; ++j) v[j] = bits2f(v8[j]);
        } else {
            float4 f0 = *(const float4*)((const float*)x + (size_t)r * M + c8);
            float4 f1 = *(const float4*)((const float*)x + (size_t)r * M + c8 + 4);
            v[0] = f0.x; v[1] = f0.y; v[2] = f0.z; v[3] = f0.w;
            v[4] = f1.x; v[5] = f1.y; v[6] = f1.z; v[7] = f1.w;
        }
#pragma unroll
        for (int j = 0; j < 8; ++j) { s[j] += v[j]; q[j] += v[j] * v[j]; }
    }
#pragma unroll
    for (int j = 0; j < 8; ++j) {
        atomicAdd(&ls[c8 + j], s[j]);
        atomicAdd(&ls[M + c8 + j], q[j]);
    }
    __syncthreads();
    for (int i = t; i < M; i += 256) {
        atomicAdd(&sum[i], ls[i]);
        atomicAdd(&sumsq[i], ls[M + i]);
    }
}

__global__ void k_bn_fin(float* __restrict__ sum, float* __restrict__ sumsq, int n, int M) {
    int c = threadIdx.x;
    if (c < M) {
        float m = sum[c] / (float)n;
        float v = fmaxf(sumsq[c] / (float)n - m * m, 0.f);
        sum[c] = m;
        sumsq[c] = rsqrtf(v + BN_EPS);
    }
}

// ---------------------------------------------------------------------------
// Wave-per-segment BN stats (sorted seg, boundaries precomputed): writes
// mu/sc DIRECTLY.  No atomics, no zero-fill, no fin pass.  M = 64*CPL.
// ---------------------------------------------------------------------------
template <int CPL>
__global__ __launch_bounds__(256) void k_segbn(
    const bf16* __restrict__ x, const int* __restrict__ gstart, int nseg,
    float* __restrict__ mu, float* __restrict__ sc)
{
    const int M = 64 * CPL;
    int s = blockIdx.x * 4 + threadIdx.y;
    if (s >= nseg) return;
    int l = threadIdx.x;
    int gs = gstart[s], ge = gstart[s + 1];
    float sum[CPL], sq[CPL];
#pragma unroll
    for (int j = 0; j < CPL; ++j) { sum[j] = 0.f; sq[j] = 0.f; }
    for (int r = gs; r < ge; ++r) {
        const bf16* px = x + (size_t)r * M + l * CPL;
        if constexpr (CPL == 4) {
            short4v v4 = *(const short4v*)px;
#pragma unroll
            for (int j = 0; j < 4; ++j) {
                float v = bits2f(v4[j]);
                sum[j] += v; sq[j] += v * v;
            }
        } else {
            __hip_bfloat162 v2 = *(const __hip_bfloat162*)px;
            float v0 = __bfloat162float(v2.x), v1 = __bfloat162float(v2.y);
            sum[0] += v0; sq[0] += v0 * v0;
            sum[1] += v1; sq[1] += v1 * v1;
        }
    }
    float c = fmaxf((float)(ge - gs), 1.f);
#pragma unroll
    for (int j = 0; j < CPL; ++j) {
        float m = sum[j] / c;
        float v = fmaxf(sq[j] / c - m * m, 0.f);
        mu[(size_t)s * M + l * CPL + j] = m;
        sc[(size_t)s * M + l * CPL + j] = rsqrtf(v + BN_EPS);
    }
}

// ---------------------------------------------------------------------------
// Wave-per-segment mean pool over 64-col fp32 rows (input pre-normalized).
// ---------------------------------------------------------------------------
__global__ __launch_bounds__(256) void k_pool(
    const float* __restrict__ z, const int* __restrict__ gstart, int nseg,
    float* __restrict__ o)
{
    int s = blockIdx.x * 4 + threadIdx.y;
    if (s >= nseg) return;
    int l = threadIdx.x;
    int gs = gstart[s], ge = gstart[s + 1];
    float acc = 0.f;
    for (int r = gs; r < ge; ++r) acc += z[(size_t)r * 64 + l];
    o[(size_t)s * 64 + l] = acc / fmaxf((float)(ge - gs), 1.f);
}

// ---------------------------------------------------------------------------
// Wave-per-segment fused l2norm + mean pool (sub path: zs is only pooled).
// ---------------------------------------------------------------------------
__global__ __launch_bounds__(256) void k_l2pool(
    const float* __restrict__ zs, const int* __restrict__ gstart, int nseg,
    float* __restrict__ o)
{
    int s = blockIdx.x * 4 + threadIdx.y;
    if (s >= nseg) return;
    int l = threadIdx.x;
    int gs = gstart[s], ge = gstart[s + 1];
    float acc = 0.f;
    for (int r = gs; r < ge; ++r) {
        float v = zs[(size_t)r * 64 + l];
        float ss = v * v;
        for (int off = 32; off > 0; off >>= 1) ss += __shfl_xor(ss, off, 64);
        acc += v / fmaxf(sqrtf(ss), 1e-12f);
    }
    o[(size_t)s * 64 + l] = acc / fmaxf((float)(ge - gs), 1.f);
}

// ---------------------------------------------------------------------------
// Row L2 normalize, M = 64; writes fp32 in place + optional bf16 copy
// ---------------------------------------------------------------------------
__global__ void k_l2norm2(float* __restrict__ x, bf16* __restrict__ xb, int n) {
    int row = blockIdx.x * 4 + threadIdx.y;
    if (row >= n) return;
    int l = threadIdx.x;
    float v = x[(size_t)row * 64 + l];
    float ss = v * v;
    for (int o = 32; o > 0; o >>= 1) ss += __shfl_xor(ss, o, 64);
    float r = v / fmaxf(sqrtf(ss), 1e-12f);
    x[(size_t)row * 64 + l] = r;
    if (xb) xb[(size_t)row * 64 + l] = __float2bfloat16(r);
}

// ---------------------------------------------------------------------------
// Host-side vector-GEMM launch helper
// ---------------------------------------------------------------------------
template <typename TA, typename TC>
static void launch_gemm(const TA* A, const float* W, TC* C, int n, int K, int M,
                        const float* bias, int act, const float* mu, const float* sc,
                        hipStream_t stream) {
    dim3 b(64, 4);
    int g = cdiv(n, 64);
    int nj = (M + 63) >> 6;
    if (nj >= 4)      k_gemm<TA, TC, 4><<<g, b, 0, stream>>>(A, W, C, n, K, M, bias, act, mu, sc);
    else if (nj == 2) k_gemm<TA, TC, 2><<<g, b, 0, stream>>>(A, W, C, n, K, M, bias, act, mu, sc);
    else              k_gemm<TA, TC, 1><<<g, b, 0, stream>>>(A, W, C, n, K, M, bias, act, mu, sc);
}

// ---------------------------------------------------------------------------
// Host launch
// ---------------------------------------------------------------------------
extern "C" void kernel_launch(void* const* d_in, const int* in_sizes, int n_in,
                              void* d_out, int out_size, void* d_ws, size_t ws_size,
                              hipStream_t stream) {
    const float* x        = (const float*)d_in[0];
    const int*   ei       = (const int*)  d_in[1];
    const int*   batch    = (const int*)  d_in[2];
    const float* target_x = (const float*)d_in[3];
    const float* pos_x    = (const float*)d_in[4];
    const int*   pos_ei   = (const int*)  d_in[5];
    const int*   pos_b    = (const int*)  d_in[6];
    const float* neg_x    = (const float*)d_in[7];
    const int*   neg_ei   = (const int*)  d_in[8];
    const int*   neg_b    = (const int*)  d_in[9];
    const float* enc_W0 = (const float*)d_in[10]; const float* enc_b0 = (const float*)d_in[11];
    const float* enc_W1 = (const float*)d_in[12]; const float* enc_b1 = (const float*)d_in[13];
    const float* enc_W2 = (const float*)d_in[14]; const float* enc_b2 = (const float*)d_in[15];
    const float* dec_W0 = (const float*)d_in[16];
    const float* dec_W1 = (const float*)d_in[17];
    const float* dec_W2 = (const float*)d_in[18];
    const float* node_W0 = (const float*)d_in[19]; const float* node_b0 = (const float*)d_in[20];
    const float* node_W1 = (const float*)d_in[21]; const float* node_b1 = (const float*)d_in[22];
    const float* node_W2 = (const float*)d_in[23]; const float* node_b2 = (const float*)d_in[24];
    const float* sub_W0 = (const float*)d_in[25]; const float* sub_b0 = (const float*)d_in[26];
    const float* sub_W1 = (const float*)d_in[27]; const float* sub_b1 = (const float*)d_in[28];
    const float* cls_W0 = (const float*)d_in[29]; const float* cls_b0 = (const float*)d_in[30];
    const float* cls_W1 = (const float*)d_in[31]; const float* cls_b1 = (const float*)d_in[32];
    const float* cls_W2 = (const float*)d_in[33]; const float* cls_b2 = (const float*)d_in[34];

    float* out = (float*)d_out;
    const size_t OFF_XREC  = 0;
    const size_t OFF_ZPOOL = (size_t)N_NODES * F_IN;
    const size_t OFF_TZ    = OFF_ZPOOL + (size_t)N_GRAPHS * H2;
    const size_t OFF_PPOOL = OFF_TZ    + (size_t)N_GRAPHS * H2;
    const size_t OFF_NPOOL = OFF_PPOOL + (size_t)N_GRAPHS * H2;
    const size_t OFF_PRED  = OFF_NPOOL + (size_t)N_GRAPHS * H2;

    // ----- workspace carve-up (by floats; total ~207 MB) -----
    char* wsp = (char*)d_ws;
    auto alloc = [&](size_t nfloats) -> float* {
        float* p = (float*)wsp;
        wsp += ((nfloats + 63) / 64) * 64 * sizeof(float);
        return p;
    };
    float* R1     = alloc((size_t)N_NODES * 128);   // fp32 N*128 / bf16 N*256
    float* R2     = alloc((size_t)N_NODES * 128);
    float* dinv   = alloc(N_NODES);
    int*   cnt    = (int*)alloc(N_NODES);           // degree, then reused as cursor
    int*   rowptr = (int*)alloc(N_NODES + 1);
    int*   bsum   = (int*)alloc(1024);
    int*   ccol   = (int*)alloc(N_EDGES);
    float* ssum   = alloc(256);
    float* ssumsq = alloc(256);   // contiguous with ssum
    bf16*  wpk    = (bf16*)alloc(101 * 1024);  // 206848-bf16 arena, 200704 used
    float* bfold  = alloc(256);   // folded biases: b1' [0..128), b2' [128..192)
    (void)ws_size; (void)in_sizes; (void)n_in; (void)out_size;

    // packed-weight arena offsets (bf16 elements): S*Mp*32 each
    bf16* eW0b = wpk;            // K38->S2,  Mp256: 16384
    bf16* eW1b = eW0b + 16384;   // K256->S8, Mp128: 32768 (unused; layout keep)
    bf16* eW2b = eW1b + 32768;   // K128->S4, Mp64 :  8192
    bf16* dW0b = eW2b + 8192;    // K64->S2,  Mp128:  8192
    bf16* dW1b = dW0b + 8192;    // K128->S4, Mp256: 32768
    bf16* dW2b = dW1b + 32768;   // K256->S8, Mp48 : 12288
    bf16* sW0b = dW2b + 12288;   // K38->S2,  Mp256: 16384
    bf16* sW1b = sW0b + 16384;   // K256->S8, Mp128: 32768
    bf16* fW1b = sW1b + 32768;   // folded enc_W1': K256, Mp128: 32768
    bf16* fW2b = fW1b + 32768;   // folded enc_W2': K128, Mp64 :  8192

    // ----- R2-tail carve (no new allocs).
    float* tailf    = R2 + (size_t)16 * 1024 * 1024;          // 64 MB offset
    float* segsumM  = tailf;                                  // mu  4096*256
    float* segsumqM = tailf + (size_t)1048576;                // sc  4096*256
    float* mx       = tailf + (size_t)2097152;                // 2*N_SUB*F_IN fp32
    int*   msrc     = (int*)(mx + (size_t)2 * N_SUB * F_IN);  // 2*E_SUB
    int*   mdst     = msrc + 2 * E_SUB;                       // 2*E_SUB
    int*   mb       = mdst + 2 * E_SUB;                       // 2*N_SUB
    int*   gstartM  = mb + 2 * N_SUB;                         // 4097 ints (sub)
    int*   gstart2k = gstartM + 4112;                         // 2049 ints (main)

    dim3 b64x4(64, 4);
    auto zero = [&](void* p, size_t nfloats) {
        k_zero<<<cdiv((int)nfloats, 256), 256, 0, stream>>>((float*)p, (int)nfloats);
    };

    // pack all 8 weights in one launch (seg-BN fused at GEMM A-load;
    // global BN folded into W via k_wfold after stats)
    k_wpack_all<<<624, 256, 0, stream>>>(enc_W0, enc_W1, enc_W2, dec_W0, dec_W1,
                                         dec_W2, sub_W0, sub_W1, wpk);

    auto build_graph = [&](const int* srcp, const int* dstp, int n, int e) {
        zero(cnt, n);
        k_count<<<cdiv(e, 256), 256, 0, stream>>>(dstp, cnt, e);
        k_dinv<<<cdiv(n, 256), 256, 0, stream>>>(cnt, dinv, n);
        int nb = cdiv(n, 256);
        k_scan_sum<<<nb, 256, 0, stream>>>(cnt, bsum, n);
        k_scan_top<<<1, 1024, 0, stream>>>(bsum, nb);
        k_scan_apply<<<nb, 256, 0, stream>>>(cnt, bsum, rowptr, n);
        zero(cnt, n);  // cnt now serves as the fill cursor
        k_fill<<<cdiv(e, 256), 256, 0, stream>>>(srcp, dstp, rowptr, cnt, ccol, e);
    };

    auto bn_stats = [&](auto* xx, int n, int M) {
        zero(ssum, 512);  // ssum+ssumsq contiguous
        int rpb = 256 / (M >> 3);
        int g = min(512, cdiv(n, rpb));
        k_bn_stats8<<<g, 256, 0, stream>>>(xx, n, M, ssum, ssumsq);
        k_bn_fin<<<1, 256, 0, stream>>>(ssum, ssumsq, n, M);
    };

    // ============ main graph encode (fused L0+L1, BN folded into W) ============
    build_graph(ei, ei + N_EDGES, N_NODES, N_EDGES);

    // Y0 = A_hat * x  (bf16 N x 64, K-pad 38->64)  — in R1 (fused01 writes R2)
    bf16* Y0 = (bf16*)R1;
    launch_gather<float, bf16>(x, dinv, rowptr, ccol, Y0, N_NODES, F_IN, 64,
                               nullptr, 0, stream);

    // a0 stats computed in-register from Y0 (a0 never materialized)
    zero(ssum, 512);
    k_l0stats<<<512, b64x4, 0, stream>>>(Y0, eW0b, enc_b0, ssum, ssumsq,
                                         N_NODES / 64);
    k_bn_fin<<<1, 256, 0, stream>>>(ssum, ssumsq, N_NODES, H0);
    k_wfold<256, 128, 128><<<128, 256, 0, stream>>>(enc_W1, ssum, ssumsq, fW1b, bfold);

    // Fused L0+L1: G1 = relu(Y0@W0+b0) @ W1' + b1'
    bf16* G1 = (bf16*)R2;
    k_fused01<<<N_NODES / 64, b64x4, 0, stream>>>(Y0, eW0b, enc_b0, fW1b, bfold,
                                                  G1, N_NODES);

    // a1 = relu(A_hat*G1 + b1)   (Y0 dead -> a1 in R1)
    bf16* a1 = (bf16*)R1;
    launch_gather6<bf16>(G1, dinv, rowptr, ccol, a1, N_NODES, 128, enc_b1, 1, stream);
    bn_stats(a1, N_NODES, H1);
    k_wfold<128, 64, 64><<<32, 256, 0, stream>>>(enc_W2, ssum, ssumsq, fW2b, bfold + 128);

    // Layer 2: G2 = a1@W2' + b2'; z = A_hat*G2 + b2, l2norm
    bf16* G2 = (bf16*)R2;
    launch_mfma<bf16, 0>(a1, fW2b, G2, N_NODES, 128, 64, H2, H2, bfold + 128, 0,
                         nullptr, nullptr, nullptr, stream);
    float* z  = R1;
    bf16*  zb = (bf16*)(R1 + (size_t)N_NODES * 64);
    launch_gather6<float>(G2, dinv, rowptr, ccol, z, N_NODES, 64, enc_b2, 0, stream);
    k_l2norm2<<<cdiv(N_NODES, 4), b64x4, 0, stream>>>(z, zb, N_NODES);

    // z_pool (boundaries from sorted batch; wave-per-segment mean)
    k_gbound<<<cdiv(N_NODES, 256), 256, 0, stream>>>(batch, N_NODES, N_GRAPHS, gstart2k);
    k_pool<<<cdiv(N_GRAPHS, 4), b64x4, 0, stream>>>(z, gstart2k, N_GRAPHS,
                                                    out + OFF_ZPOOL);

    // ===================== decode: single fused kernel =====================
    k_decoder<<<N_NODES / 64, b64x4, 0, stream>>>(zb, dW0b, dW1b, dW2b,
                                                  out + OFF_XREC, N_NODES);

    // ===================== target node MLP (fp32 vector) =====================
    float* t0 = R2;  // 2048 x 256
    launch_gemm<float, float>(target_x, node_W0, t0, N_GRAPHS, F_IN, H0, node_b0, 1,
                              nullptr, nullptr, stream);
    bn_stats(t0, N_GRAPHS, H0);
    float* t1 = R1;  // 2048 x 128
    launch_gemm<float, float>(t0, node_W1, t1, N_GRAPHS, H0, H1, node_b1, 1,
                              ssum, ssumsq, stream);
    bn_stats(t1, N_GRAPHS, H1);
    launch_gemm<float, float>(t1, node_W2, out + OFF_TZ, N_GRAPHS, H1, H2, node_b2, 0,
                              ssum, ssumsq, stream);
    k_l2norm2<<<cdiv(N_GRAPHS, 4), b64x4, 0, stream>>>(out + OFF_TZ, nullptr, N_GRAPHS);

    // ========== merged pos+neg subgraph pipeline (one batched pass) ==========
    k_merge<<<2048, 256, 0, stream>>>(pos_x, neg_x, pos_ei, neg_ei, pos_b, neg_b,
                                      mx, msrc, mdst, mb);
    const int NS2 = 2 * N_SUB, ES2 = 2 * E_SUB, NG2 = 2 * N_GRAPHS;
    build_graph(msrc, mdst, NS2, ES2);
    k_gbound<<<cdiv(NS2, 256), 256, 0, stream>>>(mb, NS2, NG2, gstartM);

    // Layer 0: Ys = A_hat*mx (bf16, pad 38->64); as0 = relu(Ys@sW0 + b)
    bf16* Ys = (bf16*)R2;
    launch_gather<float, bf16>(mx, dinv, rowptr, ccol, Ys, NS2, F_IN, 64,
                               nullptr, 0, stream);
    bf16* as0 = (bf16*)R1;  // 65536 x 256
    launch_mfma<bf16, 0>(Ys, sW0b, as0, NS2, 64, 256, H0, H0, sub_b0, 1,
                         nullptr, nullptr, nullptr, stream);
    k_segbn<4><<<cdiv(NG2, 4), b64x4, 0, stream>>>(as0, gstartM, NG2,
                                                   segsumM, segsumqM);

    // Layer 1: Gs1 = segbn(as0)@sW1; as1 = relu(A_hat*Gs1 + b1)
    bf16* Gs1 = (bf16*)R2;  // 65536 x 128
    launch_mfma<bf16, 2>(as0, sW1b, Gs1, NS2, 256, 128, H1, H1, nullptr, 0,
                         segsumM, segsumqM, mb, stream);
    bf16* as1 = (bf16*)R1;  // 65536 x 128
    launch_gather6<bf16>(Gs1, dinv, rowptr, ccol, as1, NS2, 128, sub_b1, 1, stream);
    k_segbn<2><<<cdiv(NG2, 4), b64x4, 0, stream>>>(as1, gstartM, NG2,
                                                   segsumM, segsumqM);

    // Layer 2: Gs2 = segbn(as1)@encW2; zs = A_hat*Gs2 + b2; fused l2norm+pool
    bf16* Gs2 = (bf16*)R2;  // 65536 x 64
    launch_mfma<bf16, 2>(as1, eW2b, Gs2, NS2, 128, 64, H2, H2, nullptr, 0,
                         segsumM, segsumqM, mb, stream);
    float* zs = R1;  // 65536 x 64 fp32
    launch_gather6<float>(Gs2, dinv, rowptr, ccol, zs, NS2, 64, enc_b2, 0, stream);
    k_l2pool<<<cdiv(NG2, 4), b64x4, 0, stream>>>(zs, gstartM, NG2, out + OFF_PPOOL);

    // ===================== classifier on neg_pool (fp32 vector) =====================
    float* c1 = R2;
    launch_gemm<float, float>(out + OFF_NPOOL, cls_W0, c1, N_GRAPHS, H2, H1, cls_b0, 1,
                              nullptr, nullptr, stream);
    float* c2 = R1;
    launch_gemm<float, float>(c1, cls_W1, c2, N_GRAPHS, H1, 16, cls_b1, 1,
                              nullptr, nullptr, stream);
    launch_gemm<float, float>(c2, cls_W2, out + OFF_PRED, N_GRAPHS, 16, 1, cls_b2, 2,
                              nullptr, nullptr, stream);
}

// Round 8
// 1177.729 us; speedup vs baseline: 1.1428x; 1.0002x over previous
//
#include <hip/hip_runtime.h>
#include <hip/hip_bf16.h>
#include <math.h>

// ---------------------------------------------------------------------------
// Problem constants (from reference)
// ---------------------------------------------------------------------------
#define N_NODES  200000
#define N_EDGES  800000
#define N_GRAPHS 2048
#define N_SUB    32768
#define E_SUB    131072
#define F_IN     38
#define H0       256
#define H1       128
#define H2       64
#define BN_EPS   1e-5f

typedef __hip_bfloat16 bf16;
typedef __attribute__((ext_vector_type(8))) short short8;
typedef __attribute__((ext_vector_type(4))) short short4v;
typedef __attribute__((ext_vector_type(4))) float float4v;

static __host__ __device__ inline int cdiv(int a, int b) { return (a + b - 1) / b; }

__device__ inline float ldf(const float* p, size_t i) { return p[i]; }
__device__ inline float ldf(const bf16* p, size_t i)  { return __bfloat162float(p[i]); }
__device__ inline void  stf(float* p, size_t i, float v) { p[i] = v; }
__device__ inline void  stf(bf16* p, size_t i, float v)  { p[i] = __float2bfloat16(v); }

__device__ inline float2 ldf2(const float* p, size_t i) { return ((const float2*)p)[i]; }
__device__ inline float2 ldf2(const bf16* p, size_t i) {
    __hip_bfloat162 v = ((const __hip_bfloat162*)p)[i];
    return make_float2(__bfloat162float(v.x), __bfloat162float(v.y));
}
__device__ inline void stf2(float* p, size_t i, float2 v) { ((float2*)p)[i] = v; }
__device__ inline void stf2(bf16* p, size_t i, float2 v) {
    __hip_bfloat162 t;
    t.x = __float2bfloat16(v.x);
    t.y = __float2bfloat16(v.y);
    ((__hip_bfloat162*)p)[i] = t;
}

__device__ inline short bf16bits(float v) {
    bf16 t = __float2bfloat16(v);
    return *reinterpret_cast<short*>(&t);
}
__device__ inline float bits2f(short s) {
    return __bfloat162float(*reinterpret_cast<const bf16*>(&s));
}

// ---------------------------------------------------------------------------
// Zero fill (graph-capture-safe replacement for hipMemsetAsync)
// ---------------------------------------------------------------------------
__global__ void k_zero(float* __restrict__ p, int n) {
    int i = blockIdx.x * 256 + threadIdx.x;
    if (i < n) p[i] = 0.f;
}

// ---------------------------------------------------------------------------
// Graph preprocessing: degree, CSR build
// ---------------------------------------------------------------------------
__global__ void k_count(const int* __restrict__ dst, int* __restrict__ cnt, int e) {
    int i = blockIdx.x * 256 + threadIdx.x;
    if (i < e) atomicAdd(&cnt[dst[i]], 1);
}

__global__ void k_dinv(const int* __restrict__ cnt, float* __restrict__ dinv, int n) {
    int i = blockIdx.x * 256 + threadIdx.x;
    if (i < n) dinv[i] = rsqrtf(1.0f + (float)cnt[i]);
}

__global__ void k_scan_sum(const int* __restrict__ cnt, int* __restrict__ bsum, int n) {
    __shared__ int tmp[256];
    int t = threadIdx.x;
    int i = blockIdx.x * 256 + t;
    tmp[t] = (i < n) ? cnt[i] : 0;
    __syncthreads();
    for (int off = 128; off > 0; off >>= 1) {
        if (t < off) tmp[t] += tmp[t + off];
        __syncthreads();
    }
    if (t == 0) bsum[blockIdx.x] = tmp[0];
}

__global__ void k_scan_top(int* __restrict__ bsum, int nb) {
    __shared__ int tmp[1024];
    int t = threadIdx.x;
    int v = (t < nb) ? bsum[t] : 0;
    tmp[t] = v;
    __syncthreads();
    for (int off = 1; off < 1024; off <<= 1) {
        int a = (t >= off) ? tmp[t - off] : 0;
        __syncthreads();
        tmp[t] += a;
        __syncthreads();
    }
    if (t < nb) bsum[t] = tmp[t] - v;  // exclusive
}

__global__ void k_scan_apply(const int* __restrict__ cnt, const int* __restrict__ bsum,
                             int* __restrict__ rowptr, int n) {
    __shared__ int tmp[256];
    int t = threadIdx.x;
    int i = blockIdx.x * 256 + t;
    int v = (i < n) ? cnt[i] : 0;
    tmp[t] = v;
    __syncthreads();
    for (int off = 1; off < 256; off <<= 1) {
        int a = (t >= off) ? tmp[t - off] : 0;
        __syncthreads();
        tmp[t] += a;
        __syncthreads();
    }
    int excl = tmp[t] - v + bsum[blockIdx.x];
    if (i < n) rowptr[i] = excl;
    if (i == n - 1) rowptr[n] = excl + v;
}

// cursor aliases the (consumed) cnt buffer — re-zeroed before this kernel.
__global__ void k_fill(const int* __restrict__ src, const int* __restrict__ dst,
                       const int* __restrict__ rowptr, int* __restrict__ cursor,
                       int* __restrict__ col, int e) {
    int i = blockIdx.x * 256 + threadIdx.x;
    if (i < e) {
        int d = dst[i];
        int p = rowptr[d] + atomicAdd(&cursor[d], 1);
        col[p] = src[i];
    }
}

// ---------------------------------------------------------------------------
// Segment boundaries from a SORTED segment array.
// ---------------------------------------------------------------------------
__global__ void k_gbound(const int* __restrict__ seg, int n, int nseg,
                         int* __restrict__ gstart) {
    int i = blockIdx.x * 256 + threadIdx.x;
    if (i >= n) return;
    int s = seg[i];
    if (i == 0) {
        for (int g = 0; g <= s; ++g) gstart[g] = 0;
    } else {
        int p = seg[i - 1];
        for (int g = p + 1; g <= s; ++g) gstart[g] = i;
    }
    if (i == n - 1) {
        for (int g = s + 1; g <= nseg; ++g) gstart[g] = n;
    }
}

// ---------------------------------------------------------------------------
// Merge pos/neg subgraph inputs into one batched problem.
// ---------------------------------------------------------------------------
__global__ void k_merge(const float* __restrict__ px, const float* __restrict__ nx,
                        const int* __restrict__ pei, const int* __restrict__ nei,
                        const int* __restrict__ pb, const int* __restrict__ nbt,
                        float* __restrict__ mx, int* __restrict__ msrc,
                        int* __restrict__ mdst, int* __restrict__ mb) {
    int stride = gridDim.x * 256;
    for (int i = blockIdx.x * 256 + threadIdx.x; i < N_SUB * F_IN; i += stride) {
        mx[i] = px[i];
        mx[(size_t)N_SUB * F_IN + i] = nx[i];
    }
    for (int i = blockIdx.x * 256 + threadIdx.x; i < E_SUB; i += stride) {
        msrc[i] = pei[i];
        mdst[i] = pei[E_SUB + i];
        msrc[E_SUB + i] = nei[i] + N_SUB;
        mdst[E_SUB + i] = nei[E_SUB + i] + N_SUB;
    }
    for (int i = blockIdx.x * 256 + threadIdx.x; i < N_SUB; i += stride) {
        mb[i] = pb[i];
        mb[N_SUB + i] = nbt[i] + N_GRAPHS;
    }
}

// ---------------------------------------------------------------------------
// Gather v5 (dual-chain rotated pipeline; float2/lane).  Kept for the two
// fp32-input layer-0 sites (M=38).
// ---------------------------------------------------------------------------
template <typename TI, typename TO, int PPN>
__global__ __launch_bounds__(256) void k_gather5(
    const TI* __restrict__ h, const float* __restrict__ dinv,
    const int* __restrict__ rowptr, const int* __restrict__ col,
    TO* __restrict__ o, int n, int M2, int S2,
    const float* __restrict__ bias, int relu)
{
    const int NPW = 64 / PPN;  // lane-groups per wave
    int g0 = threadIdx.x / PPN;
    int pr = threadIdx.x % PPN;
    int nA = (blockIdx.x * 4 + threadIdx.y) * (2 * NPW) + g0 * 2;
    if (nA >= n) return;
    int nB = nA + 1;
    bool okB = nB < n;
    bool pld = pr < M2, pst = pr < S2;

    int2 rp = *(const int2*)(rowptr + nA);
    float diA = dinv[nA];
    float diB = okB ? dinv[nB] : 0.f;
    float2 vsA = make_float2(0.f, 0.f), vsB = make_float2(0.f, 0.f);
    if (pld) {
        vsA = ldf2(h, (size_t)nA * M2 + pr);
        if (okB) vsB = ldf2(h, (size_t)nB * M2 + pr);
    }
    int peB = okB ? rowptr[nA + 2] : rp.y;

    int pA = rp.x, peA = rp.y;
    int pB = peA;  // rowptr[nB] == rowptr[nA+1]

    int sA1 = 0, sB1 = 0;
    float dA0 = 0.f, dB0 = 0.f;
    float2 vA0 = make_float2(0.f, 0.f), vB0 = make_float2(0.f, 0.f);

    if (pA < peA) {
        int s0 = col[pA];
        sA1 = (pA + 1 < peA) ? col[pA + 1] : 0;
        dA0 = dinv[s0];
        if (pld) vA0 = ldf2(h, (size_t)s0 * M2 + pr);
    }
    if (pB < peB) {
        int s0 = col[pB];
        sB1 = (pB + 1 < peB) ? col[pB + 1] : 0;
        dB0 = dinv[s0];
        if (pld) vB0 = ldf2(h, (size_t)s0 * M2 + pr);
    }

    float2 accA, accB;
    accA.x = diA * diA * vsA.x; accA.y = diA * diA * vsA.y;
    accB.x = diB * diB * vsB.x; accB.y = diB * diB * vsB.y;

    while (pA < peA && pB < peB) {
        int sA2 = (pA + 2 < peA) ? col[pA + 2] : 0;
        int sB2 = (pB + 2 < peB) ? col[pB + 2] : 0;
        float2 vA1 = (pA + 1 < peA && pld) ? ldf2(h, (size_t)sA1 * M2 + pr)
                                           : make_float2(0.f, 0.f);
        float2 vB1 = (pB + 1 < peB && pld) ? ldf2(h, (size_t)sB1 * M2 + pr)
                                           : make_float2(0.f, 0.f);
        float dA1 = (pA + 1 < peA) ? dinv[sA1] : 0.f;
        float dB1 = (pB + 1 < peB) ? dinv[sB1] : 0.f;
        float cfA = dA0 * diA, cfB = dB0 * diB;
        accA.x += cfA * vA0.x; accA.y += cfA * vA0.y;
        accB.x += cfB * vB0.x; accB.y += cfB * vB0.y;
        sA1 = sA2; vA0 = vA1; dA0 = dA1;
        sB1 = sB2; vB0 = vB1; dB0 = dB1;
        ++pA; ++pB;
    }
    while (pA < peA) {
        int sA2 = (pA + 2 < peA) ? col[pA + 2] : 0;
        float2 vA1 = (pA + 1 < peA && pld) ? ldf2(h, (size_t)sA1 * M2 + pr)
                                           : make_float2(0.f, 0.f);
        float dA1 = (pA + 1 < peA) ? dinv[sA1] : 0.f;
        float cfA = dA0 * diA;
        accA.x += cfA * vA0.x; accA.y += cfA * vA0.y;
        sA1 = sA2; vA0 = vA1; dA0 = dA1; ++pA;
    }
    while (pB < peB) {
        int sB2 = (pB + 2 < peB) ? col[pB + 2] : 0;
        float2 vB1 = (pB + 1 < peB && pld) ? ldf2(h, (size_t)sB1 * M2 + pr)
                                           : make_float2(0.f, 0.f);
        float dB1 = (pB + 1 < peB) ? dinv[sB1] : 0.f;
        float cfB = dB0 * diB;
        accB.x += cfB * vB0.x; accB.y += cfB * vB0.y;
        sB1 = sB2; vB0 = vB1; dB0 = dB1; ++pB;
    }

    if (pst) {
        float2 rA = accA;
        if (bias && pld) { rA.x += bias[2 * pr]; rA.y += bias[2 * pr + 1]; }
        if (relu) { rA.x = fmaxf(rA.x, 0.f); rA.y = fmaxf(rA.y, 0.f); }
        stf2(o, (size_t)nA * S2 + pr, rA);
        if (okB) {
            float2 rB = accB;
            if (bias && pld) { rB.x += bias[2 * pr]; rB.y += bias[2 * pr + 1]; }
            if (relu) { rB.x = fmaxf(rB.x, 0.f); rB.y = fmaxf(rB.y, 0.f); }
            stf2(o, (size_t)nB * S2 + pr, rB);
        }
    }
}

template <typename TI, typename TO>
static void launch_gather(const TI* h, const float* dinv, const int* rowptr,
                          const int* col, TO* o, int n, int M, int Sout,
                          const float* bias, int relu, hipStream_t stream) {
    dim3 b(64, 4);
    int M2 = M >> 1, S2 = Sout >> 1;
    if (S2 > 32)
        k_gather5<TI, TO, 64><<<cdiv(n, 8), b, 0, stream>>>(h, dinv, rowptr, col, o,
                                                            n, M2, S2, bias, relu);
    else
        k_gather5<TI, TO, 32><<<cdiv(n, 16), b, 0, stream>>>(h, dinv, rowptr, col, o,
                                                             n, M2, S2, bias, relu);
}

// ---------------------------------------------------------------------------
// Gather v6 (bf16 in, 16 B/lane): LPR lanes cover one row (LPR*8 = W cols),
// 64/LPR dual-chain lane-groups per wave; rotated pipeline.
// ---------------------------------------------------------------------------
template <typename TO, int LPR>
__global__ __launch_bounds__(256) void k_gather6(
    const bf16* __restrict__ h, const float* __restrict__ dinv,
    const int* __restrict__ rowptr, const int* __restrict__ col,
    TO* __restrict__ o, int n, const float* __restrict__ bias, int relu)
{
    const int W = LPR * 8;
    const int NG = 64 / LPR;
    const int g = threadIdx.x / LPR;
    const int c0 = (threadIdx.x % LPR) * 8;
    const int nA = (blockIdx.x * 4 + threadIdx.y) * (2 * NG) + g * 2;
    const int nB = nA + 1;
    if (nA >= n) return;           // group-uniform
    const bool okB = nB < n;

    int2 rp = *(const int2*)(rowptr + nA);
    int peB = okB ? rowptr[nB + 1] : rp.y;
    float diA = dinv[nA];
    float diB = okB ? dinv[nB] : 0.f;
    short8 zed = {0, 0, 0, 0, 0, 0, 0, 0};
    short8 slA = *(const short8*)(h + (size_t)nA * W + c0);
    short8 slB = okB ? *(const short8*)(h + (size_t)nB * W + c0) : zed;

    int pA = rp.x, peA = rp.y;
    int pB = rp.y;

    float accA[8], accB[8];
    float qA = diA * diA, qB = diB * diB;
#pragma unroll
    for (int j = 0; j < 8; ++j) {
        accA[j] = qA * bits2f(slA[j]);
        accB[j] = qB * bits2f(slB[j]);
    }

    // rotated pipeline state
    int sA1 = 0, sB1 = 0;
    float dA0 = 0.f, dB0 = 0.f;
    short8 vA0 = zed, vB0 = zed;
    if (pA < peA) {
        int s0 = col[pA];
        sA1 = (pA + 1 < peA) ? col[pA + 1] : 0;
        dA0 = dinv[s0];
        vA0 = *(const short8*)(h + (size_t)s0 * W + c0);
    }
    if (pB < peB) {
        int s0 = col[pB];
        sB1 = (pB + 1 < peB) ? col[pB + 1] : 0;
        dB0 = dinv[s0];
        vB0 = *(const short8*)(h + (size_t)s0 * W + c0);
    }

    while (__any(pA < peA || pB < peB)) {
        if (pA < peA) {
            int sA2 = (pA + 2 < peA) ? col[pA + 2] : 0;
            short8 vA1 = zed;
            float dA1 = 0.f;
            if (pA + 1 < peA) {
                vA1 = *(const short8*)(h + (size_t)sA1 * W + c0);
                dA1 = dinv[sA1];
            }
            float cf = dA0 * diA;
#pragma unroll
            for (int j = 0; j < 8; ++j) accA[j] += cf * bits2f(vA0[j]);
            vA0 = vA1; dA0 = dA1; sA1 = sA2; ++pA;
        }
        if (pB < peB) {
            int sB2 = (pB + 2 < peB) ? col[pB + 2] : 0;
            short8 vB1 = zed;
            float dB1 = 0.f;
            if (pB + 1 < peB) {
                vB1 = *(const short8*)(h + (size_t)sB1 * W + c0);
                dB1 = dinv[sB1];
            }
            float cf = dB0 * diB;
#pragma unroll
            for (int j = 0; j < 8; ++j) accB[j] += cf * bits2f(vB0[j]);
            vB0 = vB1; dB0 = dB1; sB1 = sB2; ++pB;
        }
    }

    float bv[8];
#pragma unroll
    for (int j = 0; j < 8; ++j) bv[j] = 0.f;
    if (bias) {
        float4 b0 = *(const float4*)(bias + c0);
        float4 b1 = *(const float4*)(bias + c0 + 4);
        bv[0] = b0.x; bv[1] = b0.y; bv[2] = b0.z; bv[3] = b0.w;
        bv[4] = b1.x; bv[5] = b1.y; bv[6] = b1.z; bv[7] = b1.w;
    }

    auto store_row = [&](int node, float* acc) {
        float r[8];
#pragma unroll
        for (int j = 0; j < 8; ++j) {
            r[j] = acc[j] + bv[j];
            if (relu) r[j] = fmaxf(r[j], 0.f);
        }
        size_t off = (size_t)node * W + c0;
        if constexpr (sizeof(TO) == 2) {
            short8 pk;
#pragma unroll
            for (int j = 0; j < 8; ++j) pk[j] = bf16bits(r[j]);
            *(short8*)((bf16*)o + off) = pk;
        } else {
            float4 f0 = {r[0], r[1], r[2], r[3]};
            float4 f1 = {r[4], r[5], r[6], r[7]};
            *(float4*)((float*)o + off) = f0;
            *(float4*)((float*)o + off + 4) = f1;
        }
    };
    store_row(nA, accA);
    if (okB) store_row(nB, accB);
}

template <typename TO>
static void launch_gather6(const bf16* h, const float* dinv, const int* rowptr,
                           const int* col, TO* o, int n, int W,
                           const float* bias, int relu, hipStream_t stream) {
    dim3 b(64, 4);
    if (W == 128)
        k_gather6<TO, 16><<<cdiv(n, 32), b, 0, stream>>>(h, dinv, rowptr, col, o, n,
                                                         bias, relu);
    else
        k_gather6<TO, 8><<<cdiv(n, 64), b, 0, stream>>>(h, dinv, rowptr, col, o, n,
                                                        bias, relu);
}

// ---------------------------------------------------------------------------
// W pre-pack into MFMA fragment layout (bf16), all 8 weights in ONE launch:
//   Wb[((s*Mp) + n)*32 + kk] = W[s*32+kk][n]   (zero-padded k>=K or n>=M)
// ---------------------------------------------------------------------------
template <int K, int M, int Mp>
__device__ inline void wpack1(const float* __restrict__ W, bf16* __restrict__ o, int j) {
    int kk = j & 31;
    int rem = j >> 5;
    int ncol = rem % Mp;
    int s = rem / Mp;
    int k = s * 32 + kk;
    float v = (k < K && ncol < M) ? W[(size_t)k * M + ncol] : 0.f;
    o[j] = __float2bfloat16(v);
}

__global__ void k_wpack_all(const float* __restrict__ eW0, const float* __restrict__ eW1,
                            const float* __restrict__ eW2, const float* __restrict__ dW0,
                            const float* __restrict__ dW1, const float* __restrict__ dW2,
                            const float* __restrict__ sW0, const float* __restrict__ sW1,
                            bf16* __restrict__ arena) {
    for (int i = blockIdx.x * 256 + threadIdx.x; i < 159744; i += gridDim.x * 256) {
        if (i < 16384)       wpack1<38, 256, 256>(eW0, arena, i);
        else if (i < 49152)  wpack1<256, 128, 128>(eW1, arena + 16384, i - 16384);
        else if (i < 57344)  wpack1<128, 64, 64>(eW2, arena + 49152, i - 49152);
        else if (i < 65536)  wpack1<64, 128, 128>(dW0, arena + 57344, i - 57344);
        else if (i < 98304)  wpack1<128, 256, 256>(dW1, arena + 65536, i - 65536);
        else if (i < 110592) wpack1<256, 38, 48>(dW2, arena + 98304, i - 98304);
        else if (i < 126976) wpack1<38, 256, 256>(sW0, arena + 110592, i - 110592);
        else                 wpack1<256, 128, 128>(sW1, arena + 126976, i - 126976);
    }
}

// ---------------------------------------------------------------------------
// Fold global BN into weights:  W'[k,j] = sc[k]*W[k,j] packed to MFMA layout;
// b'[j] = -sum_k mu[k]*sc[k]*W[k,j]  (all fp32 math).  bn(A)@W == A@W' + b'.
// ---------------------------------------------------------------------------
template <int K, int M, int Mp>
__global__ void k_wfold(const float* __restrict__ W, const float* __restrict__ mu,
                        const float* __restrict__ sc, bf16* __restrict__ Wb,
                        float* __restrict__ bout) {
    const int tot = (K / 32) * Mp * 32;
    for (int i = blockIdx.x * 256 + threadIdx.x; i < tot; i += gridDim.x * 256) {
        int kk = i & 31;
        int rem = i >> 5;
        int ncol = rem % Mp;
        int s = rem / Mp;
        int k = s * 32 + kk;
        float v = (k < K && ncol < M) ? sc[k] * W[(size_t)k * M + ncol] : 0.f;
        Wb[i] = __float2bfloat16(v);
    }
    if (blockIdx.x == 0 && threadIdx.x < M) {
        int j = threadIdx.x;
        float s = 0.f;
        for (int k = 0; k < K; ++k) s -= mu[k] * sc[k] * W[(size_t)k * M + j];
        bout[j] = s;
    }
}

// ---------------------------------------------------------------------------
// MFMA GEMM v5:  C = act( bn(A) @ W + bias )
// R7 evidence: sched_group_barrier is the ONLY thing this compiler honors for
// load clustering (decoder left the top-5 after SGB; source batching left
// VGPR at 72 = serial loads).  Window weight loads in groups of <=8 + SGB
// (VMEM_READ then MFMA) per window.  Live regs: acc<=64 + wfv 32 + af<=32
// ~ 130 < the (256,3) cap (~168) -> no R6-style spill.
//   BNM: 0 = none (global BN pre-folded into W); 2 = per-segment tables.
// ---------------------------------------------------------------------------
template <typename TC, int NT, int S, int BNM>
__global__ __launch_bounds__(256, 3) void k_mfma_gemm(
    const bf16* __restrict__ A, const bf16* __restrict__ Wb,
    TC* __restrict__ C, int M, int MC,
    const float* __restrict__ bias, int act,
    const float* __restrict__ mu, const float* __restrict__ sc,
    const int* __restrict__ seg)
{
    const int SA = S * 32;
    const int Mp = NT * 16;
    const int WW = (NT > 8) ? 8 : NT;   // load-window size
    const int lane = threadIdx.x;
    const int wave = threadIdx.y;
    const int row0 = blockIdx.x * 64 + wave * 16;
    const int qr = lane >> 4;
    const int lc = lane & 15;

    // batch-load all A fragments (S loads in flight)
    short8 af[S];
    {
        const bf16* arow = A + (size_t)(row0 + lc) * SA + qr * 8;
#pragma unroll
        for (int s = 0; s < S; ++s) af[s] = *(const short8*)(arow + s * 32);
    }
    if (BNM == 2) {
        size_t bnbase = (size_t)seg[row0 + lc] * SA;
#pragma unroll
        for (int s = 0; s < S; ++s) {
            int kb = s * 32 + qr * 8;
            const float* mp = mu + bnbase + kb;
            const float* sp = sc + bnbase + kb;
            float4 m0 = *(const float4*)mp, m1 = *(const float4*)(mp + 4);
            float4 s0 = *(const float4*)sp, s1 = *(const float4*)(sp + 4);
            float av[8];
#pragma unroll
            for (int j = 0; j < 8; ++j) av[j] = bits2f(af[s][j]);
            av[0] = (av[0] - m0.x) * s0.x; av[1] = (av[1] - m0.y) * s0.y;
            av[2] = (av[2] - m0.z) * s0.z; av[3] = (av[3] - m0.w) * s0.w;
            av[4] = (av[4] - m1.x) * s1.x; av[5] = (av[5] - m1.y) * s1.y;
            av[6] = (av[6] - m1.z) * s1.z; av[7] = (av[7] - m1.w) * s1.w;
#pragma unroll
            for (int j = 0; j < 8; ++j) af[s][j] = bf16bits(av[j]);
        }
    }

    float4v acc[NT];
#pragma unroll
    for (int t = 0; t < NT; ++t) acc[t] = (float4v){0.f, 0.f, 0.f, 0.f};

    const bf16* wrow = Wb + (size_t)lc * 32 + qr * 8;
#pragma unroll
    for (int s = 0; s < S; ++s) {
#pragma unroll
        for (int h = 0; h < NT / WW; ++h) {
            short8 wfv[WW];
#pragma unroll
            for (int tt = 0; tt < WW; ++tt)
                wfv[tt] = *(const short8*)(wrow + ((size_t)s * Mp + (h * WW + tt) * 16) * 32);
#pragma unroll
            for (int tt = 0; tt < WW; ++tt)
                acc[h * WW + tt] =
                    __builtin_amdgcn_mfma_f32_16x16x32_bf16(wfv[tt], af[s], acc[h * WW + tt], 0, 0, 0);
            __builtin_amdgcn_sched_group_barrier(0x020, WW, 0);  // WW VMEM reads
            __builtin_amdgcn_sched_group_barrier(0x008, WW, 0);  // WW MFMAs
        }
    }

    const int row = row0 + lc;
#pragma unroll
    for (int t = 0; t < NT; ++t) {
        int c0 = t * 16 + qr * 4;
        if (c0 >= M) continue;
        float v[4];
#pragma unroll
        for (int r = 0; r < 4; ++r) v[r] = acc[t][r];
        if (bias) {
            if (c0 + 3 < M) {
                float4 bv = *(const float4*)(bias + c0);
                v[0] += bv.x; v[1] += bv.y; v[2] += bv.z; v[3] += bv.w;
            } else {
#pragma unroll
                for (int r = 0; r < 4; ++r) if (c0 + r < M) v[r] += bias[c0 + r];
            }
        }
#pragma unroll
        for (int r = 0; r < 4; ++r) {
            if (act == 1) v[r] = fmaxf(v[r], 0.f);
            else if (act == 2) v[r] = 1.f / (1.f + expf(-v[r]));
        }
        if (c0 + 3 < M) {
            if constexpr (sizeof(TC) == 2) {
                short4v pk = {bf16bits(v[0]), bf16bits(v[1]), bf16bits(v[2]), bf16bits(v[3])};
                *(short4v*)((bf16*)C + (size_t)row * MC + c0) = pk;
            } else {
                stf2((float*)C, ((size_t)row * MC + c0) >> 1, make_float2(v[0], v[1]));
                stf2((float*)C, ((size_t)row * MC + c0 + 2) >> 1, make_float2(v[2], v[3]));
            }
        } else {
#pragma unroll
            for (int r = 0; r < 4; ++r)
                if (c0 + r < M) stf(C, (size_t)row * MC + c0 + r, v[r]);
        }
    }
}

template <typename TC, int BNM>
static void launch_mfma(const bf16* A, const bf16* Wb, TC* C, int n, int SA,
                        int Mp, int M, int MC, const float* bias, int act,
                        const float* mu, const float* sc, const int* seg,
                        hipStream_t stream) {
    dim3 b(64, 4);
    int g = n / 64;
    if (SA == 64 && Mp == 256)
        k_mfma_gemm<TC, 16, 2, BNM><<<g, b, 0, stream>>>(A, Wb, C, M, MC, bias, act, mu, sc, seg);
    else if (SA == 256 && Mp == 128)
        k_mfma_gemm<TC, 8, 8, BNM><<<g, b, 0, stream>>>(A, Wb, C, M, MC, bias, act, mu, sc, seg);
    else if (SA == 128 && Mp == 64)
        k_mfma_gemm<TC, 4, 4, BNM><<<g, b, 0, stream>>>(A, Wb, C, M, MC, bias, act, mu, sc, seg);
}

// ---------------------------------------------------------------------------
// L0 stats (R5-proven version, unchanged — timed runs fine; R6 batched
// variant spilled catastrophically).
// ---------------------------------------------------------------------------
__global__ __launch_bounds__(256) void k_l0stats(
    const bf16* __restrict__ Y0, const bf16* __restrict__ W0b,
    const float* __restrict__ b0, float* __restrict__ sum,
    float* __restrict__ sumsq, int ntiles)
{
    __shared__ float ls[4][512];
    const int lane = threadIdx.x;
    const int wave = threadIdx.y;
    const int lc = lane & 15, qr = lane >> 4;

    float bv[16];
#pragma unroll
    for (int t = 0; t < 16; ++t) bv[t] = b0[t * 16 + lc];

    float sReg[16], qReg[16];
#pragma unroll
    for (int t = 0; t < 16; ++t) { sReg[t] = 0.f; qReg[t] = 0.f; }

    for (int tile = blockIdx.x; tile < ntiles; tile += gridDim.x) {
        const int row0 = tile * 64 + wave * 16;
        const bf16* arow = Y0 + (size_t)(row0 + lc) * 64 + qr * 8;
        float4v acc[16];
#pragma unroll
        for (int t = 0; t < 16; ++t) acc[t] = (float4v){0.f, 0.f, 0.f, 0.f};
#pragma unroll
        for (int s = 0; s < 2; ++s) {
            short8 af = *(const short8*)(arow + s * 32);
#pragma unroll
            for (int t = 0; t < 16; ++t) {
                short8 wf = *(const short8*)(W0b + ((size_t)(s * 256 + t * 16 + lc)) * 32 + qr * 8);
                // UNSWAPPED: lane owns col t*16+lc, rows qr*4+r
                acc[t] = __builtin_amdgcn_mfma_f32_16x16x32_bf16(af, wf, acc[t], 0, 0, 0);
            }
        }
#pragma unroll
        for (int t = 0; t < 16; ++t) {
            float s4 = 0.f, q4 = 0.f;
#pragma unroll
            for (int r = 0; r < 4; ++r) {
                float v = fmaxf(acc[t][r] + bv[t], 0.f);
                v = bits2f(bf16bits(v));     // match bf16-stored a0 semantics
                s4 += v;
                q4 += v * v;
            }
            s4 += __shfl_xor(s4, 16, 64); s4 += __shfl_xor(s4, 32, 64);
            q4 += __shfl_xor(q4, 16, 64); q4 += __shfl_xor(q4, 32, 64);
            sReg[t] += s4;
            qReg[t] += q4;
        }
    }
    if (lane < 16) {
#pragma unroll
        for (int t = 0; t < 16; ++t) {
            ls[wave][t * 16 + lc] = sReg[t];
            ls[wave][256 + t * 16 + lc] = qReg[t];
        }
    }
    __syncthreads();
    int tid = wave * 64 + lane;
    if (tid < 256) {
        atomicAdd(&sum[tid], ls[0][tid] + ls[1][tid] + ls[2][tid] + ls[3][tid]);
        atomicAdd(&sumsq[tid],
                  ls[0][256 + tid] + ls[1][256 + tid] + ls[2][256 + tid] + ls[3][256 + tid]);
    }
}

// ---------------------------------------------------------------------------
// Fused L0+L1 v3: SGB-forced load clustering (same recipe as decoder, which
// dropped out of the top-5 in R7).  Phase-1 windows of 8 (wfv 32 VGPR live).
// ---------------------------------------------------------------------------
__global__ __launch_bounds__(256, 3) void k_fused01(
    const bf16* __restrict__ Y0, const bf16* __restrict__ W0b,
    const float* __restrict__ b0, const bf16* __restrict__ W1b,
    const float* __restrict__ b1f, bf16* __restrict__ G1, int n)
{
    __shared__ __attribute__((aligned(16))) char lds[4][8192];
    const int lane = threadIdx.x;
    const int wave = threadIdx.y;
    const int lc = lane & 15, qr = lane >> 4;
    const int row0 = blockIdx.x * 64 + wave * 16;
    char* r2 = lds[wave];            // [16][256] bf16, 512B/row
    const int swz = (lc & 7) << 4;

    // ---- phase 1: a0 = relu(Y0@W0 + b0), K=64 (S=2), 256 cols (NT=16) ----
    {
        const bf16* arow = Y0 + (size_t)(row0 + lc) * 64 + qr * 8;
        short8 af0 = *(const short8*)(arow);
        short8 af1 = *(const short8*)(arow + 32);
        float4v acc[16];
#pragma unroll
        for (int t = 0; t < 16; ++t) acc[t] = (float4v){0.f, 0.f, 0.f, 0.f};
#pragma unroll
        for (int s = 0; s < 2; ++s) {
            short8 af = s ? af1 : af0;
#pragma unroll
            for (int h = 0; h < 2; ++h) {
                short8 wfv[8];
#pragma unroll
                for (int tt = 0; tt < 8; ++tt) {
                    int t = h * 8 + tt;
                    wfv[tt] = *(const short8*)(W0b + ((size_t)(s * 256 + t * 16 + lc)) * 32 + qr * 8);
                }
#pragma unroll
                for (int tt = 0; tt < 8; ++tt) {
                    int t = h * 8 + tt;
                    acc[t] = __builtin_amdgcn_mfma_f32_16x16x32_bf16(wfv[tt], af, acc[t], 0, 0, 0);
                }
                __builtin_amdgcn_sched_group_barrier(0x020, 8, 0);  // 8 VMEM reads
                __builtin_amdgcn_sched_group_barrier(0x008, 8, 0);  // 8 MFMAs
            }
        }
#pragma unroll
        for (int t = 0; t < 16; ++t) {
            int c0 = t * 16 + qr * 4;
            float4 bv = *(const float4*)(b0 + c0);
            short4v pk = {bf16bits(fmaxf(acc[t][0] + bv.x, 0.f)),
                          bf16bits(fmaxf(acc[t][1] + bv.y, 0.f)),
                          bf16bits(fmaxf(acc[t][2] + bv.z, 0.f)),
                          bf16bits(fmaxf(acc[t][3] + bv.w, 0.f))};
            int off = lc * 512 + t * 32 + qr * 8;
            *(short4v*)(r2 + (off ^ swz)) = pk;
        }
    }

    // ---- phase 2: G1 = a0 @ W1' + b1', K=256 (S=8), 128 cols (NT=8) ----
    short8 afv[8];
#pragma unroll
    for (int s = 0; s < 8; ++s) {
        int off = lc * 512 + s * 64 + qr * 16;
        afv[s] = *(const short8*)(r2 + (off ^ swz));
    }
    float4v a2[8];
#pragma unroll
    for (int t = 0; t < 8; ++t) a2[t] = (float4v){0.f, 0.f, 0.f, 0.f};
#pragma unroll
    for (int s = 0; s < 8; ++s) {
        short8 wfv[8];
#pragma unroll
        for (int t = 0; t < 8; ++t)
            wfv[t] = *(const short8*)(W1b + ((size_t)(s * 128 + t * 16 + lc)) * 32 + qr * 8);
#pragma unroll
        for (int t = 0; t < 8; ++t)
            a2[t] = __builtin_amdgcn_mfma_f32_16x16x32_bf16(wfv[t], afv[s], a2[t], 0, 0, 0);
        __builtin_amdgcn_sched_group_barrier(0x020, 8, 0);
        __builtin_amdgcn_sched_group_barrier(0x008, 8, 0);
    }
    const int row = row0 + lc;
#pragma unroll
    for (int t = 0; t < 8; ++t) {
        int c0 = t * 16 + qr * 4;
        float4 bv = *(const float4*)(b1f + c0);
        short4v pk = {bf16bits(a2[t][0] + bv.x), bf16bits(a2[t][1] + bv.y),
                      bf16bits(a2[t][2] + bv.z), bf16bits(a2[t][3] + bv.w)};
        *(short4v*)(G1 + (size_t)row * 128 + c0) = pk;
    }
}

// ---------------------------------------------------------------------------
// Fused decoder v3 (R7 form, kept — SGB clustering verified effective).
// ---------------------------------------------------------------------------
__global__ __launch_bounds__(256, 3) void k_decoder(
    const bf16* __restrict__ zb, const bf16* __restrict__ dW0b,
    const bf16* __restrict__ dW1b, const bf16* __restrict__ dW2b,
    float* __restrict__ xrec, int n)
{
    __shared__ __attribute__((aligned(16))) char lds[4][12288];
    const int lane = threadIdx.x;
    const int wave = threadIdx.y;
    const int lc = lane & 15, qr = lane >> 4;
    const int row0 = blockIdx.x * 64 + wave * 16;
    char* r1 = lds[wave];            // [16][128] bf16, 256B/row
    char* r2 = lds[wave] + 4096;     // [16][256] bf16, 512B/row
    const int swz = (lc & 7) << 4;

    // ---- layer 1: relu(zb @ dW0), K=64 (S=2), 128 cols (NT=8) ----
    {
        const bf16* arow = zb + (size_t)(row0 + lc) * 64 + qr * 8;
        short8 af0 = *(const short8*)(arow);
        short8 af1 = *(const short8*)(arow + 32);
        float4v a1[8];
#pragma unroll
        for (int t = 0; t < 8; ++t) a1[t] = (float4v){0.f, 0.f, 0.f, 0.f};
#pragma unroll
        for (int s = 0; s < 2; ++s) {
            short8 af = s ? af1 : af0;
            short8 wfv[8];
#pragma unroll
            for (int t = 0; t < 8; ++t)
                wfv[t] = *(const short8*)(dW0b + ((size_t)(s * 128 + t * 16 + lc)) * 32 + qr * 8);
#pragma unroll
            for (int t = 0; t < 8; ++t)
                a1[t] = __builtin_amdgcn_mfma_f32_16x16x32_bf16(wfv[t], af, a1[t], 0, 0, 0);
            __builtin_amdgcn_sched_group_barrier(0x020, 8, 0);  // 8 VMEM reads
            __builtin_amdgcn_sched_group_barrier(0x008, 8, 0);  // 8 MFMAs
        }
#pragma unroll
        for (int t = 0; t < 8; ++t) {
            short4v pk = {bf16bits(fmaxf(a1[t][0], 0.f)), bf16bits(fmaxf(a1[t][1], 0.f)),
                          bf16bits(fmaxf(a1[t][2], 0.f)), bf16bits(fmaxf(a1[t][3], 0.f))};
            int off = lc * 256 + t * 32 + qr * 8;
            *(short4v*)(r1 + (off ^ swz)) = pk;
        }
    }

    // ---- layer 2: relu(r1 @ dW1), K=128 (S=4), 256 cols (NT=16) ----
    {
        short8 afv[4];
#pragma unroll
        for (int s = 0; s < 4; ++s) {
            int off = lc * 256 + s * 64 + qr * 16;
            afv[s] = *(const short8*)(r1 + (off ^ swz));
        }
        float4v a2[16];
#pragma unroll
        for (int t = 0; t < 16; ++t) a2[t] = (float4v){0.f, 0.f, 0.f, 0.f};
#pragma unroll
        for (int s = 0; s < 4; ++s) {
#pragma unroll
            for (int h = 0; h < 2; ++h) {
                short8 wfv[8];
#pragma unroll
                for (int tt = 0; tt < 8; ++tt) {
                    int t = h * 8 + tt;
                    wfv[tt] = *(const short8*)(dW1b + ((size_t)(s * 256 + t * 16 + lc)) * 32 + qr * 8);
                }
#pragma unroll
                for (int tt = 0; tt < 8; ++tt) {
                    int t = h * 8 + tt;
                    a2[t] = __builtin_amdgcn_mfma_f32_16x16x32_bf16(wfv[tt], afv[s], a2[t], 0, 0, 0);
                }
                __builtin_amdgcn_sched_group_barrier(0x020, 8, 0);
                __builtin_amdgcn_sched_group_barrier(0x008, 8, 0);
            }
        }
#pragma unroll
        for (int t = 0; t < 16; ++t) {
            short4v pk = {bf16bits(fmaxf(a2[t][0], 0.f)), bf16bits(fmaxf(a2[t][1], 0.f)),
                          bf16bits(fmaxf(a2[t][2], 0.f)), bf16bits(fmaxf(a2[t][3], 0.f))};
            int off = lc * 512 + t * 32 + qr * 8;
            *(short4v*)(r2 + (off ^ swz)) = pk;
        }
    }

    // ---- layer 3: sigmoid(r2 @ dW2), K=256 (S=8), 38 cols (NT=3, Mp=48) ----
    short8 afv[8];
#pragma unroll
    for (int s = 0; s < 8; ++s) {
        int off = lc * 512 + s * 64 + qr * 16;
        afv[s] = *(const short8*)(r2 + (off ^ swz));
    }
    float4v a3[3];
#pragma unroll
    for (int t = 0; t < 3; ++t) a3[t] = (float4v){0.f, 0.f, 0.f, 0.f};
#pragma unroll
    for (int s = 0; s < 8; ++s) {
        short8 wfv[3];
#pragma unroll
        for (int t = 0; t < 3; ++t)
            wfv[t] = *(const short8*)(dW2b + ((size_t)(s * 48 + t * 16 + lc)) * 32 + qr * 8);
#pragma unroll
        for (int t = 0; t < 3; ++t)
            a3[t] = __builtin_amdgcn_mfma_f32_16x16x32_bf16(wfv[t], afv[s], a3[t], 0, 0, 0);
        __builtin_amdgcn_sched_group_barrier(0x020, 3, 0);
        __builtin_amdgcn_sched_group_barrier(0x008, 3, 0);
    }
    float* orow = xrec + (size_t)(row0 + lc) * 38;
#pragma unroll
    for (int t = 0; t < 3; ++t) {
        int c0 = t * 16 + qr * 4;
        float v0 = 1.f / (1.f + expf(-a3[t][0]));
        float v1 = 1.f / (1.f + expf(-a3[t][1]));
        float v2 = 1.f / (1.f + expf(-a3[t][2]));
        float v3 = 1.f / (1.f + expf(-a3[t][3]));
        if (c0 + 1 < 38) *(float2*)(orow + c0) = make_float2(v0, v1);
        if (c0 + 3 < 38) *(float2*)(orow + c0 + 2) = make_float2(v2, v3);
    }
}

// ---------------------------------------------------------------------------
// LDS-tiled fp32 vector GEMM (t-MLP / classifier — tiny n, precision-tight)
// ---------------------------------------------------------------------------
template <typename TA, typename TC, int NJ>
__global__ __launch_bounds__(256) void k_gemm(
    const TA* __restrict__ A, const float* __restrict__ W,
    TC* __restrict__ C, int n, int K, int M,
    const float* __restrict__ bias, int act,
    const float* __restrict__ mu, const float* __restrict__ sc)
{
    __shared__ float alds[64 * 32];
    __shared__ float wlds[32 * 256];
    const int l = threadIdx.x;
    const int wy = threadIdx.y;
    const int tid = wy * 64 + l;
    const int row0 = blockIdx.x * 64;

    float acc[16][NJ];
#pragma unroll
    for (int r = 0; r < 16; ++r)
#pragma unroll
        for (int j = 0; j < NJ; ++j) acc[r][j] = 0.f;

    int cidx[NJ]; bool jval[NJ];
#pragma unroll
    for (int j = 0; j < NJ; ++j) {
        cidx[j] = l + 64 * j;
        jval[j] = cidx[j] < M;
    }

    for (int k0 = 0; k0 < K; k0 += 32) {
        int kt = min(32, K - k0);
        __syncthreads();
        for (int i = tid; i < 64 * 32; i += 256) {
            int r = i >> 5, kk = i & 31;
            int row = row0 + r, k = k0 + kk;
            float v = (row < n && k < K) ? ldf(A, (size_t)row * K + k) : 0.f;
            if (mu && k < K) v = (v - mu[k]) * sc[k];
            alds[i] = v;
        }
        for (int i = tid; i < kt * M; i += 256)
            wlds[i] = W[(size_t)k0 * M + i];
        if (kt < 32)
            for (int i = kt * M + tid; i < 32 * M; i += 256) wlds[i] = 0.f;
        __syncthreads();

#pragma unroll 2
        for (int kkg = 0; kkg < 8; ++kkg) {
            float wv[4][NJ];
#pragma unroll
            for (int q = 0; q < 4; ++q)
#pragma unroll
                for (int j = 0; j < NJ; ++j)
                    wv[q][j] = jval[j] ? wlds[(kkg * 4 + q) * M + cidx[j]] : 0.f;
#pragma unroll
            for (int rr = 0; rr < 16; ++rr) {
                const float4* arow = (const float4*)&alds[(wy * 16 + rr) * 32];
                float4 av = arow[kkg];
#pragma unroll
                for (int j = 0; j < NJ; ++j) {
                    acc[rr][j] += av.x * wv[0][j];
                    acc[rr][j] += av.y * wv[1][j];
                    acc[rr][j] += av.z * wv[2][j];
                    acc[rr][j] += av.w * wv[3][j];
                }
            }
        }
    }

#pragma unroll
    for (int rr = 0; rr < 16; ++rr) {
        int row = row0 + wy * 16 + rr;
        if (row >= n) continue;
#pragma unroll
        for (int j = 0; j < NJ; ++j) {
            if (!jval[j]) continue;
            float v = acc[rr][j];
            if (bias) v += bias[cidx[j]];
            if (act == 1) v = fmaxf(v, 0.f);
            else if (act == 2) v = 1.f / (1.f + expf(-v));
            stf(C, (size_t)row * M + cidx[j], v);
        }
    }
}

// ---------------------------------------------------------------------------
// BatchNorm stats: vectorized 8-col loads, LDS-staged atomics.
// ---------------------------------------------------------------------------
template <typename T>
__global__ __launch_bounds__(256) void k_bn_stats8(
    const T* __restrict__ x, int n, int M,
    float* __restrict__ sum, float* __restrict__ sumsq)
{
    __shared__ float ls[512];
    int t = threadIdx.x;
    for (int i = t; i < 2 * M; i += 256) ls[i] = 0.f;
    __syncthreads();

    int gpr = M >> 3;           // col-groups per row
    int c8 = (t % gpr) * 8;
    int g = t / gpr;
    int rpb = 256 / gpr;

    float s[8], q[8];
#pragma unroll
    for (int j = 0; j < 8; ++j) { s[j] = 0.f; q[j] = 0.f; }

    for (int r = blockIdx.x * rpb + g; r < n; r += gridDim.x * rpb) {
        float v[8];
        if constexpr (sizeof(T) == 2) {
            short8 v8 = *(const short8*)((const bf16*)x + (size_t)r * M + c8);
#pragma unroll
            for (int j = 0; j < 8; ++j) v[j] = bits2f(v8[j]);
        } else {
            float4 f0 = *(const float4*)((const float*)x + (size_t)r * M + c8);
            float4 f1 = *(const float4*)((const float*)x + (size_t)r * M + c8 + 4);
            v[0] = f0.x; v[1] = f0.y; v[2] = f0.z; v[3] = f0.w;
            v[4] = f1.x; v[5] = f1.y; v[6] = f1.z; v[7] = f1.w;
        }
#pragma unroll
        for (int j = 0; j < 8; ++j) { s[j] += v[j]; q[j] += v[j] * v[j]; }
    }
#pragma unroll
    for (int j = 0; j < 8; ++j) {
        atomicAdd(&ls[c8 + j], s[j]);
        atomicAdd(&ls[M + c8 + j], q[j]);
    }
    __syncthreads();
    for (int i = t; i < M; i += 256) {
        atomicAdd(&sum[i], ls[i]);
        atomicAdd(&sumsq[i], ls[M + i]);
    }
}

__global__ void k_bn_fin(float* __restrict__ sum, float* __restrict__ sumsq, int n, int M) {
    int c = threadIdx.x;
    if (c < M) {
        float m = sum[c] / (float)n;
        float v = fmaxf(sumsq[c] / (float)n - m * m, 0.f);
        sum[c] = m;
        sumsq[c] = rsqrtf(v + BN_EPS);
    }
}

// ---------------------------------------------------------------------------
// Wave-per-segment BN stats (sorted seg, boundaries precomputed): writes
// mu/sc DIRECTLY.  No atomics, no zero-fill, no fin pass.  M = 64*CPL.
// ---------------------------------------------------------------------------
template <int CPL>
__global__ __launch_bounds__(256) void k_segbn(
    const bf16* __restrict__ x, const int* __restrict__ gstart, int nseg,
    float* __restrict__ mu, float* __restrict__ sc)
{
    const int M = 64 * CPL;
    int s = blockIdx.x * 4 + threadIdx.y;
    if (s >= nseg) return;
    int l = threadIdx.x;
    int gs = gstart[s], ge = gstart[s + 1];
    float sum[CPL], sq[CPL];
#pragma unroll
    for (int j = 0; j < CPL; ++j) { sum[j] = 0.f; sq[j] = 0.f; }
    for (int r = gs; r < ge; ++r) {
        const bf16* px = x + (size_t)r * M + l * CPL;
        if constexpr (CPL == 4) {
            short4v v4 = *(const short4v*)px;
#pragma unroll
            for (int j = 0; j < 4; ++j) {
                float v = bits2f(v4[j]);
                sum[j] += v; sq[j] += v * v;
            }
        } else {
            __hip_bfloat162 v2 = *(const __hip_bfloat162*)px;
            float v0 = __bfloat162float(v2.x), v1 = __bfloat162float(v2.y);
            sum[0] += v0; sq[0] += v0 * v0;
            sum[1] += v1; sq[1] += v1 * v1;
        }
    }
    float c = fmaxf((float)(ge - gs), 1.f);
#pragma unroll
    for (int j = 0; j < CPL; ++j) {
        float m = sum[j] / c;
        float v = fmaxf(sq[j] / c - m * m, 0.f);
        mu[(size_t)s * M + l * CPL + j] = m;
        sc[(size_t)s * M + l * CPL + j] = rsqrtf(v + BN_EPS);
    }
}

// ---------------------------------------------------------------------------
// Wave-per-segment mean pool over 64-col fp32 rows (input pre-normalized).
// ---------------------------------------------------------------------------
__global__ __launch_bounds__(256) void k_pool(
    const float* __restrict__ z, const int* __restrict__ gstart, int nseg,
    float* __restrict__ o)
{
    int s = blockIdx.x * 4 + threadIdx.y;
    if (s >= nseg) return;
    int l = threadIdx.x;
    int gs = gstart[s], ge = gstart[s + 1];
    float acc = 0.f;
    for (int r = gs; r < ge; ++r) acc += z[(size_t)r * 64 + l];
    o[(size_t)s * 64 + l] = acc / fmaxf((float)(ge - gs), 1.f);
}

// ---------------------------------------------------------------------------
// Wave-per-segment fused l2norm + mean pool (sub path: zs is only pooled).
// ---------------------------------------------------------------------------
__global__ __launch_bounds__(256) void k_l2pool(
    const float* __restrict__ zs, const int* __restrict__ gstart, int nseg,
    float* __restrict__ o)
{
    int s = blockIdx.x * 4 + threadIdx.y;
    if (s >= nseg) return;
    int l = threadIdx.x;
    int gs = gstart[s], ge = gstart[s + 1];
    float acc = 0.f;
    for (int r = gs; r < ge; ++r) {
        float v = zs[(size_t)r * 64 + l];
        float ss = v * v;
        for (int off = 32; off > 0; off >>= 1) ss += __shfl_xor(ss, off, 64);
        acc += v / fmaxf(sqrtf(ss), 1e-12f);
    }
    o[(size_t)s * 64 + l] = acc / fmaxf((float)(ge - gs), 1.f);
}

// ---------------------------------------------------------------------------
// Row L2 normalize, M = 64; writes fp32 in place + optional bf16 copy
// ---------------------------------------------------------------------------
__global__ void k_l2norm2(float* __restrict__ x, bf16* __restrict__ xb, int n) {
    int row = blockIdx.x * 4 + threadIdx.y;
    if (row >= n) return;
    int l = threadIdx.x;
    float v = x[(size_t)row * 64 + l];
    float ss = v * v;
    for (int o = 32; o > 0; o >>= 1) ss += __shfl_xor(ss, o, 64);
    float r = v / fmaxf(sqrtf(ss), 1e-12f);
    x[(size_t)row * 64 + l] = r;
    if (xb) xb[(size_t)row * 64 + l] = __float2bfloat16(r);
}

// ---------------------------------------------------------------------------
// Host-side vector-GEMM launch helper
// ---------------------------------------------------------------------------
template <typename TA, typename TC>
static void launch_gemm(const TA* A, const float* W, TC* C, int n, int K, int M,
                        const float* bias, int act, const float* mu, const float* sc,
                        hipStream_t stream) {
    dim3 b(64, 4);
    int g = cdiv(n, 64);
    int nj = (M + 63) >> 6;
    if (nj >= 4)      k_gemm<TA, TC, 4><<<g, b, 0, stream>>>(A, W, C, n, K, M, bias, act, mu, sc);
    else if (nj == 2) k_gemm<TA, TC, 2><<<g, b, 0, stream>>>(A, W, C, n, K, M, bias, act, mu, sc);
    else              k_gemm<TA, TC, 1><<<g, b, 0, stream>>>(A, W, C, n, K, M, bias, act, mu, sc);
}

// ---------------------------------------------------------------------------
// Host launch
// ---------------------------------------------------------------------------
extern "C" void kernel_launch(void* const* d_in, const int* in_sizes, int n_in,
                              void* d_out, int out_size, void* d_ws, size_t ws_size,
                              hipStream_t stream) {
    const float* x        = (const float*)d_in[0];
    const int*   ei       = (const int*)  d_in[1];
    const int*   batch    = (const int*)  d_in[2];
    const float* target_x = (const float*)d_in[3];
    const float* pos_x    = (const float*)d_in[4];
    const int*   pos_ei   = (const int*)  d_in[5];
    const int*   pos_b    = (const int*)  d_in[6];
    const float* neg_x    = (const float*)d_in[7];
    const int*   neg_ei   = (const int*)  d_in[8];
    const int*   neg_b    = (const int*)  d_in[9];
    const float* enc_W0 = (const float*)d_in[10]; const float* enc_b0 = (const float*)d_in[11];
    const float* enc_W1 = (const float*)d_in[12]; const float* enc_b1 = (const float*)d_in[13];
    const float* enc_W2 = (const float*)d_in[14]; const float* enc_b2 = (const float*)d_in[15];
    const float* dec_W0 = (const float*)d_in[16];
    const float* dec_W1 = (const float*)d_in[17];
    const float* dec_W2 = (const float*)d_in[18];
    const float* node_W0 = (const float*)d_in[19]; const float* node_b0 = (const float*)d_in[20];
    const float* node_W1 = (const float*)d_in[21]; const float* node_b1 = (const float*)d_in[22];
    const float* node_W2 = (const float*)d_in[23]; const float* node_b2 = (const float*)d_in[24];
    const float* sub_W0 = (const float*)d_in[25]; const float* sub_b0 = (const float*)d_in[26];
    const float* sub_W1 = (const float*)d_in[27]; const float* sub_b1 = (const float*)d_in[28];
    const float* cls_W0 = (const float*)d_in[29]; const float* cls_b0 = (const float*)d_in[30];
    const float* cls_W1 = (const float*)d_in[31]; const float* cls_b1 = (const float*)d_in[32];
    const float* cls_W2 = (const float*)d_in[33]; const float* cls_b2 = (const float*)d_in[34];

    float* out = (float*)d_out;
    const size_t OFF_XREC  = 0;
    const size_t OFF_ZPOOL = (size_t)N_NODES * F_IN;
    const size_t OFF_TZ    = OFF_ZPOOL + (size_t)N_GRAPHS * H2;
    const size_t OFF_PPOOL = OFF_TZ    + (size_t)N_GRAPHS * H2;
    const size_t OFF_NPOOL = OFF_PPOOL + (size_t)N_GRAPHS * H2;
    const size_t OFF_PRED  = OFF_NPOOL + (size_t)N_GRAPHS * H2;

    // ----- workspace carve-up (by floats; total ~207 MB) -----
    char* wsp = (char*)d_ws;
    auto alloc = [&](size_t nfloats) -> float* {
        float* p = (float*)wsp;
        wsp += ((nfloats + 63) / 64) * 64 * sizeof(float);
        return p;
    };
    float* R1     = alloc((size_t)N_NODES * 128);   // fp32 N*128 / bf16 N*256
    float* R2     = alloc((size_t)N_NODES * 128);
    float* dinv   = alloc(N_NODES);
    int*   cnt    = (int*)alloc(N_NODES);           // degree, then reused as cursor
    int*   rowptr = (int*)alloc(N_NODES + 1);
    int*   bsum   = (int*)alloc(1024);
    int*   ccol   = (int*)alloc(N_EDGES);
    float* ssum   = alloc(256);
    float* ssumsq = alloc(256);   // contiguous with ssum
    bf16*  wpk    = (bf16*)alloc(101 * 1024);  // 206848-bf16 arena, 200704 used
    float* bfold  = alloc(256);   // folded biases: b1' [0..128), b2' [128..192)
    (void)ws_size; (void)in_sizes; (void)n_in; (void)out_size;

    // packed-weight arena offsets (bf16 elements): S*Mp*32 each
    bf16* eW0b = wpk;            // K38->S2,  Mp256: 16384
    bf16* eW1b = eW0b + 16384;   // K256->S8, Mp128: 32768 (unused; layout keep)
    bf16* eW2b = eW1b + 32768;   // K128->S4, Mp64 :  8192
    bf16* dW0b = eW2b + 8192;    // K64->S2,  Mp128:  8192
    bf16* dW1b = dW0b + 8192;    // K128->S4, Mp256: 32768
    bf16* dW2b = dW1b + 32768;   // K256->S8, Mp48 : 12288
    bf16* sW0b = dW2b + 12288;   // K38->S2,  Mp256: 16384
    bf16* sW1b = sW0b + 16384;   // K256->S8, Mp128: 32768
    bf16* fW1b = sW1b + 32768;   // folded enc_W1': K256, Mp128: 32768
    bf16* fW2b = fW1b + 32768;   // folded enc_W2': K128, Mp64 :  8192

    // ----- R2-tail carve (no new allocs).
    float* tailf    = R2 + (size_t)16 * 1024 * 1024;          // 64 MB offset
    float* segsumM  = tailf;                                  // mu  4096*256
    float* segsumqM = tailf + (size_t)1048576;                // sc  4096*256
    float* mx       = tailf + (size_t)2097152;                // 2*N_SUB*F_IN fp32
    int*   msrc     = (int*)(mx + (size_t)2 * N_SUB * F_IN);  // 2*E_SUB
    int*   mdst     = msrc + 2 * E_SUB;                       // 2*E_SUB
    int*   mb       = mdst + 2 * E_SUB;                       // 2*N_SUB
    int*   gstartM  = mb + 2 * N_SUB;                         // 4097 ints (sub)
    int*   gstart2k = gstartM + 4112;                         // 2049 ints (main)

    dim3 b64x4(64, 4);
    auto zero = [&](void* p, size_t nfloats) {
        k_zero<<<cdiv((int)nfloats, 256), 256, 0, stream>>>((float*)p, (int)nfloats);
    };

    // pack all 8 weights in one launch (seg-BN fused at GEMM A-load;
    // global BN folded into W via k_wfold after stats)
    k_wpack_all<<<624, 256, 0, stream>>>(enc_W0, enc_W1, enc_W2, dec_W0, dec_W1,
                                         dec_W2, sub_W0, sub_W1, wpk);

    auto build_graph = [&](const int* srcp, const int* dstp, int n, int e) {
        zero(cnt, n);
        k_count<<<cdiv(e, 256), 256, 0, stream>>>(dstp, cnt, e);
        k_dinv<<<cdiv(n, 256), 256, 0, stream>>>(cnt, dinv, n);
        int nb = cdiv(n, 256);
        k_scan_sum<<<nb, 256, 0, stream>>>(cnt, bsum, n);
        k_scan_top<<<1, 1024, 0, stream>>>(bsum, nb);
        k_scan_apply<<<nb, 256, 0, stream>>>(cnt, bsum, rowptr, n);
        zero(cnt, n);  // cnt now serves as the fill cursor
        k_fill<<<cdiv(e, 256), 256, 0, stream>>>(srcp, dstp, rowptr, cnt, ccol, e);
    };

    auto bn_stats = [&](auto* xx, int n, int M) {
        zero(ssum, 512);  // ssum+ssumsq contiguous
        int rpb = 256 / (M >> 3);
        int g = min(512, cdiv(n, rpb));
        k_bn_stats8<<<g, 256, 0, stream>>>(xx, n, M, ssum, ssumsq);
        k_bn_fin<<<1, 256, 0, stream>>>(ssum, ssumsq, n, M);
    };

    // ============ main graph encode (fused L0+L1, BN folded into W) ============
    build_graph(ei, ei + N_EDGES, N_NODES, N_EDGES);

    // Y0 = A_hat * x  (bf16 N x 64, K-pad 38->64)  — in R1 (fused01 writes R2)
    bf16* Y0 = (bf16*)R1;
    launch_gather<float, bf16>(x, dinv, rowptr, ccol, Y0, N_NODES, F_IN, 64,
                               nullptr, 0, stream);

    // a0 stats computed in-register from Y0 (a0 never materialized)
    zero(ssum, 512);
    k_l0stats<<<512, b64x4, 0, stream>>>(Y0, eW0b, enc_b0, ssum, ssumsq,
                                         N_NODES / 64);
    k_bn_fin<<<1, 256, 0, stream>>>(ssum, ssumsq, N_NODES, H0);
    k_wfold<256, 128, 128><<<128, 256, 0, stream>>>(enc_W1, ssum, ssumsq, fW1b, bfold);

    // Fused L0+L1: G1 = relu(Y0@W0+b0) @ W1' + b1'
    bf16* G1 = (bf16*)R2;
    k_fused01<<<N_NODES / 64, b64x4, 0, stream>>>(Y0, eW0b, enc_b0, fW1b, bfold,
                                                  G1, N_NODES);

    // a1 = relu(A_hat*G1 + b1)   (Y0 dead -> a1 in R1)
    bf16* a1 = (bf16*)R1;
    launch_gather6<bf16>(G1, dinv, rowptr, ccol, a1, N_NODES, 128, enc_b1, 1, stream);
    bn_stats(a1, N_NODES, H1);
    k_wfold<128, 64, 64><<<32, 256, 0, stream>>>(enc_W2, ssum, ssumsq, fW2b, bfold + 128);

    // Layer 2: G2 = a1@W2' + b2'; z = A_hat*G2 + b2, l2norm
    bf16* G2 = (bf16*)R2;
    launch_mfma<bf16, 0>(a1, fW2b, G2, N_NODES, 128, 64, H2, H2, bfold + 128, 0,
                         nullptr, nullptr, nullptr, stream);
    float* z  = R1;
    bf16*  zb = (bf16*)(R1 + (size_t)N_NODES * 64);
    launch_gather6<float>(G2, dinv, rowptr, ccol, z, N_NODES, 64, enc_b2, 0, stream);
    k_l2norm2<<<cdiv(N_NODES, 4), b64x4, 0, stream>>>(z, zb, N_NODES);

    // z_pool (boundaries from sorted batch; wave-per-segment mean)
    k_gbound<<<cdiv(N_NODES, 256), 256, 0, stream>>>(batch, N_NODES, N_GRAPHS, gstart2k);
    k_pool<<<cdiv(N_GRAPHS, 4), b64x4, 0, stream>>>(z, gstart2k, N_GRAPHS,
                                                    out + OFF_ZPOOL);

    // ===================== decode: single fused kernel =====================
    k_decoder<<<N_NODES / 64, b64x4, 0, stream>>>(zb, dW0b, dW1b, dW2b,
                                                  out + OFF_XREC, N_NODES);

    // ===================== target node MLP (fp32 vector) =====================
    float* t0 = R2;  // 2048 x 256
    launch_gemm<float, float>(target_x, node_W0, t0, N_GRAPHS, F_IN, H0, node_b0, 1,
                              nullptr, nullptr, stream);
    bn_stats(t0, N_GRAPHS, H0);
    float* t1 = R1;  // 2048 x 128
    launch_gemm<float, float>(t0, node_W1, t1, N_GRAPHS, H0, H1, node_b1, 1,
                              ssum, ssumsq, stream);
    bn_stats(t1, N_GRAPHS, H1);
    launch_gemm<float, float>(t1, node_W2, out + OFF_TZ, N_GRAPHS, H1, H2, node_b2, 0,
                              ssum, ssumsq, stream);
    k_l2norm2<<<cdiv(N_GRAPHS, 4), b64x4, 0, stream>>>(out + OFF_TZ, nullptr, N_GRAPHS);

    // ========== merged pos+neg subgraph pipeline (one batched pass) ==========
    k_merge<<<2048, 256, 0, stream>>>(pos_x, neg_x, pos_ei, neg_ei, pos_b, neg_b,
                                      mx, msrc, mdst, mb);
    const int NS2 = 2 * N_SUB, ES2 = 2 * E_SUB, NG2 = 2 * N_GRAPHS;
    build_graph(msrc, mdst, NS2, ES2);
    k_gbound<<<cdiv(NS2, 256), 256, 0, stream>>>(mb, NS2, NG2, gstartM);

    // Layer 0: Ys = A_hat*mx (bf16, pad 38->64); as0 = relu(Ys@sW0 + b)
    bf16* Ys = (bf16*)R2;
    launch_gather<float, bf16>(mx, dinv, rowptr, ccol, Ys, NS2, F_IN, 64,
                               nullptr, 0, stream);
    bf16* as0 = (bf16*)R1;  // 65536 x 256
    launch_mfma<bf16, 0>(Ys, sW0b, as0, NS2, 64, 256, H0, H0, sub_b0, 1,
                         nullptr, nullptr, nullptr, stream);
    k_segbn<4><<<cdiv(NG2, 4), b64x4, 0, stream>>>(as0, gstartM, NG2,
                                                   segsumM, segsumqM);

    // Layer 1: Gs1 = segbn(as0)@sW1; as1 = relu(A_hat*Gs1 + b1)
    bf16* Gs1 = (bf16*)R2;  // 65536 x 128
    launch_mfma<bf16, 2>(as0, sW1b, Gs1, NS2, 256, 128, H1, H1, nullptr, 0,
                         segsumM, segsumqM, mb, stream);
    bf16* as1 = (bf16*)R1;  // 65536 x 128
    launch_gather6<bf16>(Gs1, dinv, rowptr, ccol, as1, NS2, 128, sub_b1, 1, stream);
    k_segbn<2><<<cdiv(NG2, 4), b64x4, 0, stream>>>(as1, gstartM, NG2,
                                                   segsumM, segsumqM);

    // Layer 2: Gs2 = segbn(as1)@encW2; zs = A_hat*Gs2 + b2; fused l2norm+pool
    bf16* Gs2 = (bf16*)R2;  // 65536 x 64
    launch_mfma<bf16, 2>(as1, eW2b, Gs2, NS2, 128, 64, H2, H2, nullptr, 0,
                         segsumM, segsumqM, mb, stream);
    float* zs = R1;  // 65536 x 64 fp32
    launch_gather6<float>(Gs2, dinv, rowptr, ccol, zs, NS2, 64, enc_b2, 0, stream);
    k_l2pool<<<cdiv(NG2, 4), b64x4, 0, stream>>>(zs, gstartM, NG2, out + OFF_PPOOL);

    // ===================== classifier on neg_pool (fp32 vector) =====================
    float* c1 = R2;
    launch_gemm<float, float>(out + OFF_NPOOL, cls_W0, c1, N_GRAPHS, H2, H1, cls_b0, 1,
                              nullptr, nullptr, stream);
    float* c2 = R1;
    launch_gemm<float, float>(c1, cls_W1, c2, N_GRAPHS, H1, 16, cls_b1, 1,
                              nullptr, nullptr, stream);
    launch_gemm<float, float>(c2, cls_W2, out + OFF_PRED, N_GRAPHS, 16, 1, cls_b2, 2,
                              nullptr, nullptr, stream);
}

// Round 9
// 1128.437 us; speedup vs baseline: 1.1927x; 1.0437x over previous
//
#include <hip/hip_runtime.h>
#include <hip/hip_bf16.h>
#include <math.h>

// ---------------------------------------------------------------------------
// Problem constants (from reference)
// ---------------------------------------------------------------------------
#define N_NODES  200000
#define N_EDGES  800000
#define N_GRAPHS 2048
#define N_SUB    32768
#define E_SUB    131072
#define F_IN     38
#define H0       256
#define H1       128
#define H2       64
#define BN_EPS   1e-5f

typedef __hip_bfloat16 bf16;
typedef __attribute__((ext_vector_type(8))) short short8;
typedef __attribute__((ext_vector_type(4))) short short4v;
typedef __attribute__((ext_vector_type(4))) float float4v;

static __host__ __device__ inline int cdiv(int a, int b) { return (a + b - 1) / b; }

__device__ inline float ldf(const float* p, size_t i) { return p[i]; }
__device__ inline float ldf(const bf16* p, size_t i)  { return __bfloat162float(p[i]); }
__device__ inline void  stf(float* p, size_t i, float v) { p[i] = v; }
__device__ inline void  stf(bf16* p, size_t i, float v)  { p[i] = __float2bfloat16(v); }

__device__ inline float2 ldf2(const float* p, size_t i) { return ((const float2*)p)[i]; }
__device__ inline float2 ldf2(const bf16* p, size_t i) {
    __hip_bfloat162 v = ((const __hip_bfloat162*)p)[i];
    return make_float2(__bfloat162float(v.x), __bfloat162float(v.y));
}
__device__ inline void stf2(float* p, size_t i, float2 v) { ((float2*)p)[i] = v; }
__device__ inline void stf2(bf16* p, size_t i, float2 v) {
    __hip_bfloat162 t;
    t.x = __float2bfloat16(v.x);
    t.y = __float2bfloat16(v.y);
    ((__hip_bfloat162*)p)[i] = t;
}

__device__ inline short bf16bits(float v) {
    bf16 t = __float2bfloat16(v);
    return *reinterpret_cast<short*>(&t);
}
__device__ inline float bits2f(short s) {
    return __bfloat162float(*reinterpret_cast<const bf16*>(&s));
}

// ---------------------------------------------------------------------------
// Weight staging into LDS with 64B->80B row padding (kills the 16-bank-stride
// 8-way conflict of the natural 64B fragment-row layout; 80B = 20-bank stride
// spreads starts across all banks -> ~2-way = free).  Chunk c copies source
// bytes [16c,16c+16) to dst row (c>>2), intra-row offset (c&3)*16.
// ---------------------------------------------------------------------------
__device__ inline void stage_w(const bf16* __restrict__ src, char* dst,
                               int nchunk, int tid) {
    for (int c = tid; c < nchunk; c += 256) {
        short8 v = *(const short8*)(src + c * 8);
        *(short8*)(dst + ((c >> 2) * 80 + (c & 3) * 16)) = v;
    }
}
__device__ inline short8 wstage_read(const char* w, int r, int qr) {
    return *(const short8*)(w + r * 80 + qr * 16);
}

// ---------------------------------------------------------------------------
// Zero fill (graph-capture-safe replacement for hipMemsetAsync)
// ---------------------------------------------------------------------------
__global__ void k_zero(float* __restrict__ p, int n) {
    int i = blockIdx.x * 256 + threadIdx.x;
    if (i < n) p[i] = 0.f;
}

// ---------------------------------------------------------------------------
// Graph preprocessing: degree, CSR build
// ---------------------------------------------------------------------------
__global__ void k_count(const int* __restrict__ dst, int* __restrict__ cnt, int e) {
    int i = blockIdx.x * 256 + threadIdx.x;
    if (i < e) atomicAdd(&cnt[dst[i]], 1);
}

__global__ void k_dinv(const int* __restrict__ cnt, float* __restrict__ dinv, int n) {
    int i = blockIdx.x * 256 + threadIdx.x;
    if (i < n) dinv[i] = rsqrtf(1.0f + (float)cnt[i]);
}

__global__ void k_scan_sum(const int* __restrict__ cnt, int* __restrict__ bsum, int n) {
    __shared__ int tmp[256];
    int t = threadIdx.x;
    int i = blockIdx.x * 256 + t;
    tmp[t] = (i < n) ? cnt[i] : 0;
    __syncthreads();
    for (int off = 128; off > 0; off >>= 1) {
        if (t < off) tmp[t] += tmp[t + off];
        __syncthreads();
    }
    if (t == 0) bsum[blockIdx.x] = tmp[0];
}

__global__ void k_scan_top(int* __restrict__ bsum, int nb) {
    __shared__ int tmp[1024];
    int t = threadIdx.x;
    int v = (t < nb) ? bsum[t] : 0;
    tmp[t] = v;
    __syncthreads();
    for (int off = 1; off < 1024; off <<= 1) {
        int a = (t >= off) ? tmp[t - off] : 0;
        __syncthreads();
        tmp[t] += a;
        __syncthreads();
    }
    if (t < nb) bsum[t] = tmp[t] - v;  // exclusive
}

__global__ void k_scan_apply(const int* __restrict__ cnt, const int* __restrict__ bsum,
                             int* __restrict__ rowptr, int n) {
    __shared__ int tmp[256];
    int t = threadIdx.x;
    int i = blockIdx.x * 256 + t;
    int v = (i < n) ? cnt[i] : 0;
    tmp[t] = v;
    __syncthreads();
    for (int off = 1; off < 256; off <<= 1) {
        int a = (t >= off) ? tmp[t - off] : 0;
        __syncthreads();
        tmp[t] += a;
        __syncthreads();
    }
    int excl = tmp[t] - v + bsum[blockIdx.x];
    if (i < n) rowptr[i] = excl;
    if (i == n - 1) rowptr[n] = excl + v;
}

// cursor aliases the (consumed) cnt buffer — re-zeroed before this kernel.
__global__ void k_fill(const int* __restrict__ src, const int* __restrict__ dst,
                       const int* __restrict__ rowptr, int* __restrict__ cursor,
                       int* __restrict__ col, int e) {
    int i = blockIdx.x * 256 + threadIdx.x;
    if (i < e) {
        int d = dst[i];
        int p = rowptr[d] + atomicAdd(&cursor[d], 1);
        col[p] = src[i];
    }
}

// ---------------------------------------------------------------------------
// Segment boundaries from a SORTED segment array.
// ---------------------------------------------------------------------------
__global__ void k_gbound(const int* __restrict__ seg, int n, int nseg,
                         int* __restrict__ gstart) {
    int i = blockIdx.x * 256 + threadIdx.x;
    if (i >= n) return;
    int s = seg[i];
    if (i == 0) {
        for (int g = 0; g <= s; ++g) gstart[g] = 0;
    } else {
        int p = seg[i - 1];
        for (int g = p + 1; g <= s; ++g) gstart[g] = i;
    }
    if (i == n - 1) {
        for (int g = s + 1; g <= nseg; ++g) gstart[g] = n;
    }
}

// ---------------------------------------------------------------------------
// Merge pos/neg subgraph inputs into one batched problem.
// ---------------------------------------------------------------------------
__global__ void k_merge(const float* __restrict__ px, const float* __restrict__ nx,
                        const int* __restrict__ pei, const int* __restrict__ nei,
                        const int* __restrict__ pb, const int* __restrict__ nbt,
                        float* __restrict__ mx, int* __restrict__ msrc,
                        int* __restrict__ mdst, int* __restrict__ mb) {
    int stride = gridDim.x * 256;
    for (int i = blockIdx.x * 256 + threadIdx.x; i < N_SUB * F_IN; i += stride) {
        mx[i] = px[i];
        mx[(size_t)N_SUB * F_IN + i] = nx[i];
    }
    for (int i = blockIdx.x * 256 + threadIdx.x; i < E_SUB; i += stride) {
        msrc[i] = pei[i];
        mdst[i] = pei[E_SUB + i];
        msrc[E_SUB + i] = nei[i] + N_SUB;
        mdst[E_SUB + i] = nei[E_SUB + i] + N_SUB;
    }
    for (int i = blockIdx.x * 256 + threadIdx.x; i < N_SUB; i += stride) {
        mb[i] = pb[i];
        mb[N_SUB + i] = nbt[i] + N_GRAPHS;
    }
}

// ---------------------------------------------------------------------------
// Gather v5 (dual-chain rotated pipeline; float2/lane).  Kept for the two
// fp32-input layer-0 sites (M=38).
// ---------------------------------------------------------------------------
template <typename TI, typename TO, int PPN>
__global__ __launch_bounds__(256) void k_gather5(
    const TI* __restrict__ h, const float* __restrict__ dinv,
    const int* __restrict__ rowptr, const int* __restrict__ col,
    TO* __restrict__ o, int n, int M2, int S2,
    const float* __restrict__ bias, int relu)
{
    const int NPW = 64 / PPN;  // lane-groups per wave
    int g0 = threadIdx.x / PPN;
    int pr = threadIdx.x % PPN;
    int nA = (blockIdx.x * 4 + threadIdx.y) * (2 * NPW) + g0 * 2;
    if (nA >= n) return;
    int nB = nA + 1;
    bool okB = nB < n;
    bool pld = pr < M2, pst = pr < S2;

    int2 rp = *(const int2*)(rowptr + nA);
    float diA = dinv[nA];
    float diB = okB ? dinv[nB] : 0.f;
    float2 vsA = make_float2(0.f, 0.f), vsB = make_float2(0.f, 0.f);
    if (pld) {
        vsA = ldf2(h, (size_t)nA * M2 + pr);
        if (okB) vsB = ldf2(h, (size_t)nB * M2 + pr);
    }
    int peB = okB ? rowptr[nA + 2] : rp.y;

    int pA = rp.x, peA = rp.y;
    int pB = peA;  // rowptr[nB] == rowptr[nA+1]

    int sA1 = 0, sB1 = 0;
    float dA0 = 0.f, dB0 = 0.f;
    float2 vA0 = make_float2(0.f, 0.f), vB0 = make_float2(0.f, 0.f);

    if (pA < peA) {
        int s0 = col[pA];
        sA1 = (pA + 1 < peA) ? col[pA + 1] : 0;
        dA0 = dinv[s0];
        if (pld) vA0 = ldf2(h, (size_t)s0 * M2 + pr);
    }
    if (pB < peB) {
        int s0 = col[pB];
        sB1 = (pB + 1 < peB) ? col[pB + 1] : 0;
        dB0 = dinv[s0];
        if (pld) vB0 = ldf2(h, (size_t)s0 * M2 + pr);
    }

    float2 accA, accB;
    accA.x = diA * diA * vsA.x; accA.y = diA * diA * vsA.y;
    accB.x = diB * diB * vsB.x; accB.y = diB * diB * vsB.y;

    while (pA < peA && pB < peB) {
        int sA2 = (pA + 2 < peA) ? col[pA + 2] : 0;
        int sB2 = (pB + 2 < peB) ? col[pB + 2] : 0;
        float2 vA1 = (pA + 1 < peA && pld) ? ldf2(h, (size_t)sA1 * M2 + pr)
                                           : make_float2(0.f, 0.f);
        float2 vB1 = (pB + 1 < peB && pld) ? ldf2(h, (size_t)sB1 * M2 + pr)
                                           : make_float2(0.f, 0.f);
        float dA1 = (pA + 1 < peA) ? dinv[sA1] : 0.f;
        float dB1 = (pB + 1 < peB) ? dinv[sB1] : 0.f;
        float cfA = dA0 * diA, cfB = dB0 * diB;
        accA.x += cfA * vA0.x; accA.y += cfA * vA0.y;
        accB.x += cfB * vB0.x; accB.y += cfB * vB0.y;
        sA1 = sA2; vA0 = vA1; dA0 = dA1;
        sB1 = sB2; vB0 = vB1; dB0 = dB1;
        ++pA; ++pB;
    }
    while (pA < peA) {
        int sA2 = (pA + 2 < peA) ? col[pA + 2] : 0;
        float2 vA1 = (pA + 1 < peA && pld) ? ldf2(h, (size_t)sA1 * M2 + pr)
                                           : make_float2(0.f, 0.f);
        float dA1 = (pA + 1 < peA) ? dinv[sA1] : 0.f;
        float cfA = dA0 * diA;
        accA.x += cfA * vA0.x; accA.y += cfA * vA0.y;
        sA1 = sA2; vA0 = vA1; dA0 = dA1; ++pA;
    }
    while (pB < peB) {
        int sB2 = (pB + 2 < peB) ? col[pB + 2] : 0;
        float2 vB1 = (pB + 1 < peB && pld) ? ldf2(h, (size_t)sB1 * M2 + pr)
                                           : make_float2(0.f, 0.f);
        float dB1 = (pB + 1 < peB) ? dinv[sB1] : 0.f;
        float cfB = dB0 * diB;
        accB.x += cfB * vB0.x; accB.y += cfB * vB0.y;
        sB1 = sB2; vB0 = vB1; dB0 = dB1; ++pB;
    }

    if (pst) {
        float2 rA = accA;
        if (bias && pld) { rA.x += bias[2 * pr]; rA.y += bias[2 * pr + 1]; }
        if (relu) { rA.x = fmaxf(rA.x, 0.f); rA.y = fmaxf(rA.y, 0.f); }
        stf2(o, (size_t)nA * S2 + pr, rA);
        if (okB) {
            float2 rB = accB;
            if (bias && pld) { rB.x += bias[2 * pr]; rB.y += bias[2 * pr + 1]; }
            if (relu) { rB.x = fmaxf(rB.x, 0.f); rB.y = fmaxf(rB.y, 0.f); }
            stf2(o, (size_t)nB * S2 + pr, rB);
        }
    }
}

template <typename TI, typename TO>
static void launch_gather(const TI* h, const float* dinv, const int* rowptr,
                          const int* col, TO* o, int n, int M, int Sout,
                          const float* bias, int relu, hipStream_t stream) {
    dim3 b(64, 4);
    int M2 = M >> 1, S2 = Sout >> 1;
    if (S2 > 32)
        k_gather5<TI, TO, 64><<<cdiv(n, 8), b, 0, stream>>>(h, dinv, rowptr, col, o,
                                                            n, M2, S2, bias, relu);
    else
        k_gather5<TI, TO, 32><<<cdiv(n, 16), b, 0, stream>>>(h, dinv, rowptr, col, o,
                                                             n, M2, S2, bias, relu);
}

// ---------------------------------------------------------------------------
// Gather v6 (bf16 in, 16 B/lane): LPR lanes cover one row (LPR*8 = W cols),
// 64/LPR dual-chain lane-groups per wave; rotated pipeline.
// ---------------------------------------------------------------------------
template <typename TO, int LPR>
__global__ __launch_bounds__(256) void k_gather6(
    const bf16* __restrict__ h, const float* __restrict__ dinv,
    const int* __restrict__ rowptr, const int* __restrict__ col,
    TO* __restrict__ o, int n, const float* __restrict__ bias, int relu)
{
    const int W = LPR * 8;
    const int NG = 64 / LPR;
    const int g = threadIdx.x / LPR;
    const int c0 = (threadIdx.x % LPR) * 8;
    const int nA = (blockIdx.x * 4 + threadIdx.y) * (2 * NG) + g * 2;
    const int nB = nA + 1;
    if (nA >= n) return;           // group-uniform
    const bool okB = nB < n;

    int2 rp = *(const int2*)(rowptr + nA);
    int peB = okB ? rowptr[nB + 1] : rp.y;
    float diA = dinv[nA];
    float diB = okB ? dinv[nB] : 0.f;
    short8 zed = {0, 0, 0, 0, 0, 0, 0, 0};
    short8 slA = *(const short8*)(h + (size_t)nA * W + c0);
    short8 slB = okB ? *(const short8*)(h + (size_t)nB * W + c0) : zed;

    int pA = rp.x, peA = rp.y;
    int pB = rp.y;

    float accA[8], accB[8];
    float qA = diA * diA, qB = diB * diB;
#pragma unroll
    for (int j = 0; j < 8; ++j) {
        accA[j] = qA * bits2f(slA[j]);
        accB[j] = qB * bits2f(slB[j]);
    }

    // rotated pipeline state
    int sA1 = 0, sB1 = 0;
    float dA0 = 0.f, dB0 = 0.f;
    short8 vA0 = zed, vB0 = zed;
    if (pA < peA) {
        int s0 = col[pA];
        sA1 = (pA + 1 < peA) ? col[pA + 1] : 0;
        dA0 = dinv[s0];
        vA0 = *(const short8*)(h + (size_t)s0 * W + c0);
    }
    if (pB < peB) {
        int s0 = col[pB];
        sB1 = (pB + 1 < peB) ? col[pB + 1] : 0;
        dB0 = dinv[s0];
        vB0 = *(const short8*)(h + (size_t)s0 * W + c0);
    }

    while (__any(pA < peA || pB < peB)) {
        if (pA < peA) {
            int sA2 = (pA + 2 < peA) ? col[pA + 2] : 0;
            short8 vA1 = zed;
            float dA1 = 0.f;
            if (pA + 1 < peA) {
                vA1 = *(const short8*)(h + (size_t)sA1 * W + c0);
                dA1 = dinv[sA1];
            }
            float cf = dA0 * diA;
#pragma unroll
            for (int j = 0; j < 8; ++j) accA[j] += cf * bits2f(vA0[j]);
            vA0 = vA1; dA0 = dA1; sA1 = sA2; ++pA;
        }
        if (pB < peB) {
            int sB2 = (pB + 2 < peB) ? col[pB + 2] : 0;
            short8 vB1 = zed;
            float dB1 = 0.f;
            if (pB + 1 < peB) {
                vB1 = *(const short8*)(h + (size_t)sB1 * W + c0);
                dB1 = dinv[sB1];
            }
            float cf = dB0 * diB;
#pragma unroll
            for (int j = 0; j < 8; ++j) accB[j] += cf * bits2f(vB0[j]);
            vB0 = vB1; dB0 = dB1; sB1 = sB2; ++pB;
        }
    }

    float bv[8];
#pragma unroll
    for (int j = 0; j < 8; ++j) bv[j] = 0.f;
    if (bias) {
        float4 b0 = *(const float4*)(bias + c0);
        float4 b1 = *(const float4*)(bias + c0 + 4);
        bv[0] = b0.x; bv[1] = b0.y; bv[2] = b0.z; bv[3] = b0.w;
        bv[4] = b1.x; bv[5] = b1.y; bv[6] = b1.z; bv[7] = b1.w;
    }

    auto store_row = [&](int node, float* acc) {
        float r[8];
#pragma unroll
        for (int j = 0; j < 8; ++j) {
            r[j] = acc[j] + bv[j];
            if (relu) r[j] = fmaxf(r[j], 0.f);
        }
        size_t off = (size_t)node * W + c0;
        if constexpr (sizeof(TO) == 2) {
            short8 pk;
#pragma unroll
            for (int j = 0; j < 8; ++j) pk[j] = bf16bits(r[j]);
            *(short8*)((bf16*)o + off) = pk;
        } else {
            float4 f0 = {r[0], r[1], r[2], r[3]};
            float4 f1 = {r[4], r[5], r[6], r[7]};
            *(float4*)((float*)o + off) = f0;
            *(float4*)((float*)o + off + 4) = f1;
        }
    };
    store_row(nA, accA);
    if (okB) store_row(nB, accB);
}

template <typename TO>
static void launch_gather6(const bf16* h, const float* dinv, const int* rowptr,
                           const int* col, TO* o, int n, int W,
                           const float* bias, int relu, hipStream_t stream) {
    dim3 b(64, 4);
    if (W == 128)
        k_gather6<TO, 16><<<cdiv(n, 32), b, 0, stream>>>(h, dinv, rowptr, col, o, n,
                                                         bias, relu);
    else
        k_gather6<TO, 8><<<cdiv(n, 64), b, 0, stream>>>(h, dinv, rowptr, col, o, n,
                                                        bias, relu);
}

// ---------------------------------------------------------------------------
// W pre-pack into MFMA fragment layout (bf16), all 8 weights in ONE launch:
//   Wb[((s*Mp) + n)*32 + kk] = W[s*32+kk][n]   (zero-padded k>=K or n>=M)
// ---------------------------------------------------------------------------
template <int K, int M, int Mp>
__device__ inline void wpack1(const float* __restrict__ W, bf16* __restrict__ o, int j) {
    int kk = j & 31;
    int rem = j >> 5;
    int ncol = rem % Mp;
    int s = rem / Mp;
    int k = s * 32 + kk;
    float v = (k < K && ncol < M) ? W[(size_t)k * M + ncol] : 0.f;
    o[j] = __float2bfloat16(v);
}

__global__ void k_wpack_all(const float* __restrict__ eW0, const float* __restrict__ eW1,
                            const float* __restrict__ eW2, const float* __restrict__ dW0,
                            const float* __restrict__ dW1, const float* __restrict__ dW2,
                            const float* __restrict__ sW0, const float* __restrict__ sW1,
                            bf16* __restrict__ arena) {
    for (int i = blockIdx.x * 256 + threadIdx.x; i < 159744; i += gridDim.x * 256) {
        if (i < 16384)       wpack1<38, 256, 256>(eW0, arena, i);
        else if (i < 49152)  wpack1<256, 128, 128>(eW1, arena + 16384, i - 16384);
        else if (i < 57344)  wpack1<128, 64, 64>(eW2, arena + 49152, i - 49152);
        else if (i < 65536)  wpack1<64, 128, 128>(dW0, arena + 57344, i - 57344);
        else if (i < 98304)  wpack1<128, 256, 256>(dW1, arena + 65536, i - 65536);
        else if (i < 110592) wpack1<256, 38, 48>(dW2, arena + 98304, i - 98304);
        else if (i < 126976) wpack1<38, 256, 256>(sW0, arena + 110592, i - 110592);
        else                 wpack1<256, 128, 128>(sW1, arena + 126976, i - 126976);
    }
}

// ---------------------------------------------------------------------------
// Fold global BN into weights:  W'[k,j] = sc[k]*W[k,j] packed to MFMA layout;
// b'[j] = -sum_k mu[k]*sc[k]*W[k,j]  (all fp32 math).  bn(A)@W == A@W' + b'.
// ---------------------------------------------------------------------------
template <int K, int M, int Mp>
__global__ void k_wfold(const float* __restrict__ W, const float* __restrict__ mu,
                        const float* __restrict__ sc, bf16* __restrict__ Wb,
                        float* __restrict__ bout) {
    const int tot = (K / 32) * Mp * 32;
    for (int i = blockIdx.x * 256 + threadIdx.x; i < tot; i += gridDim.x * 256) {
        int kk = i & 31;
        int rem = i >> 5;
        int ncol = rem % Mp;
        int s = rem / Mp;
        int k = s * 32 + kk;
        float v = (k < K && ncol < M) ? sc[k] * W[(size_t)k * M + ncol] : 0.f;
        Wb[i] = __float2bfloat16(v);
    }
    if (blockIdx.x == 0 && threadIdx.x < M) {
        int j = threadIdx.x;
        float s = 0.f;
        for (int k = 0; k < K; ++k) s -= mu[k] * sc[k] * W[(size_t)k * M + j];
        bout[j] = s;
    }
}

// ---------------------------------------------------------------------------
// MFMA GEMM v6:  C = act( bn(A) @ W + bias ) — weights staged in LDS.
// R8 evidence: SGB load-clustering fails when acc[16]=64 VGPR leaves no room
// for in-flight wfv (VGPR pinned 72-84, loads serialize).  Root fix: every
// wave was re-fetching the same 32-64KB W from L2 (~96 serial ~200cy loads).
// Stage W cooperatively into LDS once per block (8 independent loads/32KB),
// feed MFMA from LDS.  80B-padded rows -> ~2-way bank access (free).
//   SBLK = s-values per 32KB stage; 40KB LDS max -> 3 blocks/CU.
//   BNM: 0 = none (global BN pre-folded into W); 2 = per-segment tables.
// ---------------------------------------------------------------------------
template <typename TC, int NT, int S, int BNM>
__global__ __launch_bounds__(256, 3) void k_mfma_gemm(
    const bf16* __restrict__ A, const bf16* __restrict__ Wb,
    TC* __restrict__ C, int M, int MC,
    const float* __restrict__ bias, int act,
    const float* __restrict__ mu, const float* __restrict__ sc,
    const int* __restrict__ seg)
{
    const int SA = S * 32;
    const int Mp = NT * 16;
    const int SBLK = (16384 / (Mp * 32) < S) ? (16384 / (Mp * 32)) : S;
    const int RPS = SBLK * Mp;              // 64B fragment-rows per stage
    __shared__ __attribute__((aligned(16))) char wstage[RPS * 80];

    const int lane = threadIdx.x;
    const int wave = threadIdx.y;
    const int tid = wave * 64 + lane;
    const int row0 = blockIdx.x * 64 + wave * 16;
    const int qr = lane >> 4;
    const int lc = lane & 15;

    // batch-load all A fragments (S independent loads, overlap staging)
    short8 af[S];
    {
        const bf16* arow = A + (size_t)(row0 + lc) * SA + qr * 8;
#pragma unroll
        for (int s = 0; s < S; ++s) af[s] = *(const short8*)(arow + s * 32);
    }
    if (BNM == 2) {
        size_t bnbase = (size_t)seg[row0 + lc] * SA;
#pragma unroll
        for (int s = 0; s < S; ++s) {
            int kb = s * 32 + qr * 8;
            const float* mp = mu + bnbase + kb;
            const float* sp = sc + bnbase + kb;
            float4 m0 = *(const float4*)mp, m1 = *(const float4*)(mp + 4);
            float4 s0 = *(const float4*)sp, s1 = *(const float4*)(sp + 4);
            float av[8];
#pragma unroll
            for (int j = 0; j < 8; ++j) av[j] = bits2f(af[s][j]);
            av[0] = (av[0] - m0.x) * s0.x; av[1] = (av[1] - m0.y) * s0.y;
            av[2] = (av[2] - m0.z) * s0.z; av[3] = (av[3] - m0.w) * s0.w;
            av[4] = (av[4] - m1.x) * s1.x; av[5] = (av[5] - m1.y) * s1.y;
            av[6] = (av[6] - m1.z) * s1.z; av[7] = (av[7] - m1.w) * s1.w;
#pragma unroll
            for (int j = 0; j < 8; ++j) af[s][j] = bf16bits(av[j]);
        }
    }

    float4v acc[NT];
#pragma unroll
    for (int t = 0; t < NT; ++t) acc[t] = (float4v){0.f, 0.f, 0.f, 0.f};

#pragma unroll
    for (int s0 = 0; s0 < S; s0 += SBLK) {
        if (s0) __syncthreads();                      // prev stage consumed
        stage_w(Wb + (size_t)s0 * Mp * 32, wstage, RPS * 4, tid);
        __syncthreads();
#pragma unroll
        for (int sl = 0; sl < SBLK; ++sl) {
#pragma unroll
            for (int t = 0; t < NT; ++t) {
                short8 wf = wstage_read(wstage, sl * Mp + t * 16 + lc, qr);
                acc[t] = __builtin_amdgcn_mfma_f32_16x16x32_bf16(wf, af[s0 + sl],
                                                                 acc[t], 0, 0, 0);
            }
        }
    }

    const int row = row0 + lc;
#pragma unroll
    for (int t = 0; t < NT; ++t) {
        int c0 = t * 16 + qr * 4;
        if (c0 >= M) continue;
        float v[4];
#pragma unroll
        for (int r = 0; r < 4; ++r) v[r] = acc[t][r];
        if (bias) {
            if (c0 + 3 < M) {
                float4 bv = *(const float4*)(bias + c0);
                v[0] += bv.x; v[1] += bv.y; v[2] += bv.z; v[3] += bv.w;
            } else {
#pragma unroll
                for (int r = 0; r < 4; ++r) if (c0 + r < M) v[r] += bias[c0 + r];
            }
        }
#pragma unroll
        for (int r = 0; r < 4; ++r) {
            if (act == 1) v[r] = fmaxf(v[r], 0.f);
            else if (act == 2) v[r] = 1.f / (1.f + expf(-v[r]));
        }
        if (c0 + 3 < M) {
            if constexpr (sizeof(TC) == 2) {
                short4v pk = {bf16bits(v[0]), bf16bits(v[1]), bf16bits(v[2]), bf16bits(v[3])};
                *(short4v*)((bf16*)C + (size_t)row * MC + c0) = pk;
            } else {
                stf2((float*)C, ((size_t)row * MC + c0) >> 1, make_float2(v[0], v[1]));
                stf2((float*)C, ((size_t)row * MC + c0 + 2) >> 1, make_float2(v[2], v[3]));
            }
        } else {
#pragma unroll
            for (int r = 0; r < 4; ++r)
                if (c0 + r < M) stf(C, (size_t)row * MC + c0 + r, v[r]);
        }
    }
}

template <typename TC, int BNM>
static void launch_mfma(const bf16* A, const bf16* Wb, TC* C, int n, int SA,
                        int Mp, int M, int MC, const float* bias, int act,
                        const float* mu, const float* sc, const int* seg,
                        hipStream_t stream) {
    dim3 b(64, 4);
    int g = n / 64;
    if (SA == 64 && Mp == 256)
        k_mfma_gemm<TC, 16, 2, BNM><<<g, b, 0, stream>>>(A, Wb, C, M, MC, bias, act, mu, sc, seg);
    else if (SA == 256 && Mp == 128)
        k_mfma_gemm<TC, 8, 8, BNM><<<g, b, 0, stream>>>(A, Wb, C, M, MC, bias, act, mu, sc, seg);
    else if (SA == 128 && Mp == 64)
        k_mfma_gemm<TC, 4, 4, BNM><<<g, b, 0, stream>>>(A, Wb, C, M, MC, bias, act, mu, sc, seg);
}

// ---------------------------------------------------------------------------
// L0 stats (R5-proven version, unchanged).
// ---------------------------------------------------------------------------
__global__ __launch_bounds__(256) void k_l0stats(
    const bf16* __restrict__ Y0, const bf16* __restrict__ W0b,
    const float* __restrict__ b0, float* __restrict__ sum,
    float* __restrict__ sumsq, int ntiles)
{
    __shared__ float ls[4][512];
    const int lane = threadIdx.x;
    const int wave = threadIdx.y;
    const int lc = lane & 15, qr = lane >> 4;

    float bv[16];
#pragma unroll
    for (int t = 0; t < 16; ++t) bv[t] = b0[t * 16 + lc];

    float sReg[16], qReg[16];
#pragma unroll
    for (int t = 0; t < 16; ++t) { sReg[t] = 0.f; qReg[t] = 0.f; }

    for (int tile = blockIdx.x; tile < ntiles; tile += gridDim.x) {
        const int row0 = tile * 64 + wave * 16;
        const bf16* arow = Y0 + (size_t)(row0 + lc) * 64 + qr * 8;
        float4v acc[16];
#pragma unroll
        for (int t = 0; t < 16; ++t) acc[t] = (float4v){0.f, 0.f, 0.f, 0.f};
#pragma unroll
        for (int s = 0; s < 2; ++s) {
            short8 af = *(const short8*)(arow + s * 32);
#pragma unroll
            for (int t = 0; t < 16; ++t) {
                short8 wf = *(const short8*)(W0b + ((size_t)(s * 256 + t * 16 + lc)) * 32 + qr * 8);
                // UNSWAPPED: lane owns col t*16+lc, rows qr*4+r
                acc[t] = __builtin_amdgcn_mfma_f32_16x16x32_bf16(af, wf, acc[t], 0, 0, 0);
            }
        }
#pragma unroll
        for (int t = 0; t < 16; ++t) {
            float s4 = 0.f, q4 = 0.f;
#pragma unroll
            for (int r = 0; r < 4; ++r) {
                float v = fmaxf(acc[t][r] + bv[t], 0.f);
                v = bits2f(bf16bits(v));     // match bf16-stored a0 semantics
                s4 += v;
                q4 += v * v;
            }
            s4 += __shfl_xor(s4, 16, 64); s4 += __shfl_xor(s4, 32, 64);
            q4 += __shfl_xor(q4, 16, 64); q4 += __shfl_xor(q4, 32, 64);
            sReg[t] += s4;
            qReg[t] += q4;
        }
    }
    if (lane < 16) {
#pragma unroll
        for (int t = 0; t < 16; ++t) {
            ls[wave][t * 16 + lc] = sReg[t];
            ls[wave][256 + t * 16 + lc] = qReg[t];
        }
    }
    __syncthreads();
    int tid = wave * 64 + lane;
    if (tid < 256) {
        atomicAdd(&sum[tid], ls[0][tid] + ls[1][tid] + ls[2][tid] + ls[3][tid]);
        atomicAdd(&sumsq[tid],
                  ls[0][256 + tid] + ls[1][256 + tid] + ls[2][256 + tid] + ls[3][256 + tid]);
    }
}

// ---------------------------------------------------------------------------
// Fused L0+L1 v4: weights staged in LDS (see k_mfma_gemm v6 note).
//   stage W0 (32KB) -> phase1 -> stage W1' half (32KB) x2 -> phase2.
//   LDS: 40KB wstage + 32KB a0 = 72KB -> 2 blocks/CU, VGPR cap 256.
// ---------------------------------------------------------------------------
__global__ __launch_bounds__(256, 2) void k_fused01(
    const bf16* __restrict__ Y0, const bf16* __restrict__ W0b,
    const float* __restrict__ b0, const bf16* __restrict__ W1b,
    const float* __restrict__ b1f, bf16* __restrict__ G1, int n)
{
    __shared__ __attribute__((aligned(16))) char wstage[40960];
    __shared__ __attribute__((aligned(16))) char a0buf[4][8192];
    const int lane = threadIdx.x;
    const int wave = threadIdx.y;
    const int tid = wave * 64 + lane;
    const int lc = lane & 15, qr = lane >> 4;
    const int row0 = blockIdx.x * 64 + wave * 16;
    char* r2 = a0buf[wave];          // [16][256] bf16, 512B/row
    const int swz = (lc & 7) << 4;

    // stage W0 (2048 chunks = 32KB) while issuing the A loads
    stage_w(W0b, wstage, 2048, tid);
    const bf16* arow = Y0 + (size_t)(row0 + lc) * 64 + qr * 8;
    short8 af0 = *(const short8*)(arow);
    short8 af1 = *(const short8*)(arow + 32);
    __syncthreads();

    // ---- phase 1: a0 = relu(Y0@W0 + b0), K=64 (S=2), 256 cols (NT=16) ----
    {
        float4v acc[16];
#pragma unroll
        for (int t = 0; t < 16; ++t) acc[t] = (float4v){0.f, 0.f, 0.f, 0.f};
#pragma unroll
        for (int s = 0; s < 2; ++s) {
            short8 af = s ? af1 : af0;
#pragma unroll
            for (int t = 0; t < 16; ++t) {
                short8 wf = wstage_read(wstage, s * 256 + t * 16 + lc, qr);
                acc[t] = __builtin_amdgcn_mfma_f32_16x16x32_bf16(wf, af, acc[t], 0, 0, 0);
            }
        }
#pragma unroll
        for (int t = 0; t < 16; ++t) {
            int c0 = t * 16 + qr * 4;
            float4 bv = *(const float4*)(b0 + c0);
            short4v pk = {bf16bits(fmaxf(acc[t][0] + bv.x, 0.f)),
                          bf16bits(fmaxf(acc[t][1] + bv.y, 0.f)),
                          bf16bits(fmaxf(acc[t][2] + bv.z, 0.f)),
                          bf16bits(fmaxf(acc[t][3] + bv.w, 0.f))};
            int off = lc * 512 + t * 32 + qr * 8;
            *(short4v*)(r2 + (off ^ swz)) = pk;
        }
    }

    // ---- phase 2: G1 = a0 @ W1' + b1', K=256 (S=8), 128 cols (NT=8) ----
    short8 afv[8];
#pragma unroll
    for (int s = 0; s < 8; ++s) {
        int off = lc * 512 + s * 64 + qr * 16;
        afv[s] = *(const short8*)(r2 + (off ^ swz));
    }
    float4v a2[8];
#pragma unroll
    for (int t = 0; t < 8; ++t) a2[t] = (float4v){0.f, 0.f, 0.f, 0.f};
#pragma unroll
    for (int h = 0; h < 2; ++h) {
        __syncthreads();                 // all waves done with prev wstage
        stage_w(W1b + h * 16384, wstage, 2048, tid);
        __syncthreads();
#pragma unroll
        for (int sl = 0; sl < 4; ++sl) {
            int s = h * 4 + sl;
#pragma unroll
            for (int t = 0; t < 8; ++t) {
                short8 wf = wstage_read(wstage, sl * 128 + t * 16 + lc, qr);
                a2[t] = __builtin_amdgcn_mfma_f32_16x16x32_bf16(wf, afv[s], a2[t], 0, 0, 0);
            }
        }
    }
    const int row = row0 + lc;
#pragma unroll
    for (int t = 0; t < 8; ++t) {
        int c0 = t * 16 + qr * 4;
        float4 bv = *(const float4*)(b1f + c0);
        short4v pk = {bf16bits(a2[t][0] + bv.x), bf16bits(a2[t][1] + bv.y),
                      bf16bits(a2[t][2] + bv.z), bf16bits(a2[t][3] + bv.w)};
        *(short4v*)(G1 + (size_t)row * 128 + c0) = pk;
    }
}

// ---------------------------------------------------------------------------
// Fused decoder v3 (R7 form, kept — SGB clustering verified effective).
// ---------------------------------------------------------------------------
__global__ __launch_bounds__(256, 3) void k_decoder(
    const bf16* __restrict__ zb, const bf16* __restrict__ dW0b,
    const bf16* __restrict__ dW1b, const bf16* __restrict__ dW2b,
    float* __restrict__ xrec, int n)
{
    __shared__ __attribute__((aligned(16))) char lds[4][12288];
    const int lane = threadIdx.x;
    const int wave = threadIdx.y;
    const int lc = lane & 15, qr = lane >> 4;
    const int row0 = blockIdx.x * 64 + wave * 16;
    char* r1 = lds[wave];            // [16][128] bf16, 256B/row
    char* r2 = lds[wave] + 4096;     // [16][256] bf16, 512B/row
    const int swz = (lc & 7) << 4;

    // ---- layer 1: relu(zb @ dW0), K=64 (S=2), 128 cols (NT=8) ----
    {
        const bf16* arow = zb + (size_t)(row0 + lc) * 64 + qr * 8;
        short8 af0 = *(const short8*)(arow);
        short8 af1 = *(const short8*)(arow + 32);
        float4v a1[8];
#pragma unroll
        for (int t = 0; t < 8; ++t) a1[t] = (float4v){0.f, 0.f, 0.f, 0.f};
#pragma unroll
        for (int s = 0; s < 2; ++s) {
            short8 af = s ? af1 : af0;
            short8 wfv[8];
#pragma unroll
            for (int t = 0; t < 8; ++t)
                wfv[t] = *(const short8*)(dW0b + ((size_t)(s * 128 + t * 16 + lc)) * 32 + qr * 8);
#pragma unroll
            for (int t = 0; t < 8; ++t)
                a1[t] = __builtin_amdgcn_mfma_f32_16x16x32_bf16(wfv[t], af, a1[t], 0, 0, 0);
            __builtin_amdgcn_sched_group_barrier(0x020, 8, 0);  // 8 VMEM reads
            __builtin_amdgcn_sched_group_barrier(0x008, 8, 0);  // 8 MFMAs
        }
#pragma unroll
        for (int t = 0; t < 8; ++t) {
            short4v pk = {bf16bits(fmaxf(a1[t][0], 0.f)), bf16bits(fmaxf(a1[t][1], 0.f)),
                          bf16bits(fmaxf(a1[t][2], 0.f)), bf16bits(fmaxf(a1[t][3], 0.f))};
            int off = lc * 256 + t * 32 + qr * 8;
            *(short4v*)(r1 + (off ^ swz)) = pk;
        }
    }

    // ---- layer 2: relu(r1 @ dW1), K=128 (S=4), 256 cols (NT=16) ----
    {
        short8 afv[4];
#pragma unroll
        for (int s = 0; s < 4; ++s) {
            int off = lc * 256 + s * 64 + qr * 16;
            afv[s] = *(const short8*)(r1 + (off ^ swz));
        }
        float4v a2[16];
#pragma unroll
        for (int t = 0; t < 16; ++t) a2[t] = (float4v){0.f, 0.f, 0.f, 0.f};
#pragma unroll
        for (int s = 0; s < 4; ++s) {
#pragma unroll
            for (int h = 0; h < 2; ++h) {
                short8 wfv[8];
#pragma unroll
                for (int tt = 0; tt < 8; ++tt) {
                    int t = h * 8 + tt;
                    wfv[tt] = *(const short8*)(dW1b + ((size_t)(s * 256 + t * 16 + lc)) * 32 + qr * 8);
                }
#pragma unroll
                for (int tt = 0; tt < 8; ++tt) {
                    int t = h * 8 + tt;
                    a2[t] = __builtin_amdgcn_mfma_f32_16x16x32_bf16(wfv[tt], afv[s], a2[t], 0, 0, 0);
                }
                __builtin_amdgcn_sched_group_barrier(0x020, 8, 0);
                __builtin_amdgcn_sched_group_barrier(0x008, 8, 0);
            }
        }
#pragma unroll
        for (int t = 0; t < 16; ++t) {
            short4v pk = {bf16bits(fmaxf(a2[t][0], 0.f)), bf16bits(fmaxf(a2[t][1], 0.f)),
                          bf16bits(fmaxf(a2[t][2], 0.f)), bf16bits(fmaxf(a2[t][3], 0.f))};
            int off = lc * 512 + t * 32 + qr * 8;
            *(short4v*)(r2 + (off ^ swz)) = pk;
        }
    }

    // ---- layer 3: sigmoid(r2 @ dW2), K=256 (S=8), 38 cols (NT=3, Mp=48) ----
    short8 afv[8];
#pragma unroll
    for (int s = 0; s < 8; ++s) {
        int off = lc * 512 + s * 64 + qr * 16;
        afv[s] = *(const short8*)(r2 + (off ^ swz));
    }
    float4v a3[3];
#pragma unroll
    for (int t = 0; t < 3; ++t) a3[t] = (float4v){0.f, 0.f, 0.f, 0.f};
#pragma unroll
    for (int s = 0; s < 8; ++s) {
        short8 wfv[3];
#pragma unroll
        for (int t = 0; t < 3; ++t)
            wfv[t] = *(const short8*)(dW2b + ((size_t)(s * 48 + t * 16 + lc)) * 32 + qr * 8);
#pragma unroll
        for (int t = 0; t < 3; ++t)
            a3[t] = __builtin_amdgcn_mfma_f32_16x16x32_bf16(wfv[t], afv[s], a3[t], 0, 0, 0);
        __builtin_amdgcn_sched_group_barrier(0x020, 3, 0);
        __builtin_amdgcn_sched_group_barrier(0x008, 3, 0);
    }
    float* orow = xrec + (size_t)(row0 + lc) * 38;
#pragma unroll
    for (int t = 0; t < 3; ++t) {
        int c0 = t * 16 + qr * 4;
        float v0 = 1.f / (1.f + expf(-a3[t][0]));
        float v1 = 1.f / (1.f + expf(-a3[t][1]));
        float v2 = 1.f / (1.f + expf(-a3[t][2]));
        float v3 = 1.f / (1.f + expf(-a3[t][3]));
        if (c0 + 1 < 38) *(float2*)(orow + c0) = make_float2(v0, v1);
        if (c0 + 3 < 38) *(float2*)(orow + c0 + 2) = make_float2(v2, v3);
    }
}

// ---------------------------------------------------------------------------
// LDS-tiled fp32 vector GEMM (t-MLP / classifier — tiny n, precision-tight)
// ---------------------------------------------------------------------------
template <typename TA, typename TC, int NJ>
__global__ __launch_bounds__(256) void k_gemm(
    const TA* __restrict__ A, const float* __restrict__ W,
    TC* __restrict__ C, int n, int K, int M,
    const float* __restrict__ bias, int act,
    const float* __restrict__ mu, const float* __restrict__ sc)
{
    __shared__ float alds[64 * 32];
    __shared__ float wlds[32 * 256];
    const int l = threadIdx.x;
    const int wy = threadIdx.y;
    const int tid = wy * 64 + l;
    const int row0 = blockIdx.x * 64;

    float acc[16][NJ];
#pragma unroll
    for (int r = 0; r < 16; ++r)
#pragma unroll
        for (int j = 0; j < NJ; ++j) acc[r][j] = 0.f;

    int cidx[NJ]; bool jval[NJ];
#pragma unroll
    for (int j = 0; j < NJ; ++j) {
        cidx[j] = l + 64 * j;
        jval[j] = cidx[j] < M;
    }

    for (int k0 = 0; k0 < K; k0 += 32) {
        int kt = min(32, K - k0);
        __syncthreads();
        for (int i = tid; i < 64 * 32; i += 256) {
            int r = i >> 5, kk = i & 31;
            int row = row0 + r, k = k0 + kk;
            float v = (row < n && k < K) ? ldf(A, (size_t)row * K + k) : 0.f;
            if (mu && k < K) v = (v - mu[k]) * sc[k];
            alds[i] = v;
        }
        for (int i = tid; i < kt * M; i += 256)
            wlds[i] = W[(size_t)k0 * M + i];
        if (kt < 32)
            for (int i = kt * M + tid; i < 32 * M; i += 256) wlds[i] = 0.f;
        __syncthreads();

#pragma unroll 2
        for (int kkg = 0; kkg < 8; ++kkg) {
            float wv[4][NJ];
#pragma unroll
            for (int q = 0; q < 4; ++q)
#pragma unroll
                for (int j = 0; j < NJ; ++j)
                    wv[q][j] = jval[j] ? wlds[(kkg * 4 + q) * M + cidx[j]] : 0.f;
#pragma unroll
            for (int rr = 0; rr < 16; ++rr) {
                const float4* arow = (const float4*)&alds[(wy * 16 + rr) * 32];
                float4 av = arow[kkg];
#pragma unroll
                for (int j = 0; j < NJ; ++j) {
                    acc[rr][j] += av.x * wv[0][j];
                    acc[rr][j] += av.y * wv[1][j];
                    acc[rr][j] += av.z * wv[2][j];
                    acc[rr][j] += av.w * wv[3][j];
                }
            }
        }
    }

#pragma unroll
    for (int rr = 0; rr < 16; ++rr) {
        int row = row0 + wy * 16 + rr;
        if (row >= n) continue;
#pragma unroll
        for (int j = 0; j < NJ; ++j) {
            if (!jval[j]) continue;
            float v = acc[rr][j];
            if (bias) v += bias[cidx[j]];
            if (act == 1) v = fmaxf(v, 0.f);
            else if (act == 2) v = 1.f / (1.f + expf(-v));
            stf(C, (size_t)row * M + cidx[j], v);
        }
    }
}

// ---------------------------------------------------------------------------
// BatchNorm stats: vectorized 8-col loads, LDS-staged atomics.
// ---------------------------------------------------------------------------
template <typename T>
__global__ __launch_bounds__(256) void k_bn_stats8(
    const T* __restrict__ x, int n, int M,
    float* __restrict__ sum, float* __restrict__ sumsq)
{
    __shared__ float ls[512];
    int t = threadIdx.x;
    for (int i = t; i < 2 * M; i += 256) ls[i] = 0.f;
    __syncthreads();

    int gpr = M >> 3;           // col-groups per row
    int c8 = (t % gpr) * 8;
    int g = t / gpr;
    int rpb = 256 / gpr;

    float s[8], q[8];
#pragma unroll
    for (int j = 0; j < 8; ++j) { s[j] = 0.f; q[j] = 0.f; }

    for (int r = blockIdx.x * rpb + g; r < n; r += gridDim.x * rpb) {
        float v[8];
        if constexpr (sizeof(T) == 2) {
            short8 v8 = *(const short8*)((const bf16*)x + (size_t)r * M + c8);
#pragma unroll
            for (int j = 0; j < 8; ++j) v[j] = bits2f(v8[j]);
        } else {
            float4 f0 = *(const float4*)((const float*)x + (size_t)r * M + c8);
            float4 f1 = *(const float4*)((const float*)x + (size_t)r * M + c8 + 4);
            v[0] = f0.x; v[1] = f0.y; v[2] = f0.z; v[3] = f0.w;
            v[4] = f1.x; v[5] = f1.y; v[6] = f1.z; v[7] = f1.w;
        }
#pragma unroll
        for (int j = 0; j < 8; ++j) { s[j] += v[j]; q[j] += v[j] * v[j]; }
    }
#pragma unroll
    for (int j = 0; j < 8; ++j) {
        atomicAdd(&ls[c8 + j], s[j]);
        atomicAdd(&ls[M + c8 + j], q[j]);
    }
    __syncthreads();
    for (int i = t; i < M; i += 256) {
        atomicAdd(&sum[i], ls[i]);
        atomicAdd(&sumsq[i], ls[M + i]);
    }
}

__global__ void k_bn_fin(float* __restrict__ sum, float* __restrict__ sumsq, int n, int M) {
    int c = threadIdx.x;
    if (c < M) {
        float m = sum[c] / (float)n;
        float v = fmaxf(sumsq[c] / (float)n - m * m, 0.f);
        sum[c] = m;
        sumsq[c] = rsqrtf(v + BN_EPS);
    }
}

// ---------------------------------------------------------------------------
// Wave-per-segment BN stats (sorted seg, boundaries precomputed): writes
// mu/sc DIRECTLY.  No atomics, no zero-fill, no fin pass.  M = 64*CPL.
// ---------------------------------------------------------------------------
template <int CPL>
__global__ __launch_bounds__(256) void k_segbn(
    const bf16* __restrict__ x, const int* __restrict__ gstart, int nseg,
    float* __restrict__ mu, float* __restrict__ sc)
{
    const int M = 64 * CPL;
    int s = blockIdx.x * 4 + threadIdx.y;
    if (s >= nseg) return;
    int l = threadIdx.x;
    int gs = gstart[s], ge = gstart[s + 1];
    float sum[CPL], sq[CPL];
#pragma unroll
    for (int j = 0; j < CPL; ++j) { sum[j] = 0.f; sq[j] = 0.f; }
    for (int r = gs; r < ge; ++r) {
        const bf16* px = x + (size_t)r * M + l * CPL;
        if constexpr (CPL == 4) {
            short4v v4 = *(const short4v*)px;
#pragma unroll
            for (int j = 0; j < 4; ++j) {
                float v = bits2f(v4[j]);
                sum[j] += v; sq[j] += v * v;
            }
        } else {
            __hip_bfloat162 v2 = *(const __hip_bfloat162*)px;
            float v0 = __bfloat162float(v2.x), v1 = __bfloat162float(v2.y);
            sum[0] += v0; sq[0] += v0 * v0;
            sum[1] += v1; sq[1] += v1 * v1;
        }
    }
    float c = fmaxf((float)(ge - gs), 1.f);
#pragma unroll
    for (int j = 0; j < CPL; ++j) {
        float m = sum[j] / c;
        float v = fmaxf(sq[j] / c - m * m, 0.f);
        mu[(size_t)s * M + l * CPL + j] = m;
        sc[(size_t)s * M + l * CPL + j] = rsqrtf(v + BN_EPS);
    }
}

// ---------------------------------------------------------------------------
// Wave-per-segment mean pool over 64-col fp32 rows (input pre-normalized).
// ---------------------------------------------------------------------------
__global__ __launch_bounds__(256) void k_pool(
    const float* __restrict__ z, const int* __restrict__ gstart, int nseg,
    float* __restrict__ o)
{
    int s = blockIdx.x * 4 + threadIdx.y;
    if (s >= nseg) return;
    int l = threadIdx.x;
    int gs = gstart[s], ge = gstart[s + 1];
    float acc = 0.f;
    for (int r = gs; r < ge; ++r) acc += z[(size_t)r * 64 + l];
    o[(size_t)s * 64 + l] = acc / fmaxf((float)(ge - gs), 1.f);
}

// ---------------------------------------------------------------------------
// Wave-per-segment fused l2norm + mean pool (sub path: zs is only pooled).
// ---------------------------------------------------------------------------
__global__ __launch_bounds__(256) void k_l2pool(
    const float* __restrict__ zs, const int* __restrict__ gstart, int nseg,
    float* __restrict__ o)
{
    int s = blockIdx.x * 4 + threadIdx.y;
    if (s >= nseg) return;
    int l = threadIdx.x;
    int gs = gstart[s], ge = gstart[s + 1];
    float acc = 0.f;
    for (int r = gs; r < ge; ++r) {
        float v = zs[(size_t)r * 64 + l];
        float ss = v * v;
        for (int off = 32; off > 0; off >>= 1) ss += __shfl_xor(ss, off, 64);
        acc += v / fmaxf(sqrtf(ss), 1e-12f);
    }
    o[(size_t)s * 64 + l] = acc / fmaxf((float)(ge - gs), 1.f);
}

// ---------------------------------------------------------------------------
// Row L2 normalize, M = 64; writes fp32 in place + optional bf16 copy
// ---------------------------------------------------------------------------
__global__ void k_l2norm2(float* __restrict__ x, bf16* __restrict__ xb, int n) {
    int row = blockIdx.x * 4 + threadIdx.y;
    if (row >= n) return;
    int l = threadIdx.x;
    float v = x[(size_t)row * 64 + l];
    float ss = v * v;
    for (int o = 32; o > 0; o >>= 1) ss += __shfl_xor(ss, o, 64);
    float r = v / fmaxf(sqrtf(ss), 1e-12f);
    x[(size_t)row * 64 + l] = r;
    if (xb) xb[(size_t)row * 64 + l] = __float2bfloat16(r);
}

// ---------------------------------------------------------------------------
// Host-side vector-GEMM launch helper
// ---------------------------------------------------------------------------
template <typename TA, typename TC>
static void launch_gemm(const TA* A, const float* W, TC* C, int n, int K, int M,
                        const float* bias, int act, const float* mu, const float* sc,
                        hipStream_t stream) {
    dim3 b(64, 4);
    int g = cdiv(n, 64);
    int nj = (M + 63) >> 6;
    if (nj >= 4)      k_gemm<TA, TC, 4><<<g, b, 0, stream>>>(A, W, C, n, K, M, bias, act, mu, sc);
    else if (nj == 2) k_gemm<TA, TC, 2><<<g, b, 0, stream>>>(A, W, C, n, K, M, bias, act, mu, sc);
    else              k_gemm<TA, TC, 1><<<g, b, 0, stream>>>(A, W, C, n, K, M, bias, act, mu, sc);
}

// ---------------------------------------------------------------------------
// Host launch
// ---------------------------------------------------------------------------
extern "C" void kernel_launch(void* const* d_in, const int* in_sizes, int n_in,
                              void* d_out, int out_size, void* d_ws, size_t ws_size,
                              hipStream_t stream) {
    const float* x        = (const float*)d_in[0];
    const int*   ei       = (const int*)  d_in[1];
    const int*   batch    = (const int*)  d_in[2];
    const float* target_x = (const float*)d_in[3];
    const float* pos_x    = (const float*)d_in[4];
    const int*   pos_ei   = (const int*)  d_in[5];
    const int*   pos_b    = (const int*)  d_in[6];
    const float* neg_x    = (const float*)d_in[7];
    const int*   neg_ei   = (const int*)  d_in[8];
    const int*   neg_b    = (const int*)  d_in[9];
    const float* enc_W0 = (const float*)d_in[10]; const float* enc_b0 = (const float*)d_in[11];
    const float* enc_W1 = (const float*)d_in[12]; const float* enc_b1 = (const float*)d_in[13];
    const float* enc_W2 = (const float*)d_in[14]; const float* enc_b2 = (const float*)d_in[15];
    const float* dec_W0 = (const float*)d_in[16];
    const float* dec_W1 = (const float*)d_in[17];
    const float* dec_W2 = (const float*)d_in[18];
    const float* node_W0 = (const float*)d_in[19]; const float* node_b0 = (const float*)d_in[20];
    const float* node_W1 = (const float*)d_in[21]; const float* node_b1 = (const float*)d_in[22];
    const float* node_W2 = (const float*)d_in[23]; const float* node_b2 = (const float*)d_in[24];
    const float* sub_W0 = (const float*)d_in[25]; const float* sub_b0 = (const float*)d_in[26];
    const float* sub_W1 = (const float*)d_in[27]; const float* sub_b1 = (const float*)d_in[28];
    const float* cls_W0 = (const float*)d_in[29]; const float* cls_b0 = (const float*)d_in[30];
    const float* cls_W1 = (const float*)d_in[31]; const float* cls_b1 = (const float*)d_in[32];
    const float* cls_W2 = (const float*)d_in[33]; const float* cls_b2 = (const float*)d_in[34];

    float* out = (float*)d_out;
    const size_t OFF_XREC  = 0;
    const size_t OFF_ZPOOL = (size_t)N_NODES * F_IN;
    const size_t OFF_TZ    = OFF_ZPOOL + (size_t)N_GRAPHS * H2;
    const size_t OFF_PPOOL = OFF_TZ    + (size_t)N_GRAPHS * H2;
    const size_t OFF_NPOOL = OFF_PPOOL + (size_t)N_GRAPHS * H2;
    const size_t OFF_PRED  = OFF_NPOOL + (size_t)N_GRAPHS * H2;

    // ----- workspace carve-up (by floats; total ~207 MB) -----
    char* wsp = (char*)d_ws;
    auto alloc = [&](size_t nfloats) -> float* {
        float* p = (float*)wsp;
        wsp += ((nfloats + 63) / 64) * 64 * sizeof(float);
        return p;
    };
    float* R1     = alloc((size_t)N_NODES * 128);   // fp32 N*128 / bf16 N*256
    float* R2     = alloc((size_t)N_NODES * 128);
    float* dinv   = alloc(N_NODES);
    int*   cnt    = (int*)alloc(N_NODES);           // degree, then reused as cursor
    int*   rowptr = (int*)alloc(N_NODES + 1);
    int*   bsum   = (int*)alloc(1024);
    int*   ccol   = (int*)alloc(N_EDGES);
    float* ssum   = alloc(256);
    float* ssumsq = alloc(256);   // contiguous with ssum
    bf16*  wpk    = (bf16*)alloc(101 * 1024);  // 206848-bf16 arena, 200704 used
    float* bfold  = alloc(256);   // folded biases: b1' [0..128), b2' [128..192)
    (void)ws_size; (void)in_sizes; (void)n_in; (void)out_size;

    // packed-weight arena offsets (bf16 elements): S*Mp*32 each
    bf16* eW0b = wpk;            // K38->S2,  Mp256: 16384
    bf16* eW1b = eW0b + 16384;   // K256->S8, Mp128: 32768 (unused; layout keep)
    bf16* eW2b = eW1b + 32768;   // K128->S4, Mp64 :  8192
    bf16* dW0b = eW2b + 8192;    // K64->S2,  Mp128:  8192
    bf16* dW1b = dW0b + 8192;    // K128->S4, Mp256: 32768
    bf16* dW2b = dW1b + 32768;   // K256->S8, Mp48 : 12288
    bf16* sW0b = dW2b + 12288;   // K38->S2,  Mp256: 16384
    bf16* sW1b = sW0b + 16384;   // K256->S8, Mp128: 32768
    bf16* fW1b = sW1b + 32768;   // folded enc_W1': K256, Mp128: 32768
    bf16* fW2b = fW1b + 32768;   // folded enc_W2': K128, Mp64 :  8192

    // ----- R2-tail carve (no new allocs).
    float* tailf    = R2 + (size_t)16 * 1024 * 1024;          // 64 MB offset
    float* segsumM  = tailf;                                  // mu  4096*256
    float* segsumqM = tailf + (size_t)1048576;                // sc  4096*256
    float* mx       = tailf + (size_t)2097152;                // 2*N_SUB*F_IN fp32
    int*   msrc     = (int*)(mx + (size_t)2 * N_SUB * F_IN);  // 2*E_SUB
    int*   mdst     = msrc + 2 * E_SUB;                       // 2*E_SUB
    int*   mb       = mdst + 2 * E_SUB;                       // 2*N_SUB
    int*   gstartM  = mb + 2 * N_SUB;                         // 4097 ints (sub)
    int*   gstart2k = gstartM + 4112;                         // 2049 ints (main)

    dim3 b64x4(64, 4);
    auto zero = [&](void* p, size_t nfloats) {
        k_zero<<<cdiv((int)nfloats, 256), 256, 0, stream>>>((float*)p, (int)nfloats);
    };

    // pack all 8 weights in one launch (seg-BN fused at GEMM A-load;
    // global BN folded into W via k_wfold after stats)
    k_wpack_all<<<624, 256, 0, stream>>>(enc_W0, enc_W1, enc_W2, dec_W0, dec_W1,
                                         dec_W2, sub_W0, sub_W1, wpk);

    auto build_graph = [&](const int* srcp, const int* dstp, int n, int e) {
        zero(cnt, n);
        k_count<<<cdiv(e, 256), 256, 0, stream>>>(dstp, cnt, e);
        k_dinv<<<cdiv(n, 256), 256, 0, stream>>>(cnt, dinv, n);
        int nb = cdiv(n, 256);
        k_scan_sum<<<nb, 256, 0, stream>>>(cnt, bsum, n);
        k_scan_top<<<1, 1024, 0, stream>>>(bsum, nb);
        k_scan_apply<<<nb, 256, 0, stream>>>(cnt, bsum, rowptr, n);
        zero(cnt, n);  // cnt now serves as the fill cursor
        k_fill<<<cdiv(e, 256), 256, 0, stream>>>(srcp, dstp, rowptr, cnt, ccol, e);
    };

    auto bn_stats = [&](auto* xx, int n, int M) {
        zero(ssum, 512);  // ssum+ssumsq contiguous
        int rpb = 256 / (M >> 3);
        int g = min(512, cdiv(n, rpb));
        k_bn_stats8<<<g, 256, 0, stream>>>(xx, n, M, ssum, ssumsq);
        k_bn_fin<<<1, 256, 0, stream>>>(ssum, ssumsq, n, M);
    };

    // ============ main graph encode (fused L0+L1, BN folded into W) ============
    build_graph(ei, ei + N_EDGES, N_NODES, N_EDGES);

    // Y0 = A_hat * x  (bf16 N x 64, K-pad 38->64)  — in R1 (fused01 writes R2)
    bf16* Y0 = (bf16*)R1;
    launch_gather<float, bf16>(x, dinv, rowptr, ccol, Y0, N_NODES, F_IN, 64,
                               nullptr, 0, stream);

    // a0 stats computed in-register from Y0 (a0 never materialized)
    zero(ssum, 512);
    k_l0stats<<<512, b64x4, 0, stream>>>(Y0, eW0b, enc_b0, ssum, ssumsq,
                                         N_NODES / 64);
    k_bn_fin<<<1, 256, 0, stream>>>(ssum, ssumsq, N_NODES, H0);
    k_wfold<256, 128, 128><<<128, 256, 0, stream>>>(enc_W1, ssum, ssumsq, fW1b, bfold);

    // Fused L0+L1: G1 = relu(Y0@W0+b0) @ W1' + b1'
    bf16* G1 = (bf16*)R2;
    k_fused01<<<N_NODES / 64, b64x4, 0, stream>>>(Y0, eW0b, enc_b0, fW1b, bfold,
                                                  G1, N_NODES);

    // a1 = relu(A_hat*G1 + b1)   (Y0 dead -> a1 in R1)
    bf16* a1 = (bf16*)R1;
    launch_gather6<bf16>(G1, dinv, rowptr, ccol, a1, N_NODES, 128, enc_b1, 1, stream);
    bn_stats(a1, N_NODES, H1);
    k_wfold<128, 64, 64><<<32, 256, 0, stream>>>(enc_W2, ssum, ssumsq, fW2b, bfold + 128);

    // Layer 2: G2 = a1@W2' + b2'; z = A_hat*G2 + b2, l2norm
    bf16* G2 = (bf16*)R2;
    launch_mfma<bf16, 0>(a1, fW2b, G2, N_NODES, 128, 64, H2, H2, bfold + 128, 0,
                         nullptr, nullptr, nullptr, stream);
    float* z  = R1;
    bf16*  zb = (bf16*)(R1 + (size_t)N_NODES * 64);
    launch_gather6<float>(G2, dinv, rowptr, ccol, z, N_NODES, 64, enc_b2, 0, stream);
    k_l2norm2<<<cdiv(N_NODES, 4), b64x4, 0, stream>>>(z, zb, N_NODES);

    // z_pool (boundaries from sorted batch; wave-per-segment mean)
    k_gbound<<<cdiv(N_NODES, 256), 256, 0, stream>>>(batch, N_NODES, N_GRAPHS, gstart2k);
    k_pool<<<cdiv(N_GRAPHS, 4), b64x4, 0, stream>>>(z, gstart2k, N_GRAPHS,
                                                    out + OFF_ZPOOL);

    // ===================== decode: single fused kernel =====================
    k_decoder<<<N_NODES / 64, b64x4, 0, stream>>>(zb, dW0b, dW1b, dW2b,
                                                  out + OFF_XREC, N_NODES);

    // ===================== target node MLP (fp32 vector) =====================
    float* t0 = R2;  // 2048 x 256
    launch_gemm<float, float>(target_x, node_W0, t0, N_GRAPHS, F_IN, H0, node_b0, 1,
                              nullptr, nullptr, stream);
    bn_stats(t0, N_GRAPHS, H0);
    float* t1 = R1;  // 2048 x 128
    launch_gemm<float, float>(t0, node_W1, t1, N_GRAPHS, H0, H1, node_b1, 1,
                              ssum, ssumsq, stream);
    bn_stats(t1, N_GRAPHS, H1);
    launch_gemm<float, float>(t1, node_W2, out + OFF_TZ, N_GRAPHS, H1, H2, node_b2, 0,
                              ssum, ssumsq, stream);
    k_l2norm2<<<cdiv(N_GRAPHS, 4), b64x4, 0, stream>>>(out + OFF_TZ, nullptr, N_GRAPHS);

    // ========== merged pos+neg subgraph pipeline (one batched pass) ==========
    k_merge<<<2048, 256, 0, stream>>>(pos_x, neg_x, pos_ei, neg_ei, pos_b, neg_b,
                                      mx, msrc, mdst, mb);
    const int NS2 = 2 * N_SUB, ES2 = 2 * E_SUB, NG2 = 2 * N_GRAPHS;
    build_graph(msrc, mdst, NS2, ES2);
    k_gbound<<<cdiv(NS2, 256), 256, 0, stream>>>(mb, NS2, NG2, gstartM);

    // Layer 0: Ys = A_hat*mx (bf16, pad 38->64); as0 = relu(Ys@sW0 + b)
    bf16* Ys = (bf16*)R2;
    launch_gather<float, bf16>(mx, dinv, rowptr, ccol, Ys, NS2, F_IN, 64,
                               nullptr, 0, stream);
    bf16* as0 = (bf16*)R1;  // 65536 x 256
    launch_mfma<bf16, 0>(Ys, sW0b, as0, NS2, 64, 256, H0, H0, sub_b0, 1,
                         nullptr, nullptr, nullptr, stream);
    k_segbn<4><<<cdiv(NG2, 4), b64x4, 0, stream>>>(as0, gstartM, NG2,
                                                   segsumM, segsumqM);

    // Layer 1: Gs1 = segbn(as0)@sW1; as1 = relu(A_hat*Gs1 + b1)
    bf16* Gs1 = (bf16*)R2;  // 65536 x 128
    launch_mfma<bf16, 2>(as0, sW1b, Gs1, NS2, 256, 128, H1, H1, nullptr, 0,
                         segsumM, segsumqM, mb, stream);
    bf16* as1 = (bf16*)R1;  // 65536 x 128
    launch_gather6<bf16>(Gs1, dinv, rowptr, ccol, as1, NS2, 128, sub_b1, 1, stream);
    k_segbn<2><<<cdiv(NG2, 4), b64x4, 0, stream>>>(as1, gstartM, NG2,
                                                   segsumM, segsumqM);

    // Layer 2: Gs2 = segbn(as1)@encW2; zs = A_hat*Gs2 + b2; fused l2norm+pool
    bf16* Gs2 = (bf16*)R2;  // 65536 x 64
    launch_mfma<bf16, 2>(as1, eW2b, Gs2, NS2, 128, 64, H2, H2, nullptr, 0,
                         segsumM, segsumqM, mb, stream);
    float* zs = R1;  // 65536 x 64 fp32
    launch_gather6<float>(Gs2, dinv, rowptr, ccol, zs, NS2, 64, enc_b2, 0, stream);
    k_l2pool<<<cdiv(NG2, 4), b64x4, 0, stream>>>(zs, gstartM, NG2, out + OFF_PPOOL);

    // ===================== classifier on neg_pool (fp32 vector) =====================
    float* c1 = R2;
    launch_gemm<float, float>(out + OFF_NPOOL, cls_W0, c1, N_GRAPHS, H2, H1, cls_b0, 1,
                              nullptr, nullptr, stream);
    float* c2 = R1;
    launch_gemm<float, float>(c1, cls_W1, c2, N_GRAPHS, H1, 16, cls_b1, 1,
                              nullptr, nullptr, stream);
    launch_gemm<float, float>(c2, cls_W2, out + OFF_PRED, N_GRAPHS, 16, 1, cls_b2, 2,
                              nullptr, nullptr, stream);
}